// Round 8
// baseline (988.551 us; speedup 1.0000x reference)
//
#include <hip/hip_runtime.h>
#include <hip/hip_bf16.h>
#include <cstdint>
#include <cstddef>

// ---------------------------------------------------------------------------
// Model constants
// ---------------------------------------------------------------------------
#define BT        16384          // B*T tokens
#define MAXASSIGN 33792          // 32768 + 8*127 rounded to 128-aligned segments
#define QSCALE    0.36067376022224085f   // 0.25 * log2(e): fold 1/sqrt(dh) + exp->exp2

typedef __attribute__((ext_vector_type(8)))  short short8;   // 8 bf16 = 1 MFMA frag
typedef __attribute__((ext_vector_type(4)))  short short4v;
typedef __attribute__((ext_vector_type(4)))  float f32x4;
typedef __attribute__((ext_vector_type(16))) float f32x16;

typedef const uint32_t __attribute__((address_space(1))) gas_u32;
typedef uint32_t __attribute__((address_space(3))) las_u32;

// async global->LDS direct copy, 16B per lane; LDS dest = wave base + lane*16
__device__ __forceinline__ void gload16(const void* g, void* l) {
    __builtin_amdgcn_global_load_lds((gas_u32*)g, (las_u32*)l, 16, 0, 0);
}

// gelu(x) = 0.5x(1+tanh(u)) = x*sigmoid(2u), u = sqrt(2/pi)(x+0.044715x^3).
__device__ __forceinline__ float gelu_f(float x) {
    float u2l = (x + 0.044715f * x * x * x) * 2.3022081927f;   // 2u*log2(e)
    float e = exp2f(u2l);
    float r = __builtin_amdgcn_rcpf(e + 1.0f);
    return x * e * r;
}

// pack 2 floats -> 1 u32 of 2 bf16 (RNE), a = low half
__device__ __forceinline__ unsigned pkbf(float a, float b) {
    __hip_bfloat16 ha = __float2bfloat16(a);
    __hip_bfloat16 hb = __float2bfloat16(b);
    unsigned short ua = *reinterpret_cast<unsigned short*>(&ha);
    unsigned short ub = *reinterpret_cast<unsigned short*>(&hb);
    return (unsigned)ua | ((unsigned)ub << 16);
}

// ---------------------------------------------------------------------------
// 1. x [32,55,512,8] -> xtb [16384][448] bf16 (cols 440..447 zero-padded)
// ---------------------------------------------------------------------------
__global__ __launch_bounds__(256) void transpose_kernel(const float* __restrict__ x,
                                                        __hip_bfloat16* __restrict__ xtb) {
    __shared__ unsigned tile[64][228];   // [t][packed bf16-pair col]; pad 224->228
    const int b  = blockIdx.x >> 3;      // 32 batches
    const int t0 = (blockIdx.x & 7) * 64;
    const int tid = threadIdx.x;
    tile[tid >> 2][220 + (tid & 3)] = 0u;
    const int tt  = tid >> 2;            // 0..63  (t within tile)
    const int ncp = tid & 3;             // bf16-pair within nb block
    for (int nb = 0; nb < 55; ++nb) {
        const float2* src = (const float2*)(x + (((size_t)(b * 55 + nb)) * 512 + t0) * 8);
        float2 v = src[tid];             // 256 float2 = 64t x 8nc, contiguous
        tile[tt][nb * 4 + ncp] = pkbf(v.x, v.y);
    }
    __syncthreads();
#pragma unroll
    for (int u = 0; u < 14; ++u) {
        int idx = u * 256 + tid;
        int t = idx / 56, c = idx % 56;
        *(uint4*)(xtb + ((size_t)b * 512 + t0 + t) * 448 + c * 8) =
            *(const uint4*)&tile[t][c * 4];
    }
}

// ---------------------------------------------------------------------------
// 2. Weight convert+transpose via LDS tile: out[b][n][k] = bf16(in[b][k][n])
// ---------------------------------------------------------------------------
__global__ __launch_bounds__(256) void wconvt_kernel(const float* __restrict__ in,
                                                     __hip_bfloat16* __restrict__ out,
                                                     int K, int N) {
    __shared__ float tile[64][65];
    const int kt = K >> 6, nt = N >> 6;
    const int per = kt * nt;
    const int bb  = blockIdx.x / per;
    const int rem = blockIdx.x % per;
    const int k0  = (rem / nt) << 6;
    const int n0  = (rem % nt) << 6;
    const int tid = threadIdx.x;

    const float* src = in + ((size_t)bb * K + k0) * N + n0;
    int tk = tid >> 4;               // 0..15
    int tn = (tid & 15) * 4;         // 0..60
#pragma unroll
    for (int r = 0; r < 4; ++r) {
        float4 v = *(const float4*)(src + (size_t)(tk + r * 16) * N + tn);
        tile[tk + r * 16][tn]     = v.x;
        tile[tk + r * 16][tn + 1] = v.y;
        tile[tk + r * 16][tn + 2] = v.z;
        tile[tk + r * 16][tn + 3] = v.w;
    }
    __syncthreads();
    int on = tid >> 2;               // 0..63
    int ok = (tid & 3) * 16;         // 0,16,32,48
    unsigned pk[8];
#pragma unroll
    for (int u = 0; u < 8; ++u)
        pk[u] = pkbf(tile[ok + 2 * u][on], tile[ok + 2 * u + 1][on]);
    uint4* dst = (uint4*)(out + ((size_t)bb * N + n0 + on) * K + k0 + ok);
    dst[0] = (uint4){pk[0], pk[1], pk[2], pk[3]};
    dst[1] = (uint4){pk[4], pk[5], pk[6], pk[7]};
}

// proj_W [440][128] -> projWt [128][448] bf16 with zero pad k>=440 (tiny)
__global__ __launch_bounds__(256) void projconv_kernel(const float* __restrict__ in,
                                                       __hip_bfloat16* __restrict__ out) {
    int idx = blockIdx.x * 256 + threadIdx.x;      // 128*448 exact
    int k = idx % 448, n = idx / 448;
    out[idx] = __float2bfloat16(k < 440 ? in[k * 128 + n] : 0.f);
}

// ---------------------------------------------------------------------------
// 3. bf16 MFMA GEMM, templated <MODE, BM> (per-mode DCE; BM = row-tile).
//    BM=128: 4 waves 2x2, 4x4 frags. BM=64: 2x4 frags -> 2x grid for the
//    latency-bound small GEMMs (proj/qkv/out/moe2 were 128-384 blocks).
//    mfma_f32_16x16x32_bf16, operand-swapped (acc = C^T frags). LDS
//    chunk-XOR swizzle; global_load_lds width-16 linear-dest staging with
//    inverse-swizzled global source. LDS-repack epilogue, coalesced stores.
//    MODE 0: proj, f32 out + pos.   MODE 2: out-proj, f32 residual add.
//    MODE 3: moe1, gathered A (atok), gelu, bf16 out.
//    MODE 4: moe2, f32 out * awt.
//    MODE 5: qkv, bf16 HEAD-MAJOR [part][h][token][16], Q pre-scaled.
// ---------------------------------------------------------------------------
template<int MODE, int BM>
__global__ __launch_bounds__(256) void mm_kernel(
    const __hip_bfloat16* __restrict__ A, const __hip_bfloat16* __restrict__ Wt,
    const float* __restrict__ bias, const float* __restrict__ extra,
    void* __restrict__ Cout, int K, int N, int wstride,
    const int* __restrict__ moff, const int* __restrict__ atok,
    const float* __restrict__ awt)
{
    constexpr int FI = BM / 32;          // A p-groups / frag rows per wave
    __shared__ short smem[16384];        // 32 KB: As|Bs in K-loop, C-tile after
    short* As = smem;                    // BM*64 shorts
    short* Bs = smem + BM * 64;          // 8192 shorts (128x64)
    const int tid  = threadIdx.x;
    const int row0 = blockIdx.x * BM;
    const int col0 = blockIdx.y * 128;

    const float* bias2 = bias;
    int lim = 0;
    if constexpr (MODE == 3 || MODE == 4) {
        if (row0 >= moff[8]) return;             // segments are 128-aligned
        int e = 0;
        while (moff[e + 1] <= row0) ++e;
        Wt    += (size_t)e * wstride;
        bias2  = bias + e * N;
        lim    = moff[e] + moff[9 + e];          // valid-assignment end
    }

    const int wave = tid >> 6, lane = tid & 63;
    const int crow = tid >> 3;   // 0..31  (staging row within p-group)
    const int cc   = tid & 7;    // 0..7   (16B chunk within row)

    int srow[FI];
#pragma unroll
    for (int p = 0; p < FI; ++p) {
        int grow = row0 + p * 32 + crow;
        srow[p] = grow;
        if constexpr (MODE == 3)
            srow[p] = (grow < lim) ? atok[grow] : BT;   // pad -> zeroed row
    }

    f32x4 acc[FI][4];
#pragma unroll
    for (int i = 0; i < FI; ++i)
#pragma unroll
        for (int j = 0; j < 4; ++j) acc[i][j] = (f32x4){0.f, 0.f, 0.f, 0.f};

    const int wm = (wave >> 1) * (BM / 2), wn = (wave & 1) * 64;
    const int lr = lane & 15, q = lane >> 4;

    for (int k0 = 0; k0 < K; k0 += 64) {
#pragma unroll
        for (int p = 0; p < FI; ++p) {
            int row = p * 32 + crow;
            int sc  = (cc ^ (row & 7)) << 3;             // swizzled src chunk
            short* la = &As[(p * 32 + wave * 8) * 64];
            gload16(A + (size_t)srow[p] * K + k0 + sc, la);
        }
#pragma unroll
        for (int p = 0; p < 4; ++p) {
            int row = p * 32 + crow;
            int sc  = (cc ^ (row & 7)) << 3;
            short* lb = &Bs[(p * 32 + wave * 8) * 64];
            gload16(Wt + (size_t)(col0 + row) * K + k0 + sc, lb);
        }
        __syncthreads();
#pragma unroll
        for (int s = 0; s < 2; ++s) {
            short8 af[FI], bf[4];
#pragma unroll
            for (int f = 0; f < FI; ++f) {
                int m = wm + f * 16 + lr;
                af[f] = *(const short8*)&As[(m * 8 + ((s * 4 + q) ^ (m & 7))) * 8];
            }
#pragma unroll
            for (int f = 0; f < 4; ++f) {
                int n = wn + f * 16 + lr;
                bf[f] = *(const short8*)&Bs[(n * 8 + ((s * 4 + q) ^ (n & 7))) * 8];
            }
            // swapped operands: acc[i][j] = C^T frag; lane element r is
            // C[token = row0+wm+i*16+lr][col = col0+wn+j*16+q*4+r]
#pragma unroll
            for (int i = 0; i < FI; ++i)
#pragma unroll
                for (int j = 0; j < 4; ++j)
                    acc[i][j] = __builtin_amdgcn_mfma_f32_16x16x32_bf16(
                        bf[j], af[i], acc[i][j], 0, 0, 0);
        }
        __syncthreads();
    }

    // ---- epilogue: bias in-register, LDS repack, coalesced vector stores ----
    float4 b4[4];
#pragma unroll
    for (int j = 0; j < 4; ++j)
        b4[j] = *(const float4*)&bias2[col0 + wn + j * 16 + q * 4];

    if constexpr (MODE == 3 || MODE == 5) {
        // bf16 output: BM x 128 bf16 tile, 16B-chunk XOR swizzle
        const bool qsc = (MODE == 5) && (col0 == 0);
#pragma unroll
        for (int i = 0; i < FI; ++i) {
            int trow = wm + i * 16 + lr;
#pragma unroll
            for (int j = 0; j < 4; ++j) {
                int cb = wn + j * 16 + q * 4;
                float v0 = acc[i][j][0] + b4[j].x;
                float v1 = acc[i][j][1] + b4[j].y;
                float v2 = acc[i][j][2] + b4[j].z;
                float v3 = acc[i][j][3] + b4[j].w;
                if constexpr (MODE == 3) {
                    v0 = gelu_f(v0); v1 = gelu_f(v1);
                    v2 = gelu_f(v2); v3 = gelu_f(v3);
                }
                if (qsc) { v0 *= QSCALE; v1 *= QSCALE; v2 *= QSCALE; v3 *= QSCALE; }
                uint2 pk = {pkbf(v0, v1), pkbf(v2, v3)};
                int ch = cb >> 3;
                *(uint2*)((char*)smem + trow * 256 + ((ch ^ (trow & 7)) << 4)
                          + ((cb & 7) << 1)) = pk;
            }
        }
        __syncthreads();
        __hip_bfloat16* outb = (__hip_bfloat16*)Cout;
        constexpr int TPR = 256 / BM;                // threads per row (2 or 4)
        constexpr int CPT = 16 / TPR;                // chunks per thread (8 or 4)
        int rrow = tid / TPR;
        if constexpr (MODE == 3) {
            size_t rb = (size_t)(row0 + rrow) * N + col0;
#pragma unroll
            for (int u = 0; u < CPT; ++u) {
                int c = (tid % TPR) * CPT + u;
                uint4 d = *(const uint4*)((char*)smem + rrow * 256
                                          + ((c ^ (rrow & 7)) << 4));
                *(uint4*)(outb + rb + c * 8) = d;
            }
        } else {
            size_t pbase = (size_t)(col0 >> 7) * 8 * BT * 16;
#pragma unroll
            for (int u = 0; u < CPT; ++u) {
                int c = (tid % TPR) * CPT + u;           // h = c>>1, dblk = c&1
                uint4 d = *(const uint4*)((char*)smem + rrow * 256
                                          + ((c ^ (rrow & 7)) << 4));
                size_t dst = pbase + ((size_t)(c >> 1) * BT + row0 + rrow) * 16
                           + (c & 1) * 8;
                *(uint4*)(outb + dst) = d;
            }
        }
    } else {
        // f32 output: 64-row half-tiles ([64][128] f32 = 32 KB), BM/64 passes
        float* outf = (float*)Cout;
        constexpr int HP = BM / 64;
        for (int h = 0; h < HP; ++h) {
            if (HP == 1 || (wm >> 6) == h) {
#pragma unroll
                for (int i = 0; i < FI; ++i) {
                    int trow = (wm & 63) + i * 16 + lr;
#pragma unroll
                    for (int j = 0; j < 4; ++j) {
                        int cb = wn + j * 16 + q * 4;
                        f32x4 v = acc[i][j];
                        v[0] += b4[j].x; v[1] += b4[j].y;
                        v[2] += b4[j].z; v[3] += b4[j].w;
                        int ch = cb >> 2;
                        *(f32x4*)((char*)smem + trow * 512
                                  + ((ch ^ (trow & 7)) << 4)) = v;
                    }
                }
            }
            __syncthreads();
            {
                int rrow = tid >> 2;                     // 0..63
                int grow = row0 + h * 64 + rrow;
                float aw = (MODE == 4) ? awt[grow] : 1.f;
                size_t rb = (size_t)grow * N + col0;
#pragma unroll
                for (int u = 0; u < 8; ++u) {
                    int c = (tid & 3) * 8 + u;
                    f32x4 d = *(const f32x4*)((char*)smem + rrow * 512
                                              + ((c ^ (rrow & 7)) << 4));
                    int gcol = col0 + c * 4;
                    if constexpr (MODE == 0) {
                        float4 p = *(const float4*)&extra[(grow & 511) * 128 + gcol];
                        d[0] += p.x; d[1] += p.y; d[2] += p.z; d[3] += p.w;
                    } else if constexpr (MODE == 2) {
                        float4 p = *(const float4*)&extra[rb + c * 4];
                        d[0] += p.x; d[1] += p.y; d[2] += p.z; d[3] += p.w;
                    } else if constexpr (MODE == 4) {
                        d[0] *= aw; d[1] *= aw; d[2] *= aw; d[3] *= aw;
                    }
                    *(f32x4*)&outf[rb + c * 4] = d;
                }
            }
            __syncthreads();
        }
    }
}

// ---------------------------------------------------------------------------
// 4. LayerNorm over D=128 -> bf16 zbf (layer-0 ln1 only)
// ---------------------------------------------------------------------------
__global__ __launch_bounds__(256) void ln_kernel(const float* __restrict__ x,
                                                 const float* __restrict__ g,
                                                 const float* __restrict__ b,
                                                 __hip_bfloat16* __restrict__ zbf) {
    int wave = threadIdx.x >> 6, lane = threadIdx.x & 63;
    size_t row = (size_t)blockIdx.x * 4 + wave;
    const float* xr = x + row * 128;
    float a0 = xr[lane], a1 = xr[lane + 64];
    float s = a0 + a1;
#pragma unroll
    for (int off = 32; off > 0; off >>= 1) s += __shfl_xor(s, off);
    float mean = s * (1.f / 128.f);
    float d0 = a0 - mean, d1 = a1 - mean;
    float v = d0 * d0 + d1 * d1;
#pragma unroll
    for (int off = 32; off > 0; off >>= 1) v += __shfl_xor(v, off);
    float inv = rsqrtf(v * (1.f / 128.f) + 1e-5f);
    zbf[row * 128 + lane]      = __float2bfloat16(d0 * inv * g[lane] + b[lane]);
    zbf[row * 128 + lane + 64] = __float2bfloat16(d1 * inv * g[lane + 64] + b[lane + 64]);
}

// ---------------------------------------------------------------------------
// 5. MFMA flash attention v3 — shuffle-free PV + 512 threads (8 waves).
//    qkv is head-major [part][h][token][16] -> fully coalesced staging.
// ---------------------------------------------------------------------------
__global__ __launch_bounds__(512) void attn_kernel(const __hip_bfloat16* __restrict__ qkv,
                                                   __hip_bfloat16* __restrict__ o) {
    __shared__ short Ks[512 * 24];    // K [key][16 used, 24 pitch] : 24 KB
    __shared__ short Vt[17 * 520];    // V^T [col 0..15, 16=ones][key, 520 pitch]
    const int b = blockIdx.z, hh = blockIdx.y, half = blockIdx.x;
    const int tid = threadIdx.x;
    const __hip_bfloat16* Qh = qkv + ((size_t)(0 * 8 + hh) * BT + b * 512) * 16;
    const __hip_bfloat16* Kh = qkv + ((size_t)(1 * 8 + hh) * BT + b * 512) * 16;
    const __hip_bfloat16* Vh = qkv + ((size_t)(2 * 8 + hh) * BT + b * 512) * 16;

    {
        int r = tid;   // 512 threads, 512 keys; 32B/lane contiguous reads
        const uint4* ksrc = (const uint4*)(Kh + (size_t)r * 16);
        uint4 k0 = ksrc[0], k1 = ksrc[1];
        *(uint4*)&Ks[r * 24 + 0] = k0;
        *(uint4*)&Ks[r * 24 + 8] = k1;
        const uint4* vsrc = (const uint4*)(Vh + (size_t)r * 16);
        uint4 v0 = vsrc[0], v1 = vsrc[1];
        unsigned vv[8] = {v0.x, v0.y, v0.z, v0.w, v1.x, v1.y, v1.z, v1.w};
#pragma unroll
        for (int c = 0; c < 8; ++c) {
            Vt[(2 * c)     * 520 + r] = (short)(vv[c] & 0xffff);
            Vt[(2 * c + 1) * 520 + r] = (short)(vv[c] >> 16);
        }
        Vt[16 * 520 + r] = (short)0x3F80;   // 1.0 bf16
    }
    __syncthreads();

    const int wave = tid >> 6, lane = tid & 63;
    const int lm = lane & 31, lh = lane >> 5;
    const int qrow0 = half * 256 + wave * 32;

    short8 qf = *(const short8*)(Qh + (size_t)(qrow0 + lm) * 16 + lh * 8);

    f32x16 accO;
#pragma unroll
    for (int r = 0; r < 16; ++r) accO[r] = 0.f;

    for (int kc = 0; kc < 16; ++kc) {
        short8 kf = *(const short8*)&Ks[(kc * 32 + lm) * 24 + lh * 8];
        int vr = (lm < 16) ? lm : 16;
        const short* vb2 = &Vt[vr * 520 + kc * 32];
        short4v va  = *(const short4v*)(vb2 + 4 * lh);
        short4v vbq = *(const short4v*)(vb2 + 8 + 4 * lh);
        short4v vc  = *(const short4v*)(vb2 + 16 + 4 * lh);
        short4v vd  = *(const short4v*)(vb2 + 24 + 4 * lh);
        short8 vf0, vf1;
#pragma unroll
        for (int j = 0; j < 4; ++j) {
            vf0[j] = va[j];  vf0[4 + j] = vbq[j];
            vf1[j] = vc[j];  vf1[4 + j] = vd[j];
        }
        f32x16 st;
#pragma unroll
        for (int r = 0; r < 16; ++r) st[r] = 0.f;
        st = __builtin_amdgcn_mfma_f32_32x32x16_bf16(kf, qf, st, 0, 0, 0);
        short8 pf0, pf1;
#pragma unroll
        for (int r = 0; r < 8; ++r) {
            pf0[r] = (short)(__float_as_uint(exp2f(st[r]))     >> 16);
            pf1[r] = (short)(__float_as_uint(exp2f(st[8 + r])) >> 16);
        }
        accO = __builtin_amdgcn_mfma_f32_32x32x16_bf16(pf0, vf0, accO, 0, 0, 0);
        accO = __builtin_amdgcn_mfma_f32_32x32x16_bf16(pf1, vf1, accO, 0, 0, 0);
    }

#pragma unroll
    for (int r = 0; r < 16; ++r) {
        float val = accO[r];
        float s = __shfl(val, (lane & 32) + 16);
        if (lm < 16) {
            int qr = qrow0 + (r & 3) + 8 * (r >> 2) + 4 * lh;
            o[((size_t)b * 512 + qr) * 128 + hh * 16 + lm] = __float2bfloat16(val / s);
        }
    }
}

// ---------------------------------------------------------------------------
// 6. Fused LN2 + router + offsets (R19): atomics spread over 64 slots, then
//    atomic-ticket last block (pattern proven in R16) reduces slots, writes
//    moff/fill/aux, and re-zeroes slots+ticket for the next layer. Removes
//    the per-layer offsets_kernel AND the 4KB memset dispatch.
// ---------------------------------------------------------------------------
__global__ __launch_bounds__(256) void ln2gate_kernel(
    const float* __restrict__ x, const float* __restrict__ g, const float* __restrict__ b,
    const float* __restrict__ gW, __hip_bfloat16* __restrict__ zbf,
    int* __restrict__ topi, float* __restrict__ topw,
    float* __restrict__ impS, int* __restrict__ cntS,
    int* __restrict__ ticket, int* __restrict__ moffw, int* __restrict__ fill,
    float* __restrict__ aux)
{
    __shared__ float simp[8];
    __shared__ int scnt[8];
    __shared__ int lastf;
    __shared__ int csh[8];
    __shared__ float ish[8];
    const int tid = threadIdx.x;
    if (tid < 8) { simp[tid] = 0.f; scnt[tid] = 0; }
    __syncthreads();
    const int wave = tid >> 6, lane = tid & 63;
    const size_t row = (size_t)blockIdx.x * 4 + wave;
    const float* xr = x + row * 128;
    float a0 = xr[lane], a1 = xr[lane + 64];
    float s = a0 + a1;
#pragma unroll
    for (int off = 32; off > 0; off >>= 1) s += __shfl_xor(s, off);
    float mean = s * (1.f / 128.f);
    float d0 = a0 - mean, d1 = a1 - mean;
    float v = d0 * d0 + d1 * d1;
#pragma unroll
    for (int off = 32; off > 0; off >>= 1) v += __shfl_xor(v, off);
    float inv = rsqrtf(v * (1.f / 128.f) + 1e-5f);
    float o0 = d0 * inv * g[lane] + b[lane];
    float o1 = d1 * inv * g[lane + 64] + b[lane + 64];
    zbf[row * 128 + lane]      = __float2bfloat16(o0);
    zbf[row * 128 + lane + 64] = __float2bfloat16(o1);
    // router logits: lg[e] = sum_d z[d]*gW[d][e]
    float4 gA = *(const float4*)&gW[lane * 8];
    float4 gB = *(const float4*)&gW[lane * 8 + 4];
    float4 gC = *(const float4*)&gW[(lane + 64) * 8];
    float4 gD = *(const float4*)&gW[(lane + 64) * 8 + 4];
    float lg[8];
    lg[0] = o0 * gA.x + o1 * gC.x;  lg[1] = o0 * gA.y + o1 * gC.y;
    lg[2] = o0 * gA.z + o1 * gC.z;  lg[3] = o0 * gA.w + o1 * gC.w;
    lg[4] = o0 * gB.x + o1 * gD.x;  lg[5] = o0 * gB.y + o1 * gD.y;
    lg[6] = o0 * gB.z + o1 * gD.z;  lg[7] = o0 * gB.w + o1 * gD.w;
#pragma unroll
    for (int e = 0; e < 8; ++e)
#pragma unroll
        for (int off = 32; off > 0; off >>= 1) lg[e] += __shfl_xor(lg[e], off);
    if (lane == 0) {
        float p[8];
        float mx = lg[0];
#pragma unroll
        for (int k = 1; k < 8; ++k) mx = fmaxf(mx, lg[k]);
        float ssum = 0.f;
#pragma unroll
        for (int k = 0; k < 8; ++k) { p[k] = expf(lg[k] - mx); ssum += p[k]; }
        float pinv = 1.f / ssum;
#pragma unroll
        for (int k = 0; k < 8; ++k) p[k] *= pinv;
        int i0 = 0; float v0 = p[0];
#pragma unroll
        for (int k = 1; k < 8; ++k) if (p[k] > v0) { v0 = p[k]; i0 = k; }
        int i1 = -1; float v1 = -1.f;
#pragma unroll
        for (int k = 0; k < 8; ++k) if (k != i0 && p[k] > v1) { v1 = p[k]; i1 = k; }
        float wsum = v0 + v1;
        topi[row * 2] = i0;  topi[row * 2 + 1] = i1;
        topw[row * 2] = v0 / wsum;  topw[row * 2 + 1] = v1 / wsum;
#pragma unroll
        for (int k = 0; k < 8; ++k) atomicAdd(&simp[k], p[k]);
        atomicAdd(&scnt[i0], 1); atomicAdd(&scnt[i1], 1);
    }
    __syncthreads();
    if (tid < 8) {
        int slot = (blockIdx.x & 63) * 8 + tid;
        atomicAdd(&impS[slot], simp[tid]);
        atomicAdd(&cntS[slot], scnt[tid]);
    }
    __syncthreads();                 // all slot atomics of this block complete
    if (tid == 0) {
        __threadfence();
        int t = atomicAdd(ticket, 1);
        lastf = (t == (int)(gridDim.x - 1)) ? 1 : 0;
    }
    __syncthreads();
    if (lastf) {
        // reduce 64x8 slots (volatile: bypass L1; values are L2-coherent atomics)
        if (tid < 64) {
            const int e2 = tid & 7, grp = tid >> 3;     // 8 groups x 8 experts
            int c = 0; float im = 0.f;
            for (int gg = 0; gg < 8; ++gg) {
                int sl = grp * 8 + gg;
                c  += *(volatile const int*)&cntS[sl * 8 + e2];
                im += *(volatile const float*)&impS[sl * 8 + e2];
            }
#pragma unroll
            for (int off2 = 32; off2 >= 8; off2 >>= 1) {  // all lanes active
                c  += __shfl_down(c, off2);
                im += __shfl_down(im, off2);
            }
            if (tid < 8) { csh[tid] = c; ish[tid] = im; }
        }
        __syncthreads();
        if (tid == 0) {
            int t2 = 0; float s2 = 0.f;
            for (int k = 0; k < 8; ++k) {
                int ck = csh[k];
                moffw[k] = t2; fill[k] = t2;
                moffw[9 + k] = ck;
                t2 += (ck + 127) & ~127;
                s2 += (ish[k] * (1.f / 16384.f)) * ((float)ck * (1.f / 16384.f));
            }
            moffw[8] = t2;
            aux[0] += 8.f * s2;
            *ticket = 0;                       // reset for next layer
        }
        // re-zero slots for next layer's atomics
        for (int u = tid; u < 512; u += 256) {
            cntS[u] = 0;
            impS[u] = 0.f;
        }
    }
}

// ---------------------------------------------------------------------------
// 8. Scatter tokens into expert-contiguous slots — LDS-aggregated atomics.
// ---------------------------------------------------------------------------
__global__ __launch_bounds__(256) void scatter_kernel(const int* __restrict__ topi,
                                                      const float* __restrict__ topw,
                                                      int* __restrict__ fill, int* __restrict__ atok,
                                                      float* __restrict__ awt, int* __restrict__ tokpos) {
    __shared__ int lcnt[8];
    __shared__ int lbase[8];
    const int tid = threadIdx.x;
    const int token = blockIdx.x * 256 + tid;
    if (tid < 8) lcnt[tid] = 0;
    __syncthreads();
    const int e0 = topi[token * 2], e1 = topi[token * 2 + 1];
    const float w0 = topw[token * 2], w1 = topw[token * 2 + 1];
    const int l0 = atomicAdd(&lcnt[e0], 1);
    const int l1 = atomicAdd(&lcnt[e1], 1);     // e1 != e0 (top-2 distinct)
    __syncthreads();
    if (tid < 8) lbase[tid] = atomicAdd(&fill[tid], lcnt[tid]);
    __syncthreads();
    const int p0 = lbase[e0] + l0;
    const int p1 = lbase[e1] + l1;
    atok[p0] = token;  awt[p0] = w0;  tokpos[token * 2]     = p0;
    atok[p1] = token;  awt[p1] = w1;  tokpos[token * 2 + 1] = p1;
}

// ---------------------------------------------------------------------------
// 9. Fused combine + next-layer LN1: h += expert outputs; optional LN -> zbf
// ---------------------------------------------------------------------------
__global__ __launch_bounds__(256) void combine_ln_kernel(
    const float* __restrict__ yw, const int* __restrict__ tokpos,
    float* __restrict__ h, const float* __restrict__ g, const float* __restrict__ b,
    __hip_bfloat16* __restrict__ zbf)
{
    const int tid = threadIdx.x;
    const int wave = tid >> 6, lane = tid & 63;
    const size_t row = (size_t)blockIdx.x * 4 + wave;
    const int p0 = tokpos[row * 2], p1 = tokpos[row * 2 + 1];
    float a0 = h[row * 128 + lane]      + yw[(size_t)p0 * 128 + lane]
             + yw[(size_t)p1 * 128 + lane];
    float a1 = h[row * 128 + lane + 64] + yw[(size_t)p0 * 128 + lane + 64]
             + yw[(size_t)p1 * 128 + lane + 64];
    h[row * 128 + lane]      = a0;
    h[row * 128 + lane + 64] = a1;
    if (zbf) {
        float s = a0 + a1;
#pragma unroll
        for (int off = 32; off > 0; off >>= 1) s += __shfl_xor(s, off);
        float mean = s * (1.f / 128.f);
        float d0 = a0 - mean, d1 = a1 - mean;
        float v = d0 * d0 + d1 * d1;
#pragma unroll
        for (int off = 32; off > 0; off >>= 1) v += __shfl_xor(v, off);
        float inv = rsqrtf(v * (1.f / 128.f) + 1e-5f);
        zbf[row * 128 + lane]      = __float2bfloat16(d0 * inv * g[lane] + b[lane]);
        zbf[row * 128 + lane + 64] = __float2bfloat16(d1 * inv * g[lane + 64] + b[lane + 64]);
    }
}

// ---------------------------------------------------------------------------
// 10. mean over T -> LN -> head matmul [128,2]; writes aux scalar
// ---------------------------------------------------------------------------
__global__ __launch_bounds__(1024) void head_kernel(const float* __restrict__ h,
                                                    const float* __restrict__ g,
                                                    const float* __restrict__ bb,
                                                    const float* __restrict__ hW,
                                                    const float* __restrict__ hb,
                                                    const float* __restrict__ aux,
                                                    float* __restrict__ out) {
    __shared__ float part[8][128];
    __shared__ float red[128];
    __shared__ float pl[128];
    int b = blockIdx.x, tid = threadIdx.x;
    int c = tid & 127, w = tid >> 7;            // w = 0..7
    float s = 0.f;
    for (int t = w; t < 512; t += 8) s += h[((size_t)b * 512 + t) * 128 + c];
    part[w][c] = s;
    __syncthreads();
    float pooled = 0.f;
    if (tid < 128) {
#pragma unroll
        for (int k = 0; k < 8; ++k) pooled += part[k][tid];
        pooled *= (1.f / 512.f);
        red[tid] = pooled;
    }
    __syncthreads();
    for (int st = 64; st > 0; st >>= 1) { if (tid < st) red[tid] += red[tid + st]; __syncthreads(); }
    float mean = red[0] * (1.f / 128.f);
    __syncthreads();
    float d = pooled - mean;
    if (tid < 128) red[tid] = d * d;
    __syncthreads();
    for (int st = 64; st > 0; st >>= 1) { if (tid < st) red[tid] += red[tid + st]; __syncthreads(); }
    float var = red[0] * (1.f / 128.f);
    if (tid < 128) pl[tid] = d / sqrtf(var + 1e-5f) * g[tid] + bb[tid];
    __syncthreads();
    if (tid < 2) {
        float acc = hb[tid];
        for (int k = 0; k < 128; ++k) acc += pl[k] * hW[k * 2 + tid];
        out[b * 2 + tid] = acc;
    }
    if (b == 0 && tid == 0) out[64] = aux[0];
}

// ---------------------------------------------------------------------------
extern "C" void kernel_launch(void* const* d_in, const int* in_sizes, int n_in,
                              void* d_out, int out_size, void* d_ws, size_t ws_size,
                              hipStream_t stream) {
    (void)in_sizes; (void)n_in; (void)out_size; (void)ws_size;
    const float* x      = (const float*)d_in[0];
    const float* proj_W = (const float*)d_in[1];
    const float* proj_b = (const float*)d_in[2];
    const float* pos    = (const float*)d_in[3];
    const float* ln1_g  = (const float*)d_in[4];
    const float* ln1_b  = (const float*)d_in[5];
    const float* qkv_W  = (const float*)d_in[6];
    const float* qkv_b  = (const float*)d_in[7];
    const float* out_W  = (const float*)d_in[8];
    const float* out_b  = (const float*)d_in[9];
    const float* ln2_g  = (const float*)d_in[10];
    const float* ln2_b  = (const float*)d_in[11];
    const float* gate_W = (const float*)d_in[12];
    const float* w1     = (const float*)d_in[13];
    const float* b1     = (const float*)d_in[14];
    const float* w2     = (const float*)d_in[15];
    const float* b2     = (const float*)d_in[16];
    const float* hl_g   = (const float*)d_in[17];
    const float* hl_b   = (const float*)d_in[18];
    const float* head_W = (const float*)d_in[19];
    const float* head_b = (const float*)d_in[20];
    float* outp = (float*)d_out;

    // workspace layout (float granularity)
    float* ws = (float*)d_ws;
    size_t off = 0;
    auto alloc = [&](size_t n) { float* p = ws + off; off += (n + 63) & ~(size_t)63; return p; };
    float* hidbf_f = alloc((size_t)MAXASSIGN * 256);  // bf16 hid; aliases xtb
    float* h       = alloc((size_t)BT * 128);
    float* zbf_f   = alloc((size_t)(BT + 1) * 64);    // bf16 [16385][128], row BT = zeros
    float* qkvbf_f = alloc((size_t)BT * 192);         // bf16 head-major [3][8][BT][16]
    float* obbf_f  = alloc((size_t)BT * 64);          // bf16 [16384][128]
    float* yw      = alloc((size_t)MAXASSIGN * 128);  // f32
    float* projWt_f= alloc(128 * 448 / 2);
    float* qkvWt_f = alloc(4 * 384 * 128 / 2);
    float* outWt_f = alloc(4 * 128 * 128 / 2);
    float* w1t_f   = alloc((size_t)32 * 512 * 128 / 2);
    float* w2t_f   = alloc((size_t)32 * 128 * 512 / 2);
    float* topw    = alloc(32768);
    float* awt     = alloc(MAXASSIGN);
    float* impc    = alloc(1024);                     // impS[64][8] f32 + cntS[64][8] i32
    float* auxp    = alloc(2);                        // aux f32 + ticket i32
    int* topi      = (int*)alloc(32768);
    int* atok      = (int*)alloc(MAXASSIGN);
    int* tokpos    = (int*)alloc(32768);
    int* moff      = (int*)alloc(32);
    int* fill      = (int*)alloc(8);
    float* impS    = impc;
    int*   cntS    = (int*)(impc + 512);
    int*   ticket  = (int*)(auxp + 1);

    __hip_bfloat16* hidbf  = (__hip_bfloat16*)hidbf_f;
    __hip_bfloat16* xtb    = (__hip_bfloat16*)hidbf_f;   // alias: dead after proj
    __hip_bfloat16* zbf    = (__hip_bfloat16*)zbf_f;
    __hip_bfloat16* qkvbf  = (__hip_bfloat16*)qkvbf_f;
    __hip_bfloat16* obbf   = (__hip_bfloat16*)obbf_f;
    __hip_bfloat16* projWt = (__hip_bfloat16*)projWt_f;
    __hip_bfloat16* qkvWt  = (__hip_bfloat16*)qkvWt_f;
    __hip_bfloat16* outWt  = (__hip_bfloat16*)outWt_f;
    __hip_bfloat16* w1t    = (__hip_bfloat16*)w1t_f;
    __hip_bfloat16* w2t    = (__hip_bfloat16*)w2t_f;

    hipMemsetAsync(auxp, 0, 8, stream);                              // aux + ticket
    hipMemsetAsync(impc, 0, 4096, stream);                           // slots (layer 0)
    hipMemsetAsync((char*)zbf + (size_t)BT * 256, 0, 256, stream);   // zero gather row

    // input transpose + weight conversion (once per call)
    transpose_kernel<<<256, 256, 0, stream>>>(x, xtb);
    projconv_kernel<<<224, 256, 0, stream>>>(proj_W, projWt);
    wconvt_kernel<<<48, 256, 0, stream>>>(qkv_W, qkvWt, 128, 384);
    wconvt_kernel<<<16, 256, 0, stream>>>(out_W, outWt, 128, 128);
    wconvt_kernel<<<512, 256, 0, stream>>>(w1, w1t, 128, 512);
    wconvt_kernel<<<512, 256, 0, stream>>>(w2, w2t, 512, 128);

    // proj: h = xtb @ projWt^T + proj_b + pos  (K=448)
    mm_kernel<0, 64><<<dim3(256, 1), 256, 0, stream>>>(
        xtb, projWt, proj_b, pos, h, 448, 128, 0, nullptr, nullptr, nullptr);
    // layer-0 ln1 (subsequent ln1's are fused into combine_ln)
    ln_kernel<<<4096, 256, 0, stream>>>(h, ln1_g, ln1_b, zbf);

    for (int i = 0; i < 4; ++i) {
        // qkv -> bf16 head-major, Q pre-scaled
        mm_kernel<5, 64><<<dim3(256, 3), 256, 0, stream>>>(
            zbf, qkvWt + (size_t)i * 384 * 128, qkv_b + i * 384, nullptr, qkvbf,
            128, 384, 0, nullptr, nullptr, nullptr);
        attn_kernel<<<dim3(2, 8, 32), 512, 0, stream>>>(qkvbf, obbf);
        mm_kernel<2, 64><<<dim3(256, 1), 256, 0, stream>>>(
            obbf, outWt + (size_t)i * 128 * 128, out_b + i * 128, h, h,
            128, 128, 0, nullptr, nullptr, nullptr);
        // LN2 + router + top-k + fused offsets (ticket last-block)
        ln2gate_kernel<<<4096, 256, 0, stream>>>(h, ln2_g + i * 128, ln2_b + i * 128,
                                                 gate_W + (size_t)i * 128 * 8, zbf,
                                                 topi, topw, impS, cntS,
                                                 ticket, moff, fill, auxp);
        scatter_kernel<<<64, 256, 0, stream>>>(topi, topw, fill, atok, awt, tokpos);
        // moe1: hid = gelu(gather(zbf) @ w1t^T + b1)  -> bf16
        mm_kernel<3, 128><<<dim3(264, 4), 256, 0, stream>>>(
            zbf, w1t + (size_t)i * 8 * 512 * 128, b1 + (size_t)i * 8 * 512, nullptr,
            hidbf, 128, 512, 512 * 128, moff, atok, awt);
        // moe2: yw = (hid @ w2t^T + b2) * awt  -> f32
        mm_kernel<4, 64><<<dim3(528, 1), 256, 0, stream>>>(
            hidbf, w2t + (size_t)i * 8 * 128 * 512, b2 + (size_t)i * 8 * 128, nullptr,
            yw, 512, 128, 128 * 512, moff, atok, awt);
        // combine + next-layer ln1 (fused); last layer: no LN
        combine_ln_kernel<<<4096, 256, 0, stream>>>(yw, tokpos, h,
                                                    ln1_g + (i + 1 < 4 ? (i + 1) * 128 : 0),
                                                    ln1_b + (i + 1 < 4 ? (i + 1) * 128 : 0),
                                                    (i < 3) ? zbf : (__hip_bfloat16*)nullptr);
    }
    head_kernel<<<32, 1024, 0, stream>>>(h, hl_g, hl_b, head_W, head_b, auxp, outp);
}

// Round 9
// 648.005 us; speedup vs baseline: 1.5255x; 1.5255x over previous
//
#include <hip/hip_runtime.h>
#include <hip/hip_bf16.h>
#include <cstdint>
#include <cstddef>

// ---------------------------------------------------------------------------
// Model constants
// ---------------------------------------------------------------------------
#define BT        16384          // B*T tokens
#define MAXASSIGN 33792          // 32768 + 8*127 rounded to 128-aligned segments
#define QSCALE    0.36067376022224085f   // 0.25 * log2(e): fold 1/sqrt(dh) + exp->exp2

typedef __attribute__((ext_vector_type(8)))  short short8;   // 8 bf16 = 1 MFMA frag
typedef __attribute__((ext_vector_type(4)))  short short4v;
typedef __attribute__((ext_vector_type(4)))  float f32x4;
typedef __attribute__((ext_vector_type(16))) float f32x16;

typedef const uint32_t __attribute__((address_space(1))) gas_u32;
typedef uint32_t __attribute__((address_space(3))) las_u32;

// async global->LDS direct copy, 16B per lane; LDS dest = wave base + lane*16
__device__ __forceinline__ void gload16(const void* g, void* l) {
    __builtin_amdgcn_global_load_lds((gas_u32*)g, (las_u32*)l, 16, 0, 0);
}

// gelu(x) = 0.5x(1+tanh(u)) = x*sigmoid(2u), u = sqrt(2/pi)(x+0.044715x^3).
__device__ __forceinline__ float gelu_f(float x) {
    float u2l = (x + 0.044715f * x * x * x) * 2.3022081927f;   // 2u*log2(e)
    float e = exp2f(u2l);
    float r = __builtin_amdgcn_rcpf(e + 1.0f);
    return x * e * r;
}

// pack 2 floats -> 1 u32 of 2 bf16 (RNE), a = low half
__device__ __forceinline__ unsigned pkbf(float a, float b) {
    __hip_bfloat16 ha = __float2bfloat16(a);
    __hip_bfloat16 hb = __float2bfloat16(b);
    unsigned short ua = *reinterpret_cast<unsigned short*>(&ha);
    unsigned short ub = *reinterpret_cast<unsigned short*>(&hb);
    return (unsigned)ua | ((unsigned)ub << 16);
}

// ---------------------------------------------------------------------------
// 1. x [32,55,512,8] -> xtb [16384][448] bf16 (cols 440..447 zero-padded)
// ---------------------------------------------------------------------------
__global__ __launch_bounds__(256) void transpose_kernel(const float* __restrict__ x,
                                                        __hip_bfloat16* __restrict__ xtb) {
    __shared__ unsigned tile[64][228];   // [t][packed bf16-pair col]; pad 224->228
    const int b  = blockIdx.x >> 3;      // 32 batches
    const int t0 = (blockIdx.x & 7) * 64;
    const int tid = threadIdx.x;
    tile[tid >> 2][220 + (tid & 3)] = 0u;
    const int tt  = tid >> 2;            // 0..63  (t within tile)
    const int ncp = tid & 3;             // bf16-pair within nb block
    for (int nb = 0; nb < 55; ++nb) {
        const float2* src = (const float2*)(x + (((size_t)(b * 55 + nb)) * 512 + t0) * 8);
        float2 v = src[tid];             // 256 float2 = 64t x 8nc, contiguous
        tile[tt][nb * 4 + ncp] = pkbf(v.x, v.y);
    }
    __syncthreads();
#pragma unroll
    for (int u = 0; u < 14; ++u) {
        int idx = u * 256 + tid;
        int t = idx / 56, c = idx % 56;
        *(uint4*)(xtb + ((size_t)b * 512 + t0 + t) * 448 + c * 8) =
            *(const uint4*)&tile[t][c * 4];
    }
}

// ---------------------------------------------------------------------------
// 2. Weight convert+transpose via LDS tile: out[b][n][k] = bf16(in[b][k][n])
// ---------------------------------------------------------------------------
__global__ __launch_bounds__(256) void wconvt_kernel(const float* __restrict__ in,
                                                     __hip_bfloat16* __restrict__ out,
                                                     int K, int N) {
    __shared__ float tile[64][65];
    const int kt = K >> 6, nt = N >> 6;
    const int per = kt * nt;
    const int bb  = blockIdx.x / per;
    const int rem = blockIdx.x % per;
    const int k0  = (rem / nt) << 6;
    const int n0  = (rem % nt) << 6;
    const int tid = threadIdx.x;

    const float* src = in + ((size_t)bb * K + k0) * N + n0;
    int tk = tid >> 4;               // 0..15
    int tn = (tid & 15) * 4;         // 0..60
#pragma unroll
    for (int r = 0; r < 4; ++r) {
        float4 v = *(const float4*)(src + (size_t)(tk + r * 16) * N + tn);
        tile[tk + r * 16][tn]     = v.x;
        tile[tk + r * 16][tn + 1] = v.y;
        tile[tk + r * 16][tn + 2] = v.z;
        tile[tk + r * 16][tn + 3] = v.w;
    }
    __syncthreads();
    int on = tid >> 2;               // 0..63
    int ok = (tid & 3) * 16;         // 0,16,32,48
    unsigned pk[8];
#pragma unroll
    for (int u = 0; u < 8; ++u)
        pk[u] = pkbf(tile[ok + 2 * u][on], tile[ok + 2 * u + 1][on]);
    uint4* dst = (uint4*)(out + ((size_t)bb * N + n0 + on) * K + k0 + ok);
    dst[0] = (uint4){pk[0], pk[1], pk[2], pk[3]};
    dst[1] = (uint4){pk[4], pk[5], pk[6], pk[7]};
}

// proj_W [440][128] -> projWt [128][448] bf16 with zero pad k>=440 (tiny)
__global__ __launch_bounds__(256) void projconv_kernel(const float* __restrict__ in,
                                                       __hip_bfloat16* __restrict__ out) {
    int idx = blockIdx.x * 256 + threadIdx.x;      // 128*448 exact
    int k = idx % 448, n = idx / 448;
    out[idx] = __float2bfloat16(k < 440 ? in[k * 128 + n] : 0.f);
}

// ---------------------------------------------------------------------------
// 3. bf16 MFMA GEMM, templated <MODE, BM> (per-mode DCE; BM = row-tile).
//    BM=128: 4 waves 2x2, 4x4 frags. BM=64: 2x4 frags -> 2x grid for the
//    latency-bound small GEMMs (proj/qkv/out/moe2 were 128-384 blocks).
//    mfma_f32_16x16x32_bf16, operand-swapped (acc = C^T frags). LDS
//    chunk-XOR swizzle; global_load_lds width-16 linear-dest staging with
//    inverse-swizzled global source. LDS-repack epilogue, coalesced stores.
//    MODE 0: proj, f32 out + pos.   MODE 2: out-proj, f32 residual add.
//    MODE 3: moe1, gathered A (atok), gelu, bf16 out.
//    MODE 4: moe2, f32 out * awt.
//    MODE 5: qkv, bf16 HEAD-MAJOR [part][h][token][16], Q pre-scaled.
// ---------------------------------------------------------------------------
template<int MODE, int BM>
__global__ __launch_bounds__(256) void mm_kernel(
    const __hip_bfloat16* __restrict__ A, const __hip_bfloat16* __restrict__ Wt,
    const float* __restrict__ bias, const float* __restrict__ extra,
    void* __restrict__ Cout, int K, int N, int wstride,
    const int* __restrict__ moff, const int* __restrict__ atok,
    const float* __restrict__ awt)
{
    constexpr int FI = BM / 32;          // A p-groups / frag rows per wave
    __shared__ short smem[16384];        // 32 KB: As|Bs in K-loop, C-tile after
    short* As = smem;                    // BM*64 shorts
    short* Bs = smem + BM * 64;          // 8192 shorts (128x64)
    const int tid  = threadIdx.x;
    const int row0 = blockIdx.x * BM;
    const int col0 = blockIdx.y * 128;

    const float* bias2 = bias;
    int lim = 0;
    if constexpr (MODE == 3 || MODE == 4) {
        if (row0 >= moff[8]) return;             // segments are 128-aligned
        int e = 0;
        while (moff[e + 1] <= row0) ++e;
        Wt    += (size_t)e * wstride;
        bias2  = bias + e * N;
        lim    = moff[e] + moff[9 + e];          // valid-assignment end
    }

    const int wave = tid >> 6, lane = tid & 63;
    const int crow = tid >> 3;   // 0..31  (staging row within p-group)
    const int cc   = tid & 7;    // 0..7   (16B chunk within row)

    int srow[FI];
#pragma unroll
    for (int p = 0; p < FI; ++p) {
        int grow = row0 + p * 32 + crow;
        srow[p] = grow;
        if constexpr (MODE == 3)
            srow[p] = (grow < lim) ? atok[grow] : BT;   // pad -> zeroed row
    }

    f32x4 acc[FI][4];
#pragma unroll
    for (int i = 0; i < FI; ++i)
#pragma unroll
        for (int j = 0; j < 4; ++j) acc[i][j] = (f32x4){0.f, 0.f, 0.f, 0.f};

    const int wm = (wave >> 1) * (BM / 2), wn = (wave & 1) * 64;
    const int lr = lane & 15, q = lane >> 4;

    for (int k0 = 0; k0 < K; k0 += 64) {
#pragma unroll
        for (int p = 0; p < FI; ++p) {
            int row = p * 32 + crow;
            int sc  = (cc ^ (row & 7)) << 3;             // swizzled src chunk
            short* la = &As[(p * 32 + wave * 8) * 64];
            gload16(A + (size_t)srow[p] * K + k0 + sc, la);
        }
#pragma unroll
        for (int p = 0; p < 4; ++p) {
            int row = p * 32 + crow;
            int sc  = (cc ^ (row & 7)) << 3;
            short* lb = &Bs[(p * 32 + wave * 8) * 64];
            gload16(Wt + (size_t)(col0 + row) * K + k0 + sc, lb);
        }
        __syncthreads();
#pragma unroll
        for (int s = 0; s < 2; ++s) {
            short8 af[FI], bf[4];
#pragma unroll
            for (int f = 0; f < FI; ++f) {
                int m = wm + f * 16 + lr;
                af[f] = *(const short8*)&As[(m * 8 + ((s * 4 + q) ^ (m & 7))) * 8];
            }
#pragma unroll
            for (int f = 0; f < 4; ++f) {
                int n = wn + f * 16 + lr;
                bf[f] = *(const short8*)&Bs[(n * 8 + ((s * 4 + q) ^ (n & 7))) * 8];
            }
            // swapped operands: acc[i][j] = C^T frag; lane element r is
            // C[token = row0+wm+i*16+lr][col = col0+wn+j*16+q*4+r]
#pragma unroll
            for (int i = 0; i < FI; ++i)
#pragma unroll
                for (int j = 0; j < 4; ++j)
                    acc[i][j] = __builtin_amdgcn_mfma_f32_16x16x32_bf16(
                        bf[j], af[i], acc[i][j], 0, 0, 0);
        }
        __syncthreads();
    }

    // ---- epilogue: bias in-register, LDS repack, coalesced vector stores ----
    float4 b4[4];
#pragma unroll
    for (int j = 0; j < 4; ++j)
        b4[j] = *(const float4*)&bias2[col0 + wn + j * 16 + q * 4];

    if constexpr (MODE == 3 || MODE == 5) {
        // bf16 output: BM x 128 bf16 tile, 16B-chunk XOR swizzle
        const bool qsc = (MODE == 5) && (col0 == 0);
#pragma unroll
        for (int i = 0; i < FI; ++i) {
            int trow = wm + i * 16 + lr;
#pragma unroll
            for (int j = 0; j < 4; ++j) {
                int cb = wn + j * 16 + q * 4;
                float v0 = acc[i][j][0] + b4[j].x;
                float v1 = acc[i][j][1] + b4[j].y;
                float v2 = acc[i][j][2] + b4[j].z;
                float v3 = acc[i][j][3] + b4[j].w;
                if constexpr (MODE == 3) {
                    v0 = gelu_f(v0); v1 = gelu_f(v1);
                    v2 = gelu_f(v2); v3 = gelu_f(v3);
                }
                if (qsc) { v0 *= QSCALE; v1 *= QSCALE; v2 *= QSCALE; v3 *= QSCALE; }
                uint2 pk = {pkbf(v0, v1), pkbf(v2, v3)};
                int ch = cb >> 3;
                *(uint2*)((char*)smem + trow * 256 + ((ch ^ (trow & 7)) << 4)
                          + ((cb & 7) << 1)) = pk;
            }
        }
        __syncthreads();
        __hip_bfloat16* outb = (__hip_bfloat16*)Cout;
        constexpr int TPR = 256 / BM;                // threads per row (2 or 4)
        constexpr int CPT = 16 / TPR;                // chunks per thread (8 or 4)
        int rrow = tid / TPR;
        if constexpr (MODE == 3) {
            size_t rb = (size_t)(row0 + rrow) * N + col0;
#pragma unroll
            for (int u = 0; u < CPT; ++u) {
                int c = (tid % TPR) * CPT + u;
                uint4 d = *(const uint4*)((char*)smem + rrow * 256
                                          + ((c ^ (rrow & 7)) << 4));
                *(uint4*)(outb + rb + c * 8) = d;
            }
        } else {
            size_t pbase = (size_t)(col0 >> 7) * 8 * BT * 16;
#pragma unroll
            for (int u = 0; u < CPT; ++u) {
                int c = (tid % TPR) * CPT + u;           // h = c>>1, dblk = c&1
                uint4 d = *(const uint4*)((char*)smem + rrow * 256
                                          + ((c ^ (rrow & 7)) << 4));
                size_t dst = pbase + ((size_t)(c >> 1) * BT + row0 + rrow) * 16
                           + (c & 1) * 8;
                *(uint4*)(outb + dst) = d;
            }
        }
    } else {
        // f32 output: 64-row half-tiles ([64][128] f32 = 32 KB), BM/64 passes
        float* outf = (float*)Cout;
        constexpr int HP = BM / 64;
        for (int h = 0; h < HP; ++h) {
            if (HP == 1 || (wm >> 6) == h) {
#pragma unroll
                for (int i = 0; i < FI; ++i) {
                    int trow = (wm & 63) + i * 16 + lr;
#pragma unroll
                    for (int j = 0; j < 4; ++j) {
                        int cb = wn + j * 16 + q * 4;
                        f32x4 v = acc[i][j];
                        v[0] += b4[j].x; v[1] += b4[j].y;
                        v[2] += b4[j].z; v[3] += b4[j].w;
                        int ch = cb >> 2;
                        *(f32x4*)((char*)smem + trow * 512
                                  + ((ch ^ (trow & 7)) << 4)) = v;
                    }
                }
            }
            __syncthreads();
            {
                int rrow = tid >> 2;                     // 0..63
                int grow = row0 + h * 64 + rrow;
                float aw = (MODE == 4) ? awt[grow] : 1.f;
                size_t rb = (size_t)grow * N + col0;
#pragma unroll
                for (int u = 0; u < 8; ++u) {
                    int c = (tid & 3) * 8 + u;
                    f32x4 d = *(const f32x4*)((char*)smem + rrow * 512
                                              + ((c ^ (rrow & 7)) << 4));
                    int gcol = col0 + c * 4;
                    if constexpr (MODE == 0) {
                        float4 p = *(const float4*)&extra[(grow & 511) * 128 + gcol];
                        d[0] += p.x; d[1] += p.y; d[2] += p.z; d[3] += p.w;
                    } else if constexpr (MODE == 2) {
                        float4 p = *(const float4*)&extra[rb + c * 4];
                        d[0] += p.x; d[1] += p.y; d[2] += p.z; d[3] += p.w;
                    } else if constexpr (MODE == 4) {
                        d[0] *= aw; d[1] *= aw; d[2] *= aw; d[3] *= aw;
                    }
                    *(f32x4*)&outf[rb + c * 4] = d;
                }
            }
            __syncthreads();
        }
    }
}

// ---------------------------------------------------------------------------
// 4. LayerNorm over D=128 -> bf16 zbf (layer-0 ln1 only)
// ---------------------------------------------------------------------------
__global__ __launch_bounds__(256) void ln_kernel(const float* __restrict__ x,
                                                 const float* __restrict__ g,
                                                 const float* __restrict__ b,
                                                 __hip_bfloat16* __restrict__ zbf) {
    int wave = threadIdx.x >> 6, lane = threadIdx.x & 63;
    size_t row = (size_t)blockIdx.x * 4 + wave;
    const float* xr = x + row * 128;
    float a0 = xr[lane], a1 = xr[lane + 64];
    float s = a0 + a1;
#pragma unroll
    for (int off = 32; off > 0; off >>= 1) s += __shfl_xor(s, off);
    float mean = s * (1.f / 128.f);
    float d0 = a0 - mean, d1 = a1 - mean;
    float v = d0 * d0 + d1 * d1;
#pragma unroll
    for (int off = 32; off > 0; off >>= 1) v += __shfl_xor(v, off);
    float inv = rsqrtf(v * (1.f / 128.f) + 1e-5f);
    zbf[row * 128 + lane]      = __float2bfloat16(d0 * inv * g[lane] + b[lane]);
    zbf[row * 128 + lane + 64] = __float2bfloat16(d1 * inv * g[lane + 64] + b[lane + 64]);
}

// ---------------------------------------------------------------------------
// 5. MFMA flash attention v3 — shuffle-free PV + 512 threads (8 waves).
//    qkv is head-major [part][h][token][16] -> fully coalesced staging.
// ---------------------------------------------------------------------------
__global__ __launch_bounds__(512) void attn_kernel(const __hip_bfloat16* __restrict__ qkv,
                                                   __hip_bfloat16* __restrict__ o) {
    __shared__ short Ks[512 * 24];    // K [key][16 used, 24 pitch] : 24 KB
    __shared__ short Vt[17 * 520];    // V^T [col 0..15, 16=ones][key, 520 pitch]
    const int b = blockIdx.z, hh = blockIdx.y, half = blockIdx.x;
    const int tid = threadIdx.x;
    const __hip_bfloat16* Qh = qkv + ((size_t)(0 * 8 + hh) * BT + b * 512) * 16;
    const __hip_bfloat16* Kh = qkv + ((size_t)(1 * 8 + hh) * BT + b * 512) * 16;
    const __hip_bfloat16* Vh = qkv + ((size_t)(2 * 8 + hh) * BT + b * 512) * 16;

    {
        int r = tid;   // 512 threads, 512 keys; 32B/lane contiguous reads
        const uint4* ksrc = (const uint4*)(Kh + (size_t)r * 16);
        uint4 k0 = ksrc[0], k1 = ksrc[1];
        *(uint4*)&Ks[r * 24 + 0] = k0;
        *(uint4*)&Ks[r * 24 + 8] = k1;
        const uint4* vsrc = (const uint4*)(Vh + (size_t)r * 16);
        uint4 v0 = vsrc[0], v1 = vsrc[1];
        unsigned vv[8] = {v0.x, v0.y, v0.z, v0.w, v1.x, v1.y, v1.z, v1.w};
#pragma unroll
        for (int c = 0; c < 8; ++c) {
            Vt[(2 * c)     * 520 + r] = (short)(vv[c] & 0xffff);
            Vt[(2 * c + 1) * 520 + r] = (short)(vv[c] >> 16);
        }
        Vt[16 * 520 + r] = (short)0x3F80;   // 1.0 bf16
    }
    __syncthreads();

    const int wave = tid >> 6, lane = tid & 63;
    const int lm = lane & 31, lh = lane >> 5;
    const int qrow0 = half * 256 + wave * 32;

    short8 qf = *(const short8*)(Qh + (size_t)(qrow0 + lm) * 16 + lh * 8);

    f32x16 accO;
#pragma unroll
    for (int r = 0; r < 16; ++r) accO[r] = 0.f;

    for (int kc = 0; kc < 16; ++kc) {
        short8 kf = *(const short8*)&Ks[(kc * 32 + lm) * 24 + lh * 8];
        int vr = (lm < 16) ? lm : 16;
        const short* vb2 = &Vt[vr * 520 + kc * 32];
        short4v va  = *(const short4v*)(vb2 + 4 * lh);
        short4v vbq = *(const short4v*)(vb2 + 8 + 4 * lh);
        short4v vc  = *(const short4v*)(vb2 + 16 + 4 * lh);
        short4v vd  = *(const short4v*)(vb2 + 24 + 4 * lh);
        short8 vf0, vf1;
#pragma unroll
        for (int j = 0; j < 4; ++j) {
            vf0[j] = va[j];  vf0[4 + j] = vbq[j];
            vf1[j] = vc[j];  vf1[4 + j] = vd[j];
        }
        f32x16 st;
#pragma unroll
        for (int r = 0; r < 16; ++r) st[r] = 0.f;
        st = __builtin_amdgcn_mfma_f32_32x32x16_bf16(kf, qf, st, 0, 0, 0);
        short8 pf0, pf1;
#pragma unroll
        for (int r = 0; r < 8; ++r) {
            pf0[r] = (short)(__float_as_uint(exp2f(st[r]))     >> 16);
            pf1[r] = (short)(__float_as_uint(exp2f(st[8 + r])) >> 16);
        }
        accO = __builtin_amdgcn_mfma_f32_32x32x16_bf16(pf0, vf0, accO, 0, 0, 0);
        accO = __builtin_amdgcn_mfma_f32_32x32x16_bf16(pf1, vf1, accO, 0, 0, 0);
    }

#pragma unroll
    for (int r = 0; r < 16; ++r) {
        float val = accO[r];
        float s = __shfl(val, (lane & 32) + 16);
        if (lm < 16) {
            int qr = qrow0 + (r & 3) + 8 * (r >> 2) + 4 * lh;
            o[((size_t)b * 512 + qr) * 128 + hh * 16 + lm] = __float2bfloat16(val / s);
        }
    }
}

// ---------------------------------------------------------------------------
// 6. Fused LN2 + router (R18 structure; R20: per-layer slot buffers, no
//    per-layer memset — slots zeroed once in preamble)
// ---------------------------------------------------------------------------
__global__ __launch_bounds__(256) void ln2gate_kernel(
    const float* __restrict__ x, const float* __restrict__ g, const float* __restrict__ b,
    const float* __restrict__ gW, __hip_bfloat16* __restrict__ zbf,
    int* __restrict__ topi, float* __restrict__ topw,
    float* __restrict__ impS, int* __restrict__ cntS)
{
    __shared__ float simp[8];
    __shared__ int scnt[8];
    const int tid = threadIdx.x;
    if (tid < 8) { simp[tid] = 0.f; scnt[tid] = 0; }
    __syncthreads();
    const int wave = tid >> 6, lane = tid & 63;
    const size_t row = (size_t)blockIdx.x * 4 + wave;
    const float* xr = x + row * 128;
    float a0 = xr[lane], a1 = xr[lane + 64];
    float s = a0 + a1;
#pragma unroll
    for (int off = 32; off > 0; off >>= 1) s += __shfl_xor(s, off);
    float mean = s * (1.f / 128.f);
    float d0 = a0 - mean, d1 = a1 - mean;
    float v = d0 * d0 + d1 * d1;
#pragma unroll
    for (int off = 32; off > 0; off >>= 1) v += __shfl_xor(v, off);
    float inv = rsqrtf(v * (1.f / 128.f) + 1e-5f);
    float o0 = d0 * inv * g[lane] + b[lane];
    float o1 = d1 * inv * g[lane + 64] + b[lane + 64];
    zbf[row * 128 + lane]      = __float2bfloat16(o0);
    zbf[row * 128 + lane + 64] = __float2bfloat16(o1);
    // router logits: lg[e] = sum_d z[d]*gW[d][e]
    float4 gA = *(const float4*)&gW[lane * 8];
    float4 gB = *(const float4*)&gW[lane * 8 + 4];
    float4 gC = *(const float4*)&gW[(lane + 64) * 8];
    float4 gD = *(const float4*)&gW[(lane + 64) * 8 + 4];
    float lg[8];
    lg[0] = o0 * gA.x + o1 * gC.x;  lg[1] = o0 * gA.y + o1 * gC.y;
    lg[2] = o0 * gA.z + o1 * gC.z;  lg[3] = o0 * gA.w + o1 * gC.w;
    lg[4] = o0 * gB.x + o1 * gD.x;  lg[5] = o0 * gB.y + o1 * gD.y;
    lg[6] = o0 * gB.z + o1 * gD.z;  lg[7] = o0 * gB.w + o1 * gD.w;
#pragma unroll
    for (int e = 0; e < 8; ++e)
#pragma unroll
        for (int off = 32; off > 0; off >>= 1) lg[e] += __shfl_xor(lg[e], off);
    if (lane == 0) {
        float p[8];
        float mx = lg[0];
#pragma unroll
        for (int k = 1; k < 8; ++k) mx = fmaxf(mx, lg[k]);
        float ssum = 0.f;
#pragma unroll
        for (int k = 0; k < 8; ++k) { p[k] = expf(lg[k] - mx); ssum += p[k]; }
        float pinv = 1.f / ssum;
#pragma unroll
        for (int k = 0; k < 8; ++k) p[k] *= pinv;
        int i0 = 0; float v0 = p[0];
#pragma unroll
        for (int k = 1; k < 8; ++k) if (p[k] > v0) { v0 = p[k]; i0 = k; }
        int i1 = -1; float v1 = -1.f;
#pragma unroll
        for (int k = 0; k < 8; ++k) if (k != i0 && p[k] > v1) { v1 = p[k]; i1 = k; }
        float wsum = v0 + v1;
        topi[row * 2] = i0;  topi[row * 2 + 1] = i1;
        topw[row * 2] = v0 / wsum;  topw[row * 2 + 1] = v1 / wsum;
#pragma unroll
        for (int k = 0; k < 8; ++k) atomicAdd(&simp[k], p[k]);
        atomicAdd(&scnt[i0], 1); atomicAdd(&scnt[i1], 1);
    }
    __syncthreads();
    if (tid < 8) {
        int slot = (blockIdx.x & 63) * 8 + tid;
        atomicAdd(&impS[slot], simp[tid]);
        atomicAdd(&cntS[slot], scnt[tid]);
    }
}

// ---------------------------------------------------------------------------
// 7. Sum 64-way-spread counts, 128-aligned scan, counts for bounds check,
//    fill init (= moff), aux-loss accumulation. 64 threads; shfl reduce with
//    ALL lanes active, then LDS handoff to thread 0.
// ---------------------------------------------------------------------------
__global__ void offsets_kernel(const int* __restrict__ cntS, const float* __restrict__ impS,
                               int* __restrict__ moff, int* __restrict__ fill,
                               float* __restrict__ aux) {
    __shared__ int   csh[8];
    __shared__ float ish[8];
    const int tid = threadIdx.x;             // 64 threads (1 wave)
    const int e = tid & 7, grp = tid >> 3;   // 8 groups x 8 experts
    int c = 0; float im = 0.f;
    for (int g = 0; g < 8; ++g) {            // slots grp*8..grp*8+7
        int sl = grp * 8 + g;
        c  += cntS[sl * 8 + e];
        im += impS[sl * 8 + e];
    }
#pragma unroll
    for (int off = 32; off >= 8; off >>= 1) {   // fold grp dim; all lanes active
        c  += __shfl_down(c, off);
        im += __shfl_down(im, off);
    }
    if (tid < 8) { csh[tid] = c; ish[tid] = im; }   // lane e holds expert-e total
    __syncthreads();
    if (tid == 0) {
        int t = 0; float s = 0.f;
        for (int k = 0; k < 8; ++k) {
            int ck = csh[k];
            moff[k] = t; fill[k] = t;
            moff[9 + k] = ck;
            t += (ck + 127) & ~127;
            s += (ish[k] * (1.f / 16384.f)) * ((float)ck * (1.f / 16384.f));
        }
        moff[8] = t;
        aux[0] += 8.f * s;
    }
}

// ---------------------------------------------------------------------------
// 8. Scatter tokens into expert-contiguous slots — LDS-aggregated atomics.
// ---------------------------------------------------------------------------
__global__ __launch_bounds__(256) void scatter_kernel(const int* __restrict__ topi,
                                                      const float* __restrict__ topw,
                                                      int* __restrict__ fill, int* __restrict__ atok,
                                                      float* __restrict__ awt, int* __restrict__ tokpos) {
    __shared__ int lcnt[8];
    __shared__ int lbase[8];
    const int tid = threadIdx.x;
    const int token = blockIdx.x * 256 + tid;
    if (tid < 8) lcnt[tid] = 0;
    __syncthreads();
    const int e0 = topi[token * 2], e1 = topi[token * 2 + 1];
    const float w0 = topw[token * 2], w1 = topw[token * 2 + 1];
    const int l0 = atomicAdd(&lcnt[e0], 1);
    const int l1 = atomicAdd(&lcnt[e1], 1);     // e1 != e0 (top-2 distinct)
    __syncthreads();
    if (tid < 8) lbase[tid] = atomicAdd(&fill[tid], lcnt[tid]);
    __syncthreads();
    const int p0 = lbase[e0] + l0;
    const int p1 = lbase[e1] + l1;
    atok[p0] = token;  awt[p0] = w0;  tokpos[token * 2]     = p0;
    atok[p1] = token;  awt[p1] = w1;  tokpos[token * 2 + 1] = p1;
}

// ---------------------------------------------------------------------------
// 9. Fused combine + next-layer LN1: h += expert outputs; optional LN -> zbf
// ---------------------------------------------------------------------------
__global__ __launch_bounds__(256) void combine_ln_kernel(
    const float* __restrict__ yw, const int* __restrict__ tokpos,
    float* __restrict__ h, const float* __restrict__ g, const float* __restrict__ b,
    __hip_bfloat16* __restrict__ zbf)
{
    const int tid = threadIdx.x;
    const int wave = tid >> 6, lane = tid & 63;
    const size_t row = (size_t)blockIdx.x * 4 + wave;
    const int p0 = tokpos[row * 2], p1 = tokpos[row * 2 + 1];
    float a0 = h[row * 128 + lane]      + yw[(size_t)p0 * 128 + lane]
             + yw[(size_t)p1 * 128 + lane];
    float a1 = h[row * 128 + lane + 64] + yw[(size_t)p0 * 128 + lane + 64]
             + yw[(size_t)p1 * 128 + lane + 64];
    h[row * 128 + lane]      = a0;
    h[row * 128 + lane + 64] = a1;
    if (zbf) {
        float s = a0 + a1;
#pragma unroll
        for (int off = 32; off > 0; off >>= 1) s += __shfl_xor(s, off);
        float mean = s * (1.f / 128.f);
        float d0 = a0 - mean, d1 = a1 - mean;
        float v = d0 * d0 + d1 * d1;
#pragma unroll
        for (int off = 32; off > 0; off >>= 1) v += __shfl_xor(v, off);
        float inv = rsqrtf(v * (1.f / 128.f) + 1e-5f);
        zbf[row * 128 + lane]      = __float2bfloat16(d0 * inv * g[lane] + b[lane]);
        zbf[row * 128 + lane + 64] = __float2bfloat16(d1 * inv * g[lane + 64] + b[lane + 64]);
    }
}

// ---------------------------------------------------------------------------
// 10. mean over T -> LN -> head matmul [128,2]; writes aux scalar
// ---------------------------------------------------------------------------
__global__ __launch_bounds__(1024) void head_kernel(const float* __restrict__ h,
                                                    const float* __restrict__ g,
                                                    const float* __restrict__ bb,
                                                    const float* __restrict__ hW,
                                                    const float* __restrict__ hb,
                                                    const float* __restrict__ aux,
                                                    float* __restrict__ out) {
    __shared__ float part[8][128];
    __shared__ float red[128];
    __shared__ float pl[128];
    int b = blockIdx.x, tid = threadIdx.x;
    int c = tid & 127, w = tid >> 7;            // w = 0..7
    float s = 0.f;
    for (int t = w; t < 512; t += 8) s += h[((size_t)b * 512 + t) * 128 + c];
    part[w][c] = s;
    __syncthreads();
    float pooled = 0.f;
    if (tid < 128) {
#pragma unroll
        for (int k = 0; k < 8; ++k) pooled += part[k][tid];
        pooled *= (1.f / 512.f);
        red[tid] = pooled;
    }
    __syncthreads();
    for (int st = 64; st > 0; st >>= 1) { if (tid < st) red[tid] += red[tid + st]; __syncthreads(); }
    float mean = red[0] * (1.f / 128.f);
    __syncthreads();
    float d = pooled - mean;
    if (tid < 128) red[tid] = d * d;
    __syncthreads();
    for (int st = 64; st > 0; st >>= 1) { if (tid < st) red[tid] += red[tid + st]; __syncthreads(); }
    float var = red[0] * (1.f / 128.f);
    if (tid < 128) pl[tid] = d / sqrtf(var + 1e-5f) * g[tid] + bb[tid];
    __syncthreads();
    if (tid < 2) {
        float acc = hb[tid];
        for (int k = 0; k < 128; ++k) acc += pl[k] * hW[k * 2 + tid];
        out[b * 2 + tid] = acc;
    }
    if (b == 0 && tid == 0) out[64] = aux[0];
}

// ---------------------------------------------------------------------------
extern "C" void kernel_launch(void* const* d_in, const int* in_sizes, int n_in,
                              void* d_out, int out_size, void* d_ws, size_t ws_size,
                              hipStream_t stream) {
    (void)in_sizes; (void)n_in; (void)out_size; (void)ws_size;
    const float* x      = (const float*)d_in[0];
    const float* proj_W = (const float*)d_in[1];
    const float* proj_b = (const float*)d_in[2];
    const float* pos    = (const float*)d_in[3];
    const float* ln1_g  = (const float*)d_in[4];
    const float* ln1_b  = (const float*)d_in[5];
    const float* qkv_W  = (const float*)d_in[6];
    const float* qkv_b  = (const float*)d_in[7];
    const float* out_W  = (const float*)d_in[8];
    const float* out_b  = (const float*)d_in[9];
    const float* ln2_g  = (const float*)d_in[10];
    const float* ln2_b  = (const float*)d_in[11];
    const float* gate_W = (const float*)d_in[12];
    const float* w1     = (const float*)d_in[13];
    const float* b1     = (const float*)d_in[14];
    const float* w2     = (const float*)d_in[15];
    const float* b2     = (const float*)d_in[16];
    const float* hl_g   = (const float*)d_in[17];
    const float* hl_b   = (const float*)d_in[18];
    const float* head_W = (const float*)d_in[19];
    const float* head_b = (const float*)d_in[20];
    float* outp = (float*)d_out;

    // workspace layout (float granularity)
    float* ws = (float*)d_ws;
    size_t off = 0;
    auto alloc = [&](size_t n) { float* p = ws + off; off += (n + 63) & ~(size_t)63; return p; };
    float* hidbf_f = alloc((size_t)MAXASSIGN * 256);  // bf16 hid; aliases xtb
    float* h       = alloc((size_t)BT * 128);
    float* zbf_f   = alloc((size_t)(BT + 1) * 64);    // bf16 [16385][128], row BT = zeros
    float* qkvbf_f = alloc((size_t)BT * 192);         // bf16 head-major [3][8][BT][16]
    float* obbf_f  = alloc((size_t)BT * 64);          // bf16 [16384][128]
    float* yw      = alloc((size_t)MAXASSIGN * 128);  // f32
    float* projWt_f= alloc(128 * 448 / 2);
    float* qkvWt_f = alloc(4 * 384 * 128 / 2);
    float* outWt_f = alloc(4 * 128 * 128 / 2);
    float* w1t_f   = alloc((size_t)32 * 512 * 128 / 2);
    float* w2t_f   = alloc((size_t)32 * 128 * 512 / 2);
    float* topw    = alloc(32768);
    float* awt     = alloc(MAXASSIGN);
    float* impc    = alloc(4096);                     // 4 layers x (impS[64][8] + cntS[64][8])
    float* auxp    = alloc(1);
    int* topi      = (int*)alloc(32768);
    int* atok      = (int*)alloc(MAXASSIGN);
    int* tokpos    = (int*)alloc(32768);
    int* moff      = (int*)alloc(32);
    int* fill      = (int*)alloc(8);

    __hip_bfloat16* hidbf  = (__hip_bfloat16*)hidbf_f;
    __hip_bfloat16* xtb    = (__hip_bfloat16*)hidbf_f;   // alias: dead after proj
    __hip_bfloat16* zbf    = (__hip_bfloat16*)zbf_f;
    __hip_bfloat16* qkvbf  = (__hip_bfloat16*)qkvbf_f;
    __hip_bfloat16* obbf   = (__hip_bfloat16*)obbf_f;
    __hip_bfloat16* projWt = (__hip_bfloat16*)projWt_f;
    __hip_bfloat16* qkvWt  = (__hip_bfloat16*)qkvWt_f;
    __hip_bfloat16* outWt  = (__hip_bfloat16*)outWt_f;
    __hip_bfloat16* w1t    = (__hip_bfloat16*)w1t_f;
    __hip_bfloat16* w2t    = (__hip_bfloat16*)w2t_f;

    hipMemsetAsync(auxp, 0, 4, stream);
    hipMemsetAsync(impc, 0, 16384, stream);                          // all 4 layers' slots
    hipMemsetAsync((char*)zbf + (size_t)BT * 256, 0, 256, stream);   // zero gather row

    // input transpose + weight conversion (once per call)
    transpose_kernel<<<256, 256, 0, stream>>>(x, xtb);
    projconv_kernel<<<224, 256, 0, stream>>>(proj_W, projWt);
    wconvt_kernel<<<48, 256, 0, stream>>>(qkv_W, qkvWt, 128, 384);
    wconvt_kernel<<<16, 256, 0, stream>>>(out_W, outWt, 128, 128);
    wconvt_kernel<<<512, 256, 0, stream>>>(w1, w1t, 128, 512);
    wconvt_kernel<<<512, 256, 0, stream>>>(w2, w2t, 512, 128);

    // proj: h = xtb @ projWt^T + proj_b + pos  (K=448)
    mm_kernel<0, 64><<<dim3(256, 1), 256, 0, stream>>>(
        xtb, projWt, proj_b, pos, h, 448, 128, 0, nullptr, nullptr, nullptr);
    // layer-0 ln1 (subsequent ln1's are fused into combine_ln)
    ln_kernel<<<4096, 256, 0, stream>>>(h, ln1_g, ln1_b, zbf);

    for (int i = 0; i < 4; ++i) {
        float* impS = impc + (size_t)i * 1024;          // per-layer slots
        int*   cntS = (int*)(impc + (size_t)i * 1024 + 512);
        // qkv -> bf16 head-major, Q pre-scaled
        mm_kernel<5, 64><<<dim3(256, 3), 256, 0, stream>>>(
            zbf, qkvWt + (size_t)i * 384 * 128, qkv_b + i * 384, nullptr, qkvbf,
            128, 384, 0, nullptr, nullptr, nullptr);
        attn_kernel<<<dim3(2, 8, 32), 512, 0, stream>>>(qkvbf, obbf);
        mm_kernel<2, 64><<<dim3(256, 1), 256, 0, stream>>>(
            obbf, outWt + (size_t)i * 128 * 128, out_b + i * 128, h, h,
            128, 128, 0, nullptr, nullptr, nullptr);
        ln2gate_kernel<<<4096, 256, 0, stream>>>(h, ln2_g + i * 128, ln2_b + i * 128,
                                                 gate_W + (size_t)i * 128 * 8, zbf,
                                                 topi, topw, impS, cntS);
        offsets_kernel<<<1, 64, 0, stream>>>(cntS, impS, moff, fill, auxp);
        scatter_kernel<<<64, 256, 0, stream>>>(topi, topw, fill, atok, awt, tokpos);
        // moe1: hid = gelu(gather(zbf) @ w1t^T + b1)  -> bf16
        mm_kernel<3, 128><<<dim3(264, 4), 256, 0, stream>>>(
            zbf, w1t + (size_t)i * 8 * 512 * 128, b1 + (size_t)i * 8 * 512, nullptr,
            hidbf, 128, 512, 512 * 128, moff, atok, awt);
        // moe2: yw = (hid @ w2t^T + b2) * awt  -> f32
        mm_kernel<4, 64><<<dim3(528, 1), 256, 0, stream>>>(
            hidbf, w2t + (size_t)i * 8 * 128 * 512, b2 + (size_t)i * 8 * 128, nullptr,
            yw, 512, 128, 128 * 512, moff, atok, awt);
        // combine + next-layer ln1 (fused); last layer: no LN
        combine_ln_kernel<<<4096, 256, 0, stream>>>(yw, tokpos, h,
                                                    ln1_g + (i + 1 < 4 ? (i + 1) * 128 : 0),
                                                    ln1_b + (i + 1 < 4 ? (i + 1) * 128 : 0),
                                                    (i < 3) ? zbf : (__hip_bfloat16*)nullptr);
    }
    head_kernel<<<32, 1024, 0, stream>>>(h, hl_g, hl_b, head_W, head_b, auxp, outp);
}

// Round 10
// 639.746 us; speedup vs baseline: 1.5452x; 1.0129x over previous
//
#include <hip/hip_runtime.h>
#include <hip/hip_bf16.h>
#include <cstdint>
#include <cstddef>

// ---------------------------------------------------------------------------
// Model constants
// ---------------------------------------------------------------------------
#define BT        16384          // B*T tokens
#define MAXASSIGN 33792          // 32768 + 8*127 rounded to 128-aligned segments
#define QSCALE    0.36067376022224085f   // 0.25 * log2(e): fold 1/sqrt(dh) + exp->exp2

typedef __attribute__((ext_vector_type(8)))  short short8;   // 8 bf16 = 1 MFMA frag
typedef __attribute__((ext_vector_type(4)))  short short4v;
typedef __attribute__((ext_vector_type(4)))  float f32x4;
typedef __attribute__((ext_vector_type(16))) float f32x16;

typedef const uint32_t __attribute__((address_space(1))) gas_u32;
typedef uint32_t __attribute__((address_space(3))) las_u32;

// async global->LDS direct copy, 16B per lane; LDS dest = wave base + lane*16
__device__ __forceinline__ void gload16(const void* g, void* l) {
    __builtin_amdgcn_global_load_lds((gas_u32*)g, (las_u32*)l, 16, 0, 0);
}

// gelu(x) = 0.5x(1+tanh(u)) = x*sigmoid(2u), u = sqrt(2/pi)(x+0.044715x^3).
__device__ __forceinline__ float gelu_f(float x) {
    float u2l = (x + 0.044715f * x * x * x) * 2.3022081927f;   // 2u*log2(e)
    float e = exp2f(u2l);
    float r = __builtin_amdgcn_rcpf(e + 1.0f);
    return x * e * r;
}

// pack 2 floats -> 1 u32 of 2 bf16 (RNE), a = low half
__device__ __forceinline__ unsigned pkbf(float a, float b) {
    __hip_bfloat16 ha = __float2bfloat16(a);
    __hip_bfloat16 hb = __float2bfloat16(b);
    unsigned short ua = *reinterpret_cast<unsigned short*>(&ha);
    unsigned short ub = *reinterpret_cast<unsigned short*>(&hb);
    return (unsigned)ua | ((unsigned)ub << 16);
}

// ---------------------------------------------------------------------------
// 0. One-shot init: aux, all 4 layers' router slots, zbf zero gather row.
//    (R21: replaces 3 hipMemsetAsync launches)
// ---------------------------------------------------------------------------
__global__ void init_kernel(float* __restrict__ auxp, float* __restrict__ impc,
                            unsigned* __restrict__ zrow) {
    int tid = threadIdx.x;               // 256
    if (tid == 0) auxp[0] = 0.f;
    for (int u = tid; u < 4096; u += 256) impc[u] = 0.f;
    if (tid < 64) zrow[tid] = 0u;        // 128 bf16 = 64 u32
}

// ---------------------------------------------------------------------------
// 1. x [32,55,512,8] -> xtb [16384][448] bf16 (cols 440..447 zero-padded)
//    R21: blocks >= 256 run the (tiny) projconv: proj_W [440][128] ->
//    projWt [128][448] bf16, zero pad k>=440.
// ---------------------------------------------------------------------------
__global__ __launch_bounds__(256) void transpose_kernel(const float* __restrict__ x,
                                                        __hip_bfloat16* __restrict__ xtb,
                                                        const float* __restrict__ projW,
                                                        __hip_bfloat16* __restrict__ projWt) {
    __shared__ unsigned tile[64][228];   // [t][packed bf16-pair col]; pad 224->228
    if (blockIdx.x >= 256) {             // projconv part: 224 blocks
        int idx = (blockIdx.x - 256) * 256 + threadIdx.x;   // 128*448 exact
        int k = idx % 448, n = idx / 448;
        projWt[idx] = __float2bfloat16(k < 440 ? projW[k * 128 + n] : 0.f);
        return;
    }
    const int b  = blockIdx.x >> 3;      // 32 batches
    const int t0 = (blockIdx.x & 7) * 64;
    const int tid = threadIdx.x;
    tile[tid >> 2][220 + (tid & 3)] = 0u;
    const int tt  = tid >> 2;            // 0..63  (t within tile)
    const int ncp = tid & 3;             // bf16-pair within nb block
    for (int nb = 0; nb < 55; ++nb) {
        const float2* src = (const float2*)(x + (((size_t)(b * 55 + nb)) * 512 + t0) * 8);
        float2 v = src[tid];             // 256 float2 = 64t x 8nc, contiguous
        tile[tt][nb * 4 + ncp] = pkbf(v.x, v.y);
    }
    __syncthreads();
#pragma unroll
    for (int u = 0; u < 14; ++u) {
        int idx = u * 256 + tid;
        int t = idx / 56, c = idx % 56;
        *(uint4*)(xtb + ((size_t)b * 512 + t0 + t) * 448 + c * 8) =
            *(const uint4*)&tile[t][c * 4];
    }
}

// ---------------------------------------------------------------------------
// 2. Weight convert+transpose via LDS tile: out[b][n][k] = bf16(in[b][k][n])
//    R21: all 4 weight tensors in one launch (range dispatch on blockIdx):
//    [0,48) qkv_W (4,128,384) | [48,64) out_W (4,128,128) |
//    [64,576) w1 (32,128,512) | [576,1088) w2 (32,512,128)
// ---------------------------------------------------------------------------
__global__ __launch_bounds__(256) void wconvt4_kernel(
    const float* __restrict__ qkvW, __hip_bfloat16* __restrict__ qkvWt_,
    const float* __restrict__ outW, __hip_bfloat16* __restrict__ outWt_,
    const float* __restrict__ w1i, __hip_bfloat16* __restrict__ w1o,
    const float* __restrict__ w2i, __hip_bfloat16* __restrict__ w2o)
{
    __shared__ float tile[64][65];
    const int bid = blockIdx.x;
    const float* in; __hip_bfloat16* out; int K, N, blk;
    if (bid < 48)       { in = qkvW; out = qkvWt_; K = 128; N = 384; blk = bid; }
    else if (bid < 64)  { in = outW; out = outWt_; K = 128; N = 128; blk = bid - 48; }
    else if (bid < 576) { in = w1i;  out = w1o;    K = 128; N = 512; blk = bid - 64; }
    else                { in = w2i;  out = w2o;    K = 512; N = 128; blk = bid - 576; }
    const int kt = K >> 6, nt = N >> 6;
    const int per = kt * nt;
    const int bb  = blk / per;
    const int rem = blk % per;
    const int k0  = (rem / nt) << 6;
    const int n0  = (rem % nt) << 6;
    const int tid = threadIdx.x;

    const float* src = in + ((size_t)bb * K + k0) * N + n0;
    int tk = tid >> 4;               // 0..15
    int tn = (tid & 15) * 4;         // 0..60
#pragma unroll
    for (int r = 0; r < 4; ++r) {
        float4 v = *(const float4*)(src + (size_t)(tk + r * 16) * N + tn);
        tile[tk + r * 16][tn]     = v.x;
        tile[tk + r * 16][tn + 1] = v.y;
        tile[tk + r * 16][tn + 2] = v.z;
        tile[tk + r * 16][tn + 3] = v.w;
    }
    __syncthreads();
    int on = tid >> 2;               // 0..63
    int ok = (tid & 3) * 16;         // 0,16,32,48
    unsigned pk[8];
#pragma unroll
    for (int u = 0; u < 8; ++u)
        pk[u] = pkbf(tile[ok + 2 * u][on], tile[ok + 2 * u + 1][on]);
    uint4* dst = (uint4*)(out + ((size_t)bb * N + n0 + on) * K + k0 + ok);
    dst[0] = (uint4){pk[0], pk[1], pk[2], pk[3]};
    dst[1] = (uint4){pk[4], pk[5], pk[6], pk[7]};
}

// ---------------------------------------------------------------------------
// 3. bf16 MFMA GEMM, templated <MODE, BM> (per-mode DCE; BM = row-tile).
//    BM=128: 4 waves 2x2, 4x4 frags. BM=64: 2x4 frags -> 2x grid for the
//    latency-bound small GEMMs (proj/qkv/out/moe2 were 128-384 blocks).
//    mfma_f32_16x16x32_bf16, operand-swapped (acc = C^T frags). LDS
//    chunk-XOR swizzle; global_load_lds width-16 linear-dest staging with
//    inverse-swizzled global source. LDS-repack epilogue, coalesced stores.
//    MODE 0: proj, f32 out + pos.   MODE 2: out-proj, f32 residual add.
//    MODE 3: moe1, gathered A (atok), gelu, bf16 out.
//    MODE 4: moe2, f32 out * awt.
//    MODE 5: qkv, bf16 HEAD-MAJOR [part][h][token][16], Q pre-scaled.
// ---------------------------------------------------------------------------
template<int MODE, int BM>
__global__ __launch_bounds__(256) void mm_kernel(
    const __hip_bfloat16* __restrict__ A, const __hip_bfloat16* __restrict__ Wt,
    const float* __restrict__ bias, const float* __restrict__ extra,
    void* __restrict__ Cout, int K, int N, int wstride,
    const int* __restrict__ moff, const int* __restrict__ atok,
    const float* __restrict__ awt)
{
    constexpr int FI = BM / 32;          // A p-groups / frag rows per wave
    __shared__ short smem[16384];        // 32 KB: As|Bs in K-loop, C-tile after
    short* As = smem;                    // BM*64 shorts
    short* Bs = smem + BM * 64;          // 8192 shorts (128x64)
    const int tid  = threadIdx.x;
    const int row0 = blockIdx.x * BM;
    const int col0 = blockIdx.y * 128;

    const float* bias2 = bias;
    int lim = 0;
    if constexpr (MODE == 3 || MODE == 4) {
        if (row0 >= moff[8]) return;             // segments are 128-aligned
        int e = 0;
        while (moff[e + 1] <= row0) ++e;
        Wt    += (size_t)e * wstride;
        bias2  = bias + e * N;
        lim    = moff[e] + moff[9 + e];          // valid-assignment end
    }

    const int wave = tid >> 6, lane = tid & 63;
    const int crow = tid >> 3;   // 0..31  (staging row within p-group)
    const int cc   = tid & 7;    // 0..7   (16B chunk within row)

    int srow[FI];
#pragma unroll
    for (int p = 0; p < FI; ++p) {
        int grow = row0 + p * 32 + crow;
        srow[p] = grow;
        if constexpr (MODE == 3)
            srow[p] = (grow < lim) ? atok[grow] : BT;   // pad -> zeroed row
    }

    f32x4 acc[FI][4];
#pragma unroll
    for (int i = 0; i < FI; ++i)
#pragma unroll
        for (int j = 0; j < 4; ++j) acc[i][j] = (f32x4){0.f, 0.f, 0.f, 0.f};

    const int wm = (wave >> 1) * (BM / 2), wn = (wave & 1) * 64;
    const int lr = lane & 15, q = lane >> 4;

    for (int k0 = 0; k0 < K; k0 += 64) {
#pragma unroll
        for (int p = 0; p < FI; ++p) {
            int row = p * 32 + crow;
            int sc  = (cc ^ (row & 7)) << 3;             // swizzled src chunk
            short* la = &As[(p * 32 + wave * 8) * 64];
            gload16(A + (size_t)srow[p] * K + k0 + sc, la);
        }
#pragma unroll
        for (int p = 0; p < 4; ++p) {
            int row = p * 32 + crow;
            int sc  = (cc ^ (row & 7)) << 3;
            short* lb = &Bs[(p * 32 + wave * 8) * 64];
            gload16(Wt + (size_t)(col0 + row) * K + k0 + sc, lb);
        }
        __syncthreads();
#pragma unroll
        for (int s = 0; s < 2; ++s) {
            short8 af[FI], bf[4];
#pragma unroll
            for (int f = 0; f < FI; ++f) {
                int m = wm + f * 16 + lr;
                af[f] = *(const short8*)&As[(m * 8 + ((s * 4 + q) ^ (m & 7))) * 8];
            }
#pragma unroll
            for (int f = 0; f < 4; ++f) {
                int n = wn + f * 16 + lr;
                bf[f] = *(const short8*)&Bs[(n * 8 + ((s * 4 + q) ^ (n & 7))) * 8];
            }
            // swapped operands: acc[i][j] = C^T frag; lane element r is
            // C[token = row0+wm+i*16+lr][col = col0+wn+j*16+q*4+r]
#pragma unroll
            for (int i = 0; i < FI; ++i)
#pragma unroll
                for (int j = 0; j < 4; ++j)
                    acc[i][j] = __builtin_amdgcn_mfma_f32_16x16x32_bf16(
                        bf[j], af[i], acc[i][j], 0, 0, 0);
        }
        __syncthreads();
    }

    // ---- epilogue: bias in-register, LDS repack, coalesced vector stores ----
    float4 b4[4];
#pragma unroll
    for (int j = 0; j < 4; ++j)
        b4[j] = *(const float4*)&bias2[col0 + wn + j * 16 + q * 4];

    if constexpr (MODE == 3 || MODE == 5) {
        // bf16 output: BM x 128 bf16 tile, 16B-chunk XOR swizzle
        const bool qsc = (MODE == 5) && (col0 == 0);
#pragma unroll
        for (int i = 0; i < FI; ++i) {
            int trow = wm + i * 16 + lr;
#pragma unroll
            for (int j = 0; j < 4; ++j) {
                int cb = wn + j * 16 + q * 4;
                float v0 = acc[i][j][0] + b4[j].x;
                float v1 = acc[i][j][1] + b4[j].y;
                float v2 = acc[i][j][2] + b4[j].z;
                float v3 = acc[i][j][3] + b4[j].w;
                if constexpr (MODE == 3) {
                    v0 = gelu_f(v0); v1 = gelu_f(v1);
                    v2 = gelu_f(v2); v3 = gelu_f(v3);
                }
                if (qsc) { v0 *= QSCALE; v1 *= QSCALE; v2 *= QSCALE; v3 *= QSCALE; }
                uint2 pk = {pkbf(v0, v1), pkbf(v2, v3)};
                int ch = cb >> 3;
                *(uint2*)((char*)smem + trow * 256 + ((ch ^ (trow & 7)) << 4)
                          + ((cb & 7) << 1)) = pk;
            }
        }
        __syncthreads();
        __hip_bfloat16* outb = (__hip_bfloat16*)Cout;
        constexpr int TPR = 256 / BM;                // threads per row (2 or 4)
        constexpr int CPT = 16 / TPR;                // chunks per thread (8 or 4)
        int rrow = tid / TPR;
        if constexpr (MODE == 3) {
            size_t rb = (size_t)(row0 + rrow) * N + col0;
#pragma unroll
            for (int u = 0; u < CPT; ++u) {
                int c = (tid % TPR) * CPT + u;
                uint4 d = *(const uint4*)((char*)smem + rrow * 256
                                          + ((c ^ (rrow & 7)) << 4));
                *(uint4*)(outb + rb + c * 8) = d;
            }
        } else {
            size_t pbase = (size_t)(col0 >> 7) * 8 * BT * 16;
#pragma unroll
            for (int u = 0; u < CPT; ++u) {
                int c = (tid % TPR) * CPT + u;           // h = c>>1, dblk = c&1
                uint4 d = *(const uint4*)((char*)smem + rrow * 256
                                          + ((c ^ (rrow & 7)) << 4));
                size_t dst = pbase + ((size_t)(c >> 1) * BT + row0 + rrow) * 16
                           + (c & 1) * 8;
                *(uint4*)(outb + dst) = d;
            }
        }
    } else {
        // f32 output: 64-row half-tiles ([64][128] f32 = 32 KB), BM/64 passes
        float* outf = (float*)Cout;
        constexpr int HP = BM / 64;
        for (int h = 0; h < HP; ++h) {
            if (HP == 1 || (wm >> 6) == h) {
#pragma unroll
                for (int i = 0; i < FI; ++i) {
                    int trow = (wm & 63) + i * 16 + lr;
#pragma unroll
                    for (int j = 0; j < 4; ++j) {
                        int cb = wn + j * 16 + q * 4;
                        f32x4 v = acc[i][j];
                        v[0] += b4[j].x; v[1] += b4[j].y;
                        v[2] += b4[j].z; v[3] += b4[j].w;
                        int ch = cb >> 2;
                        *(f32x4*)((char*)smem + trow * 512
                                  + ((ch ^ (trow & 7)) << 4)) = v;
                    }
                }
            }
            __syncthreads();
            {
                int rrow = tid >> 2;                     // 0..63
                int grow = row0 + h * 64 + rrow;
                float aw = (MODE == 4) ? awt[grow] : 1.f;
                size_t rb = (size_t)grow * N + col0;
#pragma unroll
                for (int u = 0; u < 8; ++u) {
                    int c = (tid & 3) * 8 + u;
                    f32x4 d = *(const f32x4*)((char*)smem + rrow * 512
                                              + ((c ^ (rrow & 7)) << 4));
                    int gcol = col0 + c * 4;
                    if constexpr (MODE == 0) {
                        float4 p = *(const float4*)&extra[(grow & 511) * 128 + gcol];
                        d[0] += p.x; d[1] += p.y; d[2] += p.z; d[3] += p.w;
                    } else if constexpr (MODE == 2) {
                        float4 p = *(const float4*)&extra[rb + c * 4];
                        d[0] += p.x; d[1] += p.y; d[2] += p.z; d[3] += p.w;
                    } else if constexpr (MODE == 4) {
                        d[0] *= aw; d[1] *= aw; d[2] *= aw; d[3] *= aw;
                    }
                    *(f32x4*)&outf[rb + c * 4] = d;
                }
            }
            __syncthreads();
        }
    }
}

// ---------------------------------------------------------------------------
// 4. LayerNorm over D=128 -> bf16 zbf (layer-0 ln1 only)
// ---------------------------------------------------------------------------
__global__ __launch_bounds__(256) void ln_kernel(const float* __restrict__ x,
                                                 const float* __restrict__ g,
                                                 const float* __restrict__ b,
                                                 __hip_bfloat16* __restrict__ zbf) {
    int wave = threadIdx.x >> 6, lane = threadIdx.x & 63;
    size_t row = (size_t)blockIdx.x * 4 + wave;
    const float* xr = x + row * 128;
    float a0 = xr[lane], a1 = xr[lane + 64];
    float s = a0 + a1;
#pragma unroll
    for (int off = 32; off > 0; off >>= 1) s += __shfl_xor(s, off);
    float mean = s * (1.f / 128.f);
    float d0 = a0 - mean, d1 = a1 - mean;
    float v = d0 * d0 + d1 * d1;
#pragma unroll
    for (int off = 32; off > 0; off >>= 1) v += __shfl_xor(v, off);
    float inv = rsqrtf(v * (1.f / 128.f) + 1e-5f);
    zbf[row * 128 + lane]      = __float2bfloat16(d0 * inv * g[lane] + b[lane]);
    zbf[row * 128 + lane + 64] = __float2bfloat16(d1 * inv * g[lane + 64] + b[lane + 64]);
}

// ---------------------------------------------------------------------------
// 5. MFMA flash attention v3 — shuffle-free PV + 512 threads (8 waves).
//    qkv is head-major [part][h][token][16] -> fully coalesced staging.
// ---------------------------------------------------------------------------
__global__ __launch_bounds__(512) void attn_kernel(const __hip_bfloat16* __restrict__ qkv,
                                                   __hip_bfloat16* __restrict__ o) {
    __shared__ short Ks[512 * 24];    // K [key][16 used, 24 pitch] : 24 KB
    __shared__ short Vt[17 * 520];    // V^T [col 0..15, 16=ones][key, 520 pitch]
    const int b = blockIdx.z, hh = blockIdx.y, half = blockIdx.x;
    const int tid = threadIdx.x;
    const __hip_bfloat16* Qh = qkv + ((size_t)(0 * 8 + hh) * BT + b * 512) * 16;
    const __hip_bfloat16* Kh = qkv + ((size_t)(1 * 8 + hh) * BT + b * 512) * 16;
    const __hip_bfloat16* Vh = qkv + ((size_t)(2 * 8 + hh) * BT + b * 512) * 16;

    {
        int r = tid;   // 512 threads, 512 keys; 32B/lane contiguous reads
        const uint4* ksrc = (const uint4*)(Kh + (size_t)r * 16);
        uint4 k0 = ksrc[0], k1 = ksrc[1];
        *(uint4*)&Ks[r * 24 + 0] = k0;
        *(uint4*)&Ks[r * 24 + 8] = k1;
        const uint4* vsrc = (const uint4*)(Vh + (size_t)r * 16);
        uint4 v0 = vsrc[0], v1 = vsrc[1];
        unsigned vv[8] = {v0.x, v0.y, v0.z, v0.w, v1.x, v1.y, v1.z, v1.w};
#pragma unroll
        for (int c = 0; c < 8; ++c) {
            Vt[(2 * c)     * 520 + r] = (short)(vv[c] & 0xffff);
            Vt[(2 * c + 1) * 520 + r] = (short)(vv[c] >> 16);
        }
        Vt[16 * 520 + r] = (short)0x3F80;   // 1.0 bf16
    }
    __syncthreads();

    const int wave = tid >> 6, lane = tid & 63;
    const int lm = lane & 31, lh = lane >> 5;
    const int qrow0 = half * 256 + wave * 32;

    short8 qf = *(const short8*)(Qh + (size_t)(qrow0 + lm) * 16 + lh * 8);

    f32x16 accO;
#pragma unroll
    for (int r = 0; r < 16; ++r) accO[r] = 0.f;

    for (int kc = 0; kc < 16; ++kc) {
        short8 kf = *(const short8*)&Ks[(kc * 32 + lm) * 24 + lh * 8];
        int vr = (lm < 16) ? lm : 16;
        const short* vb2 = &Vt[vr * 520 + kc * 32];
        short4v va  = *(const short4v*)(vb2 + 4 * lh);
        short4v vbq = *(const short4v*)(vb2 + 8 + 4 * lh);
        short4v vc  = *(const short4v*)(vb2 + 16 + 4 * lh);
        short4v vd  = *(const short4v*)(vb2 + 24 + 4 * lh);
        short8 vf0, vf1;
#pragma unroll
        for (int j = 0; j < 4; ++j) {
            vf0[j] = va[j];  vf0[4 + j] = vbq[j];
            vf1[j] = vc[j];  vf1[4 + j] = vd[j];
        }
        f32x16 st;
#pragma unroll
        for (int r = 0; r < 16; ++r) st[r] = 0.f;
        st = __builtin_amdgcn_mfma_f32_32x32x16_bf16(kf, qf, st, 0, 0, 0);
        short8 pf0, pf1;
#pragma unroll
        for (int r = 0; r < 8; ++r) {
            pf0[r] = (short)(__float_as_uint(exp2f(st[r]))     >> 16);
            pf1[r] = (short)(__float_as_uint(exp2f(st[8 + r])) >> 16);
        }
        accO = __builtin_amdgcn_mfma_f32_32x32x16_bf16(pf0, vf0, accO, 0, 0, 0);
        accO = __builtin_amdgcn_mfma_f32_32x32x16_bf16(pf1, vf1, accO, 0, 0, 0);
    }

#pragma unroll
    for (int r = 0; r < 16; ++r) {
        float val = accO[r];
        float s = __shfl(val, (lane & 32) + 16);
        if (lm < 16) {
            int qr = qrow0 + (r & 3) + 8 * (r >> 2) + 4 * lh;
            o[((size_t)b * 512 + qr) * 128 + hh * 16 + lm] = __float2bfloat16(val / s);
        }
    }
}

// ---------------------------------------------------------------------------
// 6. Fused LN2 + router. R21: slot index = blockIdx>>6 so slot s aggregates
//    exactly scatter-block s's 256 tokens (blocks 64s..64s+63) — enables the
//    fill-free deterministic scatter. Per-layer slot buffers zeroed once in
//    preamble. Same contention (64 blocks/slot) as before.
// ---------------------------------------------------------------------------
__global__ __launch_bounds__(256) void ln2gate_kernel(
    const float* __restrict__ x, const float* __restrict__ g, const float* __restrict__ b,
    const float* __restrict__ gW, __hip_bfloat16* __restrict__ zbf,
    int* __restrict__ topi, float* __restrict__ topw,
    float* __restrict__ impS, int* __restrict__ cntS)
{
    __shared__ float simp[8];
    __shared__ int scnt[8];
    const int tid = threadIdx.x;
    if (tid < 8) { simp[tid] = 0.f; scnt[tid] = 0; }
    __syncthreads();
    const int wave = tid >> 6, lane = tid & 63;
    const size_t row = (size_t)blockIdx.x * 4 + wave;
    const float* xr = x + row * 128;
    float a0 = xr[lane], a1 = xr[lane + 64];
    float s = a0 + a1;
#pragma unroll
    for (int off = 32; off > 0; off >>= 1) s += __shfl_xor(s, off);
    float mean = s * (1.f / 128.f);
    float d0 = a0 - mean, d1 = a1 - mean;
    float v = d0 * d0 + d1 * d1;
#pragma unroll
    for (int off = 32; off > 0; off >>= 1) v += __shfl_xor(v, off);
    float inv = rsqrtf(v * (1.f / 128.f) + 1e-5f);
    float o0 = d0 * inv * g[lane] + b[lane];
    float o1 = d1 * inv * g[lane + 64] + b[lane + 64];
    zbf[row * 128 + lane]      = __float2bfloat16(o0);
    zbf[row * 128 + lane + 64] = __float2bfloat16(o1);
    // router logits: lg[e] = sum_d z[d]*gW[d][e]
    float4 gA = *(const float4*)&gW[lane * 8];
    float4 gB = *(const float4*)&gW[lane * 8 + 4];
    float4 gC = *(const float4*)&gW[(lane + 64) * 8];
    float4 gD = *(const float4*)&gW[(lane + 64) * 8 + 4];
    float lg[8];
    lg[0] = o0 * gA.x + o1 * gC.x;  lg[1] = o0 * gA.y + o1 * gC.y;
    lg[2] = o0 * gA.z + o1 * gC.z;  lg[3] = o0 * gA.w + o1 * gC.w;
    lg[4] = o0 * gB.x + o1 * gD.x;  lg[5] = o0 * gB.y + o1 * gD.y;
    lg[6] = o0 * gB.z + o1 * gD.z;  lg[7] = o0 * gB.w + o1 * gD.w;
#pragma unroll
    for (int e = 0; e < 8; ++e)
#pragma unroll
        for (int off = 32; off > 0; off >>= 1) lg[e] += __shfl_xor(lg[e], off);
    if (lane == 0) {
        float p[8];
        float mx = lg[0];
#pragma unroll
        for (int k = 1; k < 8; ++k) mx = fmaxf(mx, lg[k]);
        float ssum = 0.f;
#pragma unroll
        for (int k = 0; k < 8; ++k) { p[k] = expf(lg[k] - mx); ssum += p[k]; }
        float pinv = 1.f / ssum;
#pragma unroll
        for (int k = 0; k < 8; ++k) p[k] *= pinv;
        int i0 = 0; float v0 = p[0];
#pragma unroll
        for (int k = 1; k < 8; ++k) if (p[k] > v0) { v0 = p[k]; i0 = k; }
        int i1 = -1; float v1 = -1.f;
#pragma unroll
        for (int k = 0; k < 8; ++k) if (k != i0 && p[k] > v1) { v1 = p[k]; i1 = k; }
        float wsum = v0 + v1;
        topi[row * 2] = i0;  topi[row * 2 + 1] = i1;
        topw[row * 2] = v0 / wsum;  topw[row * 2 + 1] = v1 / wsum;
#pragma unroll
        for (int k = 0; k < 8; ++k) atomicAdd(&simp[k], p[k]);
        atomicAdd(&scnt[i0], 1); atomicAdd(&scnt[i1], 1);
    }
    __syncthreads();
    if (tid < 8) {
        int slot = (blockIdx.x >> 6) * 8 + tid;     // slot s = scatter block s
        atomicAdd(&impS[slot], simp[tid]);
        atomicAdd(&cntS[slot], scnt[tid]);
    }
}

// ---------------------------------------------------------------------------
// 8. Scatter + fused offsets (R21). Each of the 64 blocks redundantly
//    reduces the 64x8 slot table (L2-hot): global per-expert totals -> moff
//    scan; prefix over slots < blk -> this block's deterministic base per
//    expert (slot s == token range of scatter block s). No global fill
//    atomics, no extra kernel. Block 0 writes moff[] + aux.
// ---------------------------------------------------------------------------
__global__ __launch_bounds__(256) void scatter_kernel(
    const int* __restrict__ topi, const float* __restrict__ topw,
    const int* __restrict__ cntS, const float* __restrict__ impS,
    int* __restrict__ atok, float* __restrict__ awt, int* __restrict__ tokpos,
    int* __restrict__ moffw, float* __restrict__ aux)
{
    __shared__ int lcnt[8];
    __shared__ int lbase[8];
    __shared__ int csum[8];
    __shared__ float isum[8];
    const int tid = threadIdx.x;
    const int blk = blockIdx.x;                  // 0..63
    if (tid < 64) {                              // wave 0, all lanes active
        int e = tid & 7, grp = tid >> 3;
        int ct = 0, cp = 0; float im = 0.f;
        for (int g = 0; g < 8; ++g) {
            int sl = grp * 8 + g;
            int vv = cntS[sl * 8 + e];
            ct += vv;
            cp += (sl < blk) ? vv : 0;
            im += impS[sl * 8 + e];
        }
#pragma unroll
        for (int off = 32; off >= 8; off >>= 1) {
            ct += __shfl_down(ct, off);
            cp += __shfl_down(cp, off);
            im += __shfl_down(im, off);
        }
        if (tid < 8) { csum[tid] = ct; isum[tid] = im; lbase[tid] = cp; lcnt[tid] = 0; }
    }
    __syncthreads();
    if (tid < 8) {
        int t = 0;
        for (int k = 0; k < tid; ++k) t += (csum[k] + 127) & ~127;   // moff[tid]
        lbase[tid] += t;                         // moff[e] + prefix-before-block
    }
    if (blk == 0 && tid == 64) {                 // separate lane: write moff + aux
        int t = 0; float s = 0.f;
        for (int k = 0; k < 8; ++k) {
            int ck = csum[k];
            moffw[k] = t;
            moffw[9 + k] = ck;
            t += (ck + 127) & ~127;
            s += (isum[k] * (1.f / 16384.f)) * ((float)ck * (1.f / 16384.f));
        }
        moffw[8] = t;
        aux[0] += 8.f * s;
    }
    __syncthreads();
    const int token = blk * 256 + tid;
    const int e0 = topi[token * 2], e1 = topi[token * 2 + 1];
    const float w0 = topw[token * 2], w1 = topw[token * 2 + 1];
    const int l0 = atomicAdd(&lcnt[e0], 1);
    const int l1 = atomicAdd(&lcnt[e1], 1);      // e1 != e0 (top-2 distinct)
    const int p0 = lbase[e0] + l0;
    const int p1 = lbase[e1] + l1;
    atok[p0] = token;  awt[p0] = w0;  tokpos[token * 2]     = p0;
    atok[p1] = token;  awt[p1] = w1;  tokpos[token * 2 + 1] = p1;
}

// ---------------------------------------------------------------------------
// 9. Fused combine + next-layer LN1: h += expert outputs; optional LN -> zbf
// ---------------------------------------------------------------------------
__global__ __launch_bounds__(256) void combine_ln_kernel(
    const float* __restrict__ yw, const int* __restrict__ tokpos,
    float* __restrict__ h, const float* __restrict__ g, const float* __restrict__ b,
    __hip_bfloat16* __restrict__ zbf)
{
    const int tid = threadIdx.x;
    const int wave = tid >> 6, lane = tid & 63;
    const size_t row = (size_t)blockIdx.x * 4 + wave;
    const int p0 = tokpos[row * 2], p1 = tokpos[row * 2 + 1];
    float a0 = h[row * 128 + lane]      + yw[(size_t)p0 * 128 + lane]
             + yw[(size_t)p1 * 128 + lane];
    float a1 = h[row * 128 + lane + 64] + yw[(size_t)p0 * 128 + lane + 64]
             + yw[(size_t)p1 * 128 + lane + 64];
    h[row * 128 + lane]      = a0;
    h[row * 128 + lane + 64] = a1;
    if (zbf) {
        float s = a0 + a1;
#pragma unroll
        for (int off = 32; off > 0; off >>= 1) s += __shfl_xor(s, off);
        float mean = s * (1.f / 128.f);
        float d0 = a0 - mean, d1 = a1 - mean;
        float v = d0 * d0 + d1 * d1;
#pragma unroll
        for (int off = 32; off > 0; off >>= 1) v += __shfl_xor(v, off);
        float inv = rsqrtf(v * (1.f / 128.f) + 1e-5f);
        zbf[row * 128 + lane]      = __float2bfloat16(d0 * inv * g[lane] + b[lane]);
        zbf[row * 128 + lane + 64] = __float2bfloat16(d1 * inv * g[lane + 64] + b[lane + 64]);
    }
}

// ---------------------------------------------------------------------------
// 10. mean over T -> LN -> head matmul [128,2]; writes aux scalar
// ---------------------------------------------------------------------------
__global__ __launch_bounds__(1024) void head_kernel(const float* __restrict__ h,
                                                    const float* __restrict__ g,
                                                    const float* __restrict__ bb,
                                                    const float* __restrict__ hW,
                                                    const float* __restrict__ hb,
                                                    const float* __restrict__ aux,
                                                    float* __restrict__ out) {
    __shared__ float part[8][128];
    __shared__ float red[128];
    __shared__ float pl[128];
    int b = blockIdx.x, tid = threadIdx.x;
    int c = tid & 127, w = tid >> 7;            // w = 0..7
    float s = 0.f;
    for (int t = w; t < 512; t += 8) s += h[((size_t)b * 512 + t) * 128 + c];
    part[w][c] = s;
    __syncthreads();
    float pooled = 0.f;
    if (tid < 128) {
#pragma unroll
        for (int k = 0; k < 8; ++k) pooled += part[k][tid];
        pooled *= (1.f / 512.f);
        red[tid] = pooled;
    }
    __syncthreads();
    for (int st = 64; st > 0; st >>= 1) { if (tid < st) red[tid] += red[tid + st]; __syncthreads(); }
    float mean = red[0] * (1.f / 128.f);
    __syncthreads();
    float d = pooled - mean;
    if (tid < 128) red[tid] = d * d;
    __syncthreads();
    for (int st = 64; st > 0; st >>= 1) { if (tid < st) red[tid] += red[tid + st]; __syncthreads(); }
    float var = red[0] * (1.f / 128.f);
    if (tid < 128) pl[tid] = d / sqrtf(var + 1e-5f) * g[tid] + bb[tid];
    __syncthreads();
    if (tid < 2) {
        float acc = hb[tid];
        for (int k = 0; k < 128; ++k) acc += pl[k] * hW[k * 2 + tid];
        out[b * 2 + tid] = acc;
    }
    if (b == 0 && tid == 0) out[64] = aux[0];
}

// ---------------------------------------------------------------------------
extern "C" void kernel_launch(void* const* d_in, const int* in_sizes, int n_in,
                              void* d_out, int out_size, void* d_ws, size_t ws_size,
                              hipStream_t stream) {
    (void)in_sizes; (void)n_in; (void)out_size; (void)ws_size;
    const float* x      = (const float*)d_in[0];
    const float* proj_W = (const float*)d_in[1];
    const float* proj_b = (const float*)d_in[2];
    const float* pos    = (const float*)d_in[3];
    const float* ln1_g  = (const float*)d_in[4];
    const float* ln1_b  = (const float*)d_in[5];
    const float* qkv_W  = (const float*)d_in[6];
    const float* qkv_b  = (const float*)d_in[7];
    const float* out_W  = (const float*)d_in[8];
    const float* out_b  = (const float*)d_in[9];
    const float* ln2_g  = (const float*)d_in[10];
    const float* ln2_b  = (const float*)d_in[11];
    const float* gate_W = (const float*)d_in[12];
    const float* w1     = (const float*)d_in[13];
    const float* b1     = (const float*)d_in[14];
    const float* w2     = (const float*)d_in[15];
    const float* b2     = (const float*)d_in[16];
    const float* hl_g   = (const float*)d_in[17];
    const float* hl_b   = (const float*)d_in[18];
    const float* head_W = (const float*)d_in[19];
    const float* head_b = (const float*)d_in[20];
    float* outp = (float*)d_out;

    // workspace layout (float granularity)
    float* ws = (float*)d_ws;
    size_t off = 0;
    auto alloc = [&](size_t n) { float* p = ws + off; off += (n + 63) & ~(size_t)63; return p; };
    float* hidbf_f = alloc((size_t)MAXASSIGN * 256);  // bf16 hid; aliases xtb
    float* h       = alloc((size_t)BT * 128);
    float* zbf_f   = alloc((size_t)(BT + 1) * 64);    // bf16 [16385][128], row BT = zeros
    float* qkvbf_f = alloc((size_t)BT * 192);         // bf16 head-major [3][8][BT][16]
    float* obbf_f  = alloc((size_t)BT * 64);          // bf16 [16384][128]
    float* yw      = alloc((size_t)MAXASSIGN * 128);  // f32
    float* projWt_f= alloc(128 * 448 / 2);
    float* qkvWt_f = alloc(4 * 384 * 128 / 2);
    float* outWt_f = alloc(4 * 128 * 128 / 2);
    float* w1t_f   = alloc((size_t)32 * 512 * 128 / 2);
    float* w2t_f   = alloc((size_t)32 * 128 * 512 / 2);
    float* topw    = alloc(32768);
    float* awt     = alloc(MAXASSIGN);
    float* impc    = alloc(4096);                     // 4 layers x (impS[64][8] + cntS[64][8])
    float* auxp    = alloc(1);
    int* topi      = (int*)alloc(32768);
    int* atok      = (int*)alloc(MAXASSIGN);
    int* tokpos    = (int*)alloc(32768);
    int* moff      = (int*)alloc(32);

    __hip_bfloat16* hidbf  = (__hip_bfloat16*)hidbf_f;
    __hip_bfloat16* xtb    = (__hip_bfloat16*)hidbf_f;   // alias: dead after proj
    __hip_bfloat16* zbf    = (__hip_bfloat16*)zbf_f;
    __hip_bfloat16* qkvbf  = (__hip_bfloat16*)qkvbf_f;
    __hip_bfloat16* obbf   = (__hip_bfloat16*)obbf_f;
    __hip_bfloat16* projWt = (__hip_bfloat16*)projWt_f;
    __hip_bfloat16* qkvWt  = (__hip_bfloat16*)qkvWt_f;
    __hip_bfloat16* outWt  = (__hip_bfloat16*)outWt_f;
    __hip_bfloat16* w1t    = (__hip_bfloat16*)w1t_f;
    __hip_bfloat16* w2t    = (__hip_bfloat16*)w2t_f;

    // init: aux, all layers' slots, zbf zero gather row (1 launch, was 3 memsets)
    init_kernel<<<1, 256, 0, stream>>>(auxp, impc,
                                       (unsigned*)((char*)zbf + (size_t)BT * 256));

    // input transpose + projconv (1 launch) + all weight conversions (1 launch)
    transpose_kernel<<<480, 256, 0, stream>>>(x, xtb, proj_W, projWt);
    wconvt4_kernel<<<1088, 256, 0, stream>>>(qkv_W, qkvWt, out_W, outWt,
                                             w1, w1t, w2, w2t);

    // proj: h = xtb @ projWt^T + proj_b + pos  (K=448)
    mm_kernel<0, 64><<<dim3(256, 1), 256, 0, stream>>>(
        xtb, projWt, proj_b, pos, h, 448, 128, 0, nullptr, nullptr, nullptr);
    // layer-0 ln1 (subsequent ln1's are fused into combine_ln)
    ln_kernel<<<4096, 256, 0, stream>>>(h, ln1_g, ln1_b, zbf);

    for (int i = 0; i < 4; ++i) {
        float* impS = impc + (size_t)i * 1024;          // per-layer slots
        int*   cntS = (int*)(impc + (size_t)i * 1024 + 512);
        // qkv -> bf16 head-major, Q pre-scaled
        mm_kernel<5, 64><<<dim3(256, 3), 256, 0, stream>>>(
            zbf, qkvWt + (size_t)i * 384 * 128, qkv_b + i * 384, nullptr, qkvbf,
            128, 384, 0, nullptr, nullptr, nullptr);
        attn_kernel<<<dim3(2, 8, 32), 512, 0, stream>>>(qkvbf, obbf);
        mm_kernel<2, 64><<<dim3(256, 1), 256, 0, stream>>>(
            obbf, outWt + (size_t)i * 128 * 128, out_b + i * 128, h, h,
            128, 128, 0, nullptr, nullptr, nullptr);
        ln2gate_kernel<<<4096, 256, 0, stream>>>(h, ln2_g + i * 128, ln2_b + i * 128,
                                                 gate_W + (size_t)i * 128 * 8, zbf,
                                                 topi, topw, impS, cntS);
        // scatter + fused offsets (no fill atomics, no offsets kernel)
        scatter_kernel<<<64, 256, 0, stream>>>(topi, topw, cntS, impS,
                                               atok, awt, tokpos, moff, auxp);
        // moe1: hid = gelu(gather(zbf) @ w1t^T + b1)  -> bf16
        mm_kernel<3, 128><<<dim3(264, 4), 256, 0, stream>>>(
            zbf, w1t + (size_t)i * 8 * 512 * 128, b1 + (size_t)i * 8 * 512, nullptr,
            hidbf, 128, 512, 512 * 128, moff, atok, awt);
        // moe2: yw = (hid @ w2t^T + b2) * awt  -> f32
        mm_kernel<4, 64><<<dim3(528, 1), 256, 0, stream>>>(
            hidbf, w2t + (size_t)i * 8 * 128 * 512, b2 + (size_t)i * 8 * 128, nullptr,
            yw, 512, 128, 128 * 512, moff, atok, awt);
        // combine + next-layer ln1 (fused); last layer: no LN
        combine_ln_kernel<<<4096, 256, 0, stream>>>(yw, tokpos, h,
                                                    ln1_g + (i + 1 < 4 ? (i + 1) * 128 : 0),
                                                    ln1_b + (i + 1 < 4 ? (i + 1) * 128 : 0),
                                                    (i < 3) ? zbf : (__hip_bfloat16*)nullptr);
    }
    head_kernel<<<32, 1024, 0, stream>>>(h, hl_g, hl_b, head_W, head_b, auxp, outp);
}

// Round 11
// 599.862 us; speedup vs baseline: 1.6480x; 1.0665x over previous
//
#include <hip/hip_runtime.h>
#include <hip/hip_bf16.h>
#include <cstdint>
#include <cstddef>

// ---------------------------------------------------------------------------
// Model constants
// ---------------------------------------------------------------------------
#define BT        16384          // B*T tokens
#define MAXASSIGN 33792          // 32768 + 8*127 rounded to 128-aligned segments
#define QSCALE    0.36067376022224085f   // 0.25 * log2(e): fold 1/sqrt(dh) + exp->exp2

typedef __attribute__((ext_vector_type(8)))  short short8;   // 8 bf16 = 1 MFMA frag
typedef __attribute__((ext_vector_type(4)))  short short4v;
typedef __attribute__((ext_vector_type(4)))  float f32x4;
typedef __attribute__((ext_vector_type(16))) float f32x16;

typedef const uint32_t __attribute__((address_space(1))) gas_u32;
typedef uint32_t __attribute__((address_space(3))) las_u32;

// async global->LDS direct copy, 16B per lane; LDS dest = wave base + lane*16
__device__ __forceinline__ void gload16(const void* g, void* l) {
    __builtin_amdgcn_global_load_lds((gas_u32*)g, (las_u32*)l, 16, 0, 0);
}

// gelu(x) = 0.5x(1+tanh(u)) = x*sigmoid(2u), u = sqrt(2/pi)(x+0.044715x^3).
__device__ __forceinline__ float gelu_f(float x) {
    float u2l = (x + 0.044715f * x * x * x) * 2.3022081927f;   // 2u*log2(e)
    float e = exp2f(u2l);
    float r = __builtin_amdgcn_rcpf(e + 1.0f);
    return x * e * r;
}

// pack 2 floats -> 1 u32 of 2 bf16 (RNE), a = low half
__device__ __forceinline__ unsigned pkbf(float a, float b) {
    __hip_bfloat16 ha = __float2bfloat16(a);
    __hip_bfloat16 hb = __float2bfloat16(b);
    unsigned short ua = *reinterpret_cast<unsigned short*>(&ha);
    unsigned short ub = *reinterpret_cast<unsigned short*>(&hb);
    return (unsigned)ua | ((unsigned)ub << 16);
}

__device__ __forceinline__ float bf2f(unsigned short u) {
    unsigned v = (unsigned)u << 16;
    return __uint_as_float(v);
}

// ---------------------------------------------------------------------------
// 0. One-shot init: aux, all 4 layers' router slots, zbf zero gather row.
// ---------------------------------------------------------------------------
__global__ void init_kernel(float* __restrict__ auxp, float* __restrict__ impc,
                            unsigned* __restrict__ zrow) {
    int tid = threadIdx.x;               // 256
    if (tid == 0) auxp[0] = 0.f;
    for (int u = tid; u < 4096; u += 256) impc[u] = 0.f;
    if (tid < 64) zrow[tid] = 0u;        // 128 bf16 = 64 u32
}

// ---------------------------------------------------------------------------
// 1. x [32,55,512,8] -> xtb [16384][448] bf16 (cols 440..447 zero-padded)
//    blocks >= 256 run the (tiny) projconv.
// ---------------------------------------------------------------------------
__global__ __launch_bounds__(256) void transpose_kernel(const float* __restrict__ x,
                                                        __hip_bfloat16* __restrict__ xtb,
                                                        const float* __restrict__ projW,
                                                        __hip_bfloat16* __restrict__ projWt) {
    __shared__ unsigned tile[64][228];   // [t][packed bf16-pair col]; pad 224->228
    if (blockIdx.x >= 256) {             // projconv part: 224 blocks
        int idx = (blockIdx.x - 256) * 256 + threadIdx.x;   // 128*448 exact
        int k = idx % 448, n = idx / 448;
        projWt[idx] = __float2bfloat16(k < 440 ? projW[k * 128 + n] : 0.f);
        return;
    }
    const int b  = blockIdx.x >> 3;      // 32 batches
    const int t0 = (blockIdx.x & 7) * 64;
    const int tid = threadIdx.x;
    tile[tid >> 2][220 + (tid & 3)] = 0u;
    const int tt  = tid >> 2;            // 0..63  (t within tile)
    const int ncp = tid & 3;             // bf16-pair within nb block
    for (int nb = 0; nb < 55; ++nb) {
        const float2* src = (const float2*)(x + (((size_t)(b * 55 + nb)) * 512 + t0) * 8);
        float2 v = src[tid];             // 256 float2 = 64t x 8nc, contiguous
        tile[tt][nb * 4 + ncp] = pkbf(v.x, v.y);
    }
    __syncthreads();
#pragma unroll
    for (int u = 0; u < 14; ++u) {
        int idx = u * 256 + tid;
        int t = idx / 56, c = idx % 56;
        *(uint4*)(xtb + ((size_t)b * 512 + t0 + t) * 448 + c * 8) =
            *(const uint4*)&tile[t][c * 4];
    }
}

// ---------------------------------------------------------------------------
// 2. Weight convert+transpose via LDS tile, all 4 tensors in one launch:
//    [0,48) qkv_W | [48,64) out_W | [64,576) w1 | [576,1088) w2
// ---------------------------------------------------------------------------
__global__ __launch_bounds__(256) void wconvt4_kernel(
    const float* __restrict__ qkvW, __hip_bfloat16* __restrict__ qkvWt_,
    const float* __restrict__ outW, __hip_bfloat16* __restrict__ outWt_,
    const float* __restrict__ w1i, __hip_bfloat16* __restrict__ w1o,
    const float* __restrict__ w2i, __hip_bfloat16* __restrict__ w2o)
{
    __shared__ float tile[64][65];
    const int bid = blockIdx.x;
    const float* in; __hip_bfloat16* out; int K, N, blk;
    if (bid < 48)       { in = qkvW; out = qkvWt_; K = 128; N = 384; blk = bid; }
    else if (bid < 64)  { in = outW; out = outWt_; K = 128; N = 128; blk = bid - 48; }
    else if (bid < 576) { in = w1i;  out = w1o;    K = 128; N = 512; blk = bid - 64; }
    else                { in = w2i;  out = w2o;    K = 512; N = 128; blk = bid - 576; }
    const int kt = K >> 6, nt = N >> 6;
    const int per = kt * nt;
    const int bb  = blk / per;
    const int rem = blk % per;
    const int k0  = (rem / nt) << 6;
    const int n0  = (rem % nt) << 6;
    const int tid = threadIdx.x;

    const float* src = in + ((size_t)bb * K + k0) * N + n0;
    int tk = tid >> 4;               // 0..15
    int tn = (tid & 15) * 4;         // 0..60
#pragma unroll
    for (int r = 0; r < 4; ++r) {
        float4 v = *(const float4*)(src + (size_t)(tk + r * 16) * N + tn);
        tile[tk + r * 16][tn]     = v.x;
        tile[tk + r * 16][tn + 1] = v.y;
        tile[tk + r * 16][tn + 2] = v.z;
        tile[tk + r * 16][tn + 3] = v.w;
    }
    __syncthreads();
    int on = tid >> 2;               // 0..63
    int ok = (tid & 3) * 16;         // 0,16,32,48
    unsigned pk[8];
#pragma unroll
    for (int u = 0; u < 8; ++u)
        pk[u] = pkbf(tile[ok + 2 * u][on], tile[ok + 2 * u + 1][on]);
    uint4* dst = (uint4*)(out + ((size_t)bb * N + n0 + on) * K + k0 + ok);
    dst[0] = (uint4){pk[0], pk[1], pk[2], pk[3]};
    dst[1] = (uint4){pk[4], pk[5], pk[6], pk[7]};
}

// ---------------------------------------------------------------------------
// 3. bf16 MFMA GEMM, templated <MODE, BM> (per-mode DCE; BM = row-tile).
//    BM=128: 4 waves 2x2, 4x4 frags. BM=64: 2x4 frags (2x grid for the
//    latency-bound K=64..128 GEMMs — R18-measured win; R22: moe1 too).
//    mfma_f32_16x16x32_bf16, operand-swapped (acc = C^T frags). LDS
//    chunk-XOR swizzle; global_load_lds width-16 linear-dest staging with
//    inverse-swizzled global source. LDS-repack epilogue, coalesced stores.
//    MODE 0: proj, f32 out + pos.   MODE 2: out-proj, f32 residual add.
//    MODE 3: moe1, gathered A (atok), gelu, bf16 out.
//    MODE 4: moe2, bf16 out * awt (R22: was f32; halves write traffic).
//    MODE 5: qkv, bf16 HEAD-MAJOR [part][h][token][16], Q pre-scaled.
// ---------------------------------------------------------------------------
template<int MODE, int BM>
__global__ __launch_bounds__(256) void mm_kernel(
    const __hip_bfloat16* __restrict__ A, const __hip_bfloat16* __restrict__ Wt,
    const float* __restrict__ bias, const float* __restrict__ extra,
    void* __restrict__ Cout, int K, int N, int wstride,
    const int* __restrict__ moff, const int* __restrict__ atok,
    const float* __restrict__ awt)
{
    constexpr int FI = BM / 32;          // A p-groups / frag rows per wave
    __shared__ short smem[16384];        // 32 KB: As|Bs in K-loop, C-tile after
    short* As = smem;                    // BM*64 shorts
    short* Bs = smem + BM * 64;          // 8192 shorts (128x64)
    const int tid  = threadIdx.x;
    const int row0 = blockIdx.x * BM;
    const int col0 = blockIdx.y * 128;

    const float* bias2 = bias;
    int lim = 0;
    if constexpr (MODE == 3 || MODE == 4) {
        if (row0 >= moff[8]) return;             // segments are 128-aligned
        int e = 0;                               // (64-tile never straddles)
        while (moff[e + 1] <= row0) ++e;
        Wt    += (size_t)e * wstride;
        bias2  = bias + e * N;
        lim    = moff[e] + moff[9 + e];          // valid-assignment end
    }

    const int wave = tid >> 6, lane = tid & 63;
    const int crow = tid >> 3;   // 0..31  (staging row within p-group)
    const int cc   = tid & 7;    // 0..7   (16B chunk within row)

    int srow[FI];
#pragma unroll
    for (int p = 0; p < FI; ++p) {
        int grow = row0 + p * 32 + crow;
        srow[p] = grow;
        if constexpr (MODE == 3)
            srow[p] = (grow < lim) ? atok[grow] : BT;   // pad -> zeroed row
    }

    f32x4 acc[FI][4];
#pragma unroll
    for (int i = 0; i < FI; ++i)
#pragma unroll
        for (int j = 0; j < 4; ++j) acc[i][j] = (f32x4){0.f, 0.f, 0.f, 0.f};

    const int wm = (wave >> 1) * (BM / 2), wn = (wave & 1) * 64;
    const int lr = lane & 15, q = lane >> 4;

    for (int k0 = 0; k0 < K; k0 += 64) {
#pragma unroll
        for (int p = 0; p < FI; ++p) {
            int row = p * 32 + crow;
            int sc  = (cc ^ (row & 7)) << 3;             // swizzled src chunk
            short* la = &As[(p * 32 + wave * 8) * 64];
            gload16(A + (size_t)srow[p] * K + k0 + sc, la);
        }
#pragma unroll
        for (int p = 0; p < 4; ++p) {
            int row = p * 32 + crow;
            int sc  = (cc ^ (row & 7)) << 3;
            short* lb = &Bs[(p * 32 + wave * 8) * 64];
            gload16(Wt + (size_t)(col0 + row) * K + k0 + sc, lb);
        }
        __syncthreads();
#pragma unroll
        for (int s = 0; s < 2; ++s) {
            short8 af[FI], bf[4];
#pragma unroll
            for (int f = 0; f < FI; ++f) {
                int m = wm + f * 16 + lr;
                af[f] = *(const short8*)&As[(m * 8 + ((s * 4 + q) ^ (m & 7))) * 8];
            }
#pragma unroll
            for (int f = 0; f < 4; ++f) {
                int n = wn + f * 16 + lr;
                bf[f] = *(const short8*)&Bs[(n * 8 + ((s * 4 + q) ^ (n & 7))) * 8];
            }
            // swapped operands: acc[i][j] = C^T frag; lane element r is
            // C[token = row0+wm+i*16+lr][col = col0+wn+j*16+q*4+r]
#pragma unroll
            for (int i = 0; i < FI; ++i)
#pragma unroll
                for (int j = 0; j < 4; ++j)
                    acc[i][j] = __builtin_amdgcn_mfma_f32_16x16x32_bf16(
                        bf[j], af[i], acc[i][j], 0, 0, 0);
        }
        __syncthreads();
    }

    // ---- epilogue: bias in-register, LDS repack, coalesced vector stores ----
    float4 b4[4];
#pragma unroll
    for (int j = 0; j < 4; ++j)
        b4[j] = *(const float4*)&bias2[col0 + wn + j * 16 + q * 4];

    if constexpr (MODE == 3 || MODE == 4 || MODE == 5) {
        // bf16 output: BM x 128 bf16 tile, 16B-chunk XOR swizzle
        const bool qsc = (MODE == 5) && (col0 == 0);
#pragma unroll
        for (int i = 0; i < FI; ++i) {
            int trow = wm + i * 16 + lr;
            float aw = 1.f;
            if constexpr (MODE == 4) aw = awt[row0 + trow];
#pragma unroll
            for (int j = 0; j < 4; ++j) {
                int cb = wn + j * 16 + q * 4;
                float v0 = acc[i][j][0] + b4[j].x;
                float v1 = acc[i][j][1] + b4[j].y;
                float v2 = acc[i][j][2] + b4[j].z;
                float v3 = acc[i][j][3] + b4[j].w;
                if constexpr (MODE == 3) {
                    v0 = gelu_f(v0); v1 = gelu_f(v1);
                    v2 = gelu_f(v2); v3 = gelu_f(v3);
                }
                if constexpr (MODE == 4) {
                    v0 *= aw; v1 *= aw; v2 *= aw; v3 *= aw;
                }
                if (qsc) { v0 *= QSCALE; v1 *= QSCALE; v2 *= QSCALE; v3 *= QSCALE; }
                uint2 pk = {pkbf(v0, v1), pkbf(v2, v3)};
                int ch = cb >> 3;
                *(uint2*)((char*)smem + trow * 256 + ((ch ^ (trow & 7)) << 4)
                          + ((cb & 7) << 1)) = pk;
            }
        }
        __syncthreads();
        __hip_bfloat16* outb = (__hip_bfloat16*)Cout;
        constexpr int TPR = 256 / BM;                // threads per row (2 or 4)
        constexpr int CPT = 16 / TPR;                // chunks per thread (8 or 4)
        int rrow = tid / TPR;
        if constexpr (MODE == 3 || MODE == 4) {
            size_t rb = (size_t)(row0 + rrow) * N + col0;
#pragma unroll
            for (int u = 0; u < CPT; ++u) {
                int c = (tid % TPR) * CPT + u;
                uint4 d = *(const uint4*)((char*)smem + rrow * 256
                                          + ((c ^ (rrow & 7)) << 4));
                *(uint4*)(outb + rb + c * 8) = d;
            }
        } else {
            size_t pbase = (size_t)(col0 >> 7) * 8 * BT * 16;
#pragma unroll
            for (int u = 0; u < CPT; ++u) {
                int c = (tid % TPR) * CPT + u;           // h = c>>1, dblk = c&1
                uint4 d = *(const uint4*)((char*)smem + rrow * 256
                                          + ((c ^ (rrow & 7)) << 4));
                size_t dst = pbase + ((size_t)(c >> 1) * BT + row0 + rrow) * 16
                           + (c & 1) * 8;
                *(uint4*)(outb + dst) = d;
            }
        }
    } else {
        // f32 output: 64-row half-tiles ([64][128] f32 = 32 KB), BM/64 passes
        float* outf = (float*)Cout;
        constexpr int HP = BM / 64;
        for (int h = 0; h < HP; ++h) {
            if (HP == 1 || (wm >> 6) == h) {
#pragma unroll
                for (int i = 0; i < FI; ++i) {
                    int trow = (wm & 63) + i * 16 + lr;
#pragma unroll
                    for (int j = 0; j < 4; ++j) {
                        int cb = wn + j * 16 + q * 4;
                        f32x4 v = acc[i][j];
                        v[0] += b4[j].x; v[1] += b4[j].y;
                        v[2] += b4[j].z; v[3] += b4[j].w;
                        int ch = cb >> 2;
                        *(f32x4*)((char*)smem + trow * 512
                                  + ((ch ^ (trow & 7)) << 4)) = v;
                    }
                }
            }
            __syncthreads();
            {
                int rrow = tid >> 2;                     // 0..63
                int grow = row0 + h * 64 + rrow;
                size_t rb = (size_t)grow * N + col0;
#pragma unroll
                for (int u = 0; u < 8; ++u) {
                    int c = (tid & 3) * 8 + u;
                    f32x4 d = *(const f32x4*)((char*)smem + rrow * 512
                                              + ((c ^ (rrow & 7)) << 4));
                    int gcol = col0 + c * 4;
                    if constexpr (MODE == 0) {
                        float4 p = *(const float4*)&extra[(grow & 511) * 128 + gcol];
                        d[0] += p.x; d[1] += p.y; d[2] += p.z; d[3] += p.w;
                    } else if constexpr (MODE == 2) {
                        float4 p = *(const float4*)&extra[rb + c * 4];
                        d[0] += p.x; d[1] += p.y; d[2] += p.z; d[3] += p.w;
                    }
                    *(f32x4*)&outf[rb + c * 4] = d;
                }
            }
            __syncthreads();
        }
    }
}

// ---------------------------------------------------------------------------
// 4. LayerNorm over D=128 -> bf16 zbf (layer-0 ln1 only)
// ---------------------------------------------------------------------------
__global__ __launch_bounds__(256) void ln_kernel(const float* __restrict__ x,
                                                 const float* __restrict__ g,
                                                 const float* __restrict__ b,
                                                 __hip_bfloat16* __restrict__ zbf) {
    int wave = threadIdx.x >> 6, lane = threadIdx.x & 63;
    size_t row = (size_t)blockIdx.x * 4 + wave;
    const float* xr = x + row * 128;
    float a0 = xr[lane], a1 = xr[lane + 64];
    float s = a0 + a1;
#pragma unroll
    for (int off = 32; off > 0; off >>= 1) s += __shfl_xor(s, off);
    float mean = s * (1.f / 128.f);
    float d0 = a0 - mean, d1 = a1 - mean;
    float v = d0 * d0 + d1 * d1;
#pragma unroll
    for (int off = 32; off > 0; off >>= 1) v += __shfl_xor(v, off);
    float inv = rsqrtf(v * (1.f / 128.f) + 1e-5f);
    zbf[row * 128 + lane]      = __float2bfloat16(d0 * inv * g[lane] + b[lane]);
    zbf[row * 128 + lane + 64] = __float2bfloat16(d1 * inv * g[lane + 64] + b[lane + 64]);
}

// ---------------------------------------------------------------------------
// 5. MFMA flash attention v3 — shuffle-free PV + 512 threads (8 waves).
//    qkv is head-major [part][h][token][16] -> fully coalesced staging.
// ---------------------------------------------------------------------------
__global__ __launch_bounds__(512) void attn_kernel(const __hip_bfloat16* __restrict__ qkv,
                                                   __hip_bfloat16* __restrict__ o) {
    __shared__ short Ks[512 * 24];    // K [key][16 used, 24 pitch] : 24 KB
    __shared__ short Vt[17 * 520];    // V^T [col 0..15, 16=ones][key, 520 pitch]
    const int b = blockIdx.z, hh = blockIdx.y, half = blockIdx.x;
    const int tid = threadIdx.x;
    const __hip_bfloat16* Qh = qkv + ((size_t)(0 * 8 + hh) * BT + b * 512) * 16;
    const __hip_bfloat16* Kh = qkv + ((size_t)(1 * 8 + hh) * BT + b * 512) * 16;
    const __hip_bfloat16* Vh = qkv + ((size_t)(2 * 8 + hh) * BT + b * 512) * 16;

    {
        int r = tid;   // 512 threads, 512 keys; 32B/lane contiguous reads
        const uint4* ksrc = (const uint4*)(Kh + (size_t)r * 16);
        uint4 k0 = ksrc[0], k1 = ksrc[1];
        *(uint4*)&Ks[r * 24 + 0] = k0;
        *(uint4*)&Ks[r * 24 + 8] = k1;
        const uint4* vsrc = (const uint4*)(Vh + (size_t)r * 16);
        uint4 v0 = vsrc[0], v1 = vsrc[1];
        unsigned vv[8] = {v0.x, v0.y, v0.z, v0.w, v1.x, v1.y, v1.z, v1.w};
#pragma unroll
        for (int c = 0; c < 8; ++c) {
            Vt[(2 * c)     * 520 + r] = (short)(vv[c] & 0xffff);
            Vt[(2 * c + 1) * 520 + r] = (short)(vv[c] >> 16);
        }
        Vt[16 * 520 + r] = (short)0x3F80;   // 1.0 bf16
    }
    __syncthreads();

    const int wave = tid >> 6, lane = tid & 63;
    const int lm = lane & 31, lh = lane >> 5;
    const int qrow0 = half * 256 + wave * 32;

    short8 qf = *(const short8*)(Qh + (size_t)(qrow0 + lm) * 16 + lh * 8);

    f32x16 accO;
#pragma unroll
    for (int r = 0; r < 16; ++r) accO[r] = 0.f;

    for (int kc = 0; kc < 16; ++kc) {
        short8 kf = *(const short8*)&Ks[(kc * 32 + lm) * 24 + lh * 8];
        int vr = (lm < 16) ? lm : 16;
        const short* vb2 = &Vt[vr * 520 + kc * 32];
        short4v va  = *(const short4v*)(vb2 + 4 * lh);
        short4v vbq = *(const short4v*)(vb2 + 8 + 4 * lh);
        short4v vc  = *(const short4v*)(vb2 + 16 + 4 * lh);
        short4v vd  = *(const short4v*)(vb2 + 24 + 4 * lh);
        short8 vf0, vf1;
#pragma unroll
        for (int j = 0; j < 4; ++j) {
            vf0[j] = va[j];  vf0[4 + j] = vbq[j];
            vf1[j] = vc[j];  vf1[4 + j] = vd[j];
        }
        f32x16 st;
#pragma unroll
        for (int r = 0; r < 16; ++r) st[r] = 0.f;
        st = __builtin_amdgcn_mfma_f32_32x32x16_bf16(kf, qf, st, 0, 0, 0);
        short8 pf0, pf1;
#pragma unroll
        for (int r = 0; r < 8; ++r) {
            pf0[r] = (short)(__float_as_uint(exp2f(st[r]))     >> 16);
            pf1[r] = (short)(__float_as_uint(exp2f(st[8 + r])) >> 16);
        }
        accO = __builtin_amdgcn_mfma_f32_32x32x16_bf16(pf0, vf0, accO, 0, 0, 0);
        accO = __builtin_amdgcn_mfma_f32_32x32x16_bf16(pf1, vf1, accO, 0, 0, 0);
    }

#pragma unroll
    for (int r = 0; r < 16; ++r) {
        float val = accO[r];
        float s = __shfl(val, (lane & 32) + 16);
        if (lm < 16) {
            int qr = qrow0 + (r & 3) + 8 * (r >> 2) + 4 * lh;
            o[((size_t)b * 512 + qr) * 128 + hh * 16 + lm] = __float2bfloat16(val / s);
        }
    }
}

// ---------------------------------------------------------------------------
// 6. Fused LN2 + router. Slot index = blockIdx>>6: slot s aggregates exactly
//    scatter-block s's 256 tokens. Per-layer slots zeroed once in preamble.
// ---------------------------------------------------------------------------
__global__ __launch_bounds__(256) void ln2gate_kernel(
    const float* __restrict__ x, const float* __restrict__ g, const float* __restrict__ b,
    const float* __restrict__ gW, __hip_bfloat16* __restrict__ zbf,
    int* __restrict__ topi, float* __restrict__ topw,
    float* __restrict__ impS, int* __restrict__ cntS)
{
    __shared__ float simp[8];
    __shared__ int scnt[8];
    const int tid = threadIdx.x;
    if (tid < 8) { simp[tid] = 0.f; scnt[tid] = 0; }
    __syncthreads();
    const int wave = tid >> 6, lane = tid & 63;
    const size_t row = (size_t)blockIdx.x * 4 + wave;
    const float* xr = x + row * 128;
    float a0 = xr[lane], a1 = xr[lane + 64];
    float s = a0 + a1;
#pragma unroll
    for (int off = 32; off > 0; off >>= 1) s += __shfl_xor(s, off);
    float mean = s * (1.f / 128.f);
    float d0 = a0 - mean, d1 = a1 - mean;
    float v = d0 * d0 + d1 * d1;
#pragma unroll
    for (int off = 32; off > 0; off >>= 1) v += __shfl_xor(v, off);
    float inv = rsqrtf(v * (1.f / 128.f) + 1e-5f);
    float o0 = d0 * inv * g[lane] + b[lane];
    float o1 = d1 * inv * g[lane + 64] + b[lane + 64];
    zbf[row * 128 + lane]      = __float2bfloat16(o0);
    zbf[row * 128 + lane + 64] = __float2bfloat16(o1);
    // router logits: lg[e] = sum_d z[d]*gW[d][e]
    float4 gA = *(const float4*)&gW[lane * 8];
    float4 gB = *(const float4*)&gW[lane * 8 + 4];
    float4 gC = *(const float4*)&gW[(lane + 64) * 8];
    float4 gD = *(const float4*)&gW[(lane + 64) * 8 + 4];
    float lg[8];
    lg[0] = o0 * gA.x + o1 * gC.x;  lg[1] = o0 * gA.y + o1 * gC.y;
    lg[2] = o0 * gA.z + o1 * gC.z;  lg[3] = o0 * gA.w + o1 * gC.w;
    lg[4] = o0 * gB.x + o1 * gD.x;  lg[5] = o0 * gB.y + o1 * gD.y;
    lg[6] = o0 * gB.z + o1 * gD.z;  lg[7] = o0 * gB.w + o1 * gD.w;
#pragma unroll
    for (int e = 0; e < 8; ++e)
#pragma unroll
        for (int off = 32; off > 0; off >>= 1) lg[e] += __shfl_xor(lg[e], off);
    if (lane == 0) {
        float p[8];
        float mx = lg[0];
#pragma unroll
        for (int k = 1; k < 8; ++k) mx = fmaxf(mx, lg[k]);
        float ssum = 0.f;
#pragma unroll
        for (int k = 0; k < 8; ++k) { p[k] = expf(lg[k] - mx); ssum += p[k]; }
        float pinv = 1.f / ssum;
#pragma unroll
        for (int k = 0; k < 8; ++k) p[k] *= pinv;
        int i0 = 0; float v0 = p[0];
#pragma unroll
        for (int k = 1; k < 8; ++k) if (p[k] > v0) { v0 = p[k]; i0 = k; }
        int i1 = -1; float v1 = -1.f;
#pragma unroll
        for (int k = 0; k < 8; ++k) if (k != i0 && p[k] > v1) { v1 = p[k]; i1 = k; }
        float wsum = v0 + v1;
        topi[row * 2] = i0;  topi[row * 2 + 1] = i1;
        topw[row * 2] = v0 / wsum;  topw[row * 2 + 1] = v1 / wsum;
#pragma unroll
        for (int k = 0; k < 8; ++k) atomicAdd(&simp[k], p[k]);
        atomicAdd(&scnt[i0], 1); atomicAdd(&scnt[i1], 1);
    }
    __syncthreads();
    if (tid < 8) {
        int slot = (blockIdx.x >> 6) * 8 + tid;     // slot s = scatter block s
        atomicAdd(&impS[slot], simp[tid]);
        atomicAdd(&cntS[slot], scnt[tid]);
    }
}

// ---------------------------------------------------------------------------
// 8. Scatter + fused offsets. Each of the 64 blocks redundantly reduces the
//    64x8 slot table (L2-hot); prefix over slots < blk gives deterministic
//    per-expert base. Block 0 writes moff[] + aux. No global fill atomics.
// ---------------------------------------------------------------------------
__global__ __launch_bounds__(256) void scatter_kernel(
    const int* __restrict__ topi, const float* __restrict__ topw,
    const int* __restrict__ cntS, const float* __restrict__ impS,
    int* __restrict__ atok, float* __restrict__ awt, int* __restrict__ tokpos,
    int* __restrict__ moffw, float* __restrict__ aux)
{
    __shared__ int lcnt[8];
    __shared__ int lbase[8];
    __shared__ int csum[8];
    __shared__ float isum[8];
    const int tid = threadIdx.x;
    const int blk = blockIdx.x;                  // 0..63
    if (tid < 64) {                              // wave 0, all lanes active
        int e = tid & 7, grp = tid >> 3;
        int ct = 0, cp = 0; float im = 0.f;
        for (int g = 0; g < 8; ++g) {
            int sl = grp * 8 + g;
            int vv = cntS[sl * 8 + e];
            ct += vv;
            cp += (sl < blk) ? vv : 0;
            im += impS[sl * 8 + e];
        }
#pragma unroll
        for (int off = 32; off >= 8; off >>= 1) {
            ct += __shfl_down(ct, off);
            cp += __shfl_down(cp, off);
            im += __shfl_down(im, off);
        }
        if (tid < 8) { csum[tid] = ct; isum[tid] = im; lbase[tid] = cp; lcnt[tid] = 0; }
    }
    __syncthreads();
    if (tid < 8) {
        int t = 0;
        for (int k = 0; k < tid; ++k) t += (csum[k] + 127) & ~127;   // moff[tid]
        lbase[tid] += t;                         // moff[e] + prefix-before-block
    }
    if (blk == 0 && tid == 64) {                 // separate lane: write moff + aux
        int t = 0; float s = 0.f;
        for (int k = 0; k < 8; ++k) {
            int ck = csum[k];
            moffw[k] = t;
            moffw[9 + k] = ck;
            t += (ck + 127) & ~127;
            s += (isum[k] * (1.f / 16384.f)) * ((float)ck * (1.f / 16384.f));
        }
        moffw[8] = t;
        aux[0] += 8.f * s;
    }
    __syncthreads();
    const int token = blk * 256 + tid;
    const int e0 = topi[token * 2], e1 = topi[token * 2 + 1];
    const float w0 = topw[token * 2], w1 = topw[token * 2 + 1];
    const int l0 = atomicAdd(&lcnt[e0], 1);
    const int l1 = atomicAdd(&lcnt[e1], 1);      // e1 != e0 (top-2 distinct)
    const int p0 = lbase[e0] + l0;
    const int p1 = lbase[e1] + l1;
    atok[p0] = token;  awt[p0] = w0;  tokpos[token * 2]     = p0;
    atok[p1] = token;  awt[p1] = w1;  tokpos[token * 2 + 1] = p1;
}

// ---------------------------------------------------------------------------
// 9. Fused combine + next-layer LN1: h += expert outputs (bf16 yw, R22);
//    optional LN -> zbf
// ---------------------------------------------------------------------------
__global__ __launch_bounds__(256) void combine_ln_kernel(
    const __hip_bfloat16* __restrict__ yw, const int* __restrict__ tokpos,
    float* __restrict__ h, const float* __restrict__ g, const float* __restrict__ b,
    __hip_bfloat16* __restrict__ zbf)
{
    const int tid = threadIdx.x;
    const int wave = tid >> 6, lane = tid & 63;
    const size_t row = (size_t)blockIdx.x * 4 + wave;
    const int p0 = tokpos[row * 2], p1 = tokpos[row * 2 + 1];
    const unsigned short* y0 = (const unsigned short*)(yw + (size_t)p0 * 128);
    const unsigned short* y1 = (const unsigned short*)(yw + (size_t)p1 * 128);
    float a0 = h[row * 128 + lane]      + bf2f(y0[lane])      + bf2f(y1[lane]);
    float a1 = h[row * 128 + lane + 64] + bf2f(y0[lane + 64]) + bf2f(y1[lane + 64]);
    h[row * 128 + lane]      = a0;
    h[row * 128 + lane + 64] = a1;
    if (zbf) {
        float s = a0 + a1;
#pragma unroll
        for (int off = 32; off > 0; off >>= 1) s += __shfl_xor(s, off);
        float mean = s * (1.f / 128.f);
        float d0 = a0 - mean, d1 = a1 - mean;
        float v = d0 * d0 + d1 * d1;
#pragma unroll
        for (int off = 32; off > 0; off >>= 1) v += __shfl_xor(v, off);
        float inv = rsqrtf(v * (1.f / 128.f) + 1e-5f);
        zbf[row * 128 + lane]      = __float2bfloat16(d0 * inv * g[lane] + b[lane]);
        zbf[row * 128 + lane + 64] = __float2bfloat16(d1 * inv * g[lane + 64] + b[lane + 64]);
    }
}

// ---------------------------------------------------------------------------
// 10. mean over T -> LN -> head matmul [128,2]; writes aux scalar
// ---------------------------------------------------------------------------
__global__ __launch_bounds__(1024) void head_kernel(const float* __restrict__ h,
                                                    const float* __restrict__ g,
                                                    const float* __restrict__ bb,
                                                    const float* __restrict__ hW,
                                                    const float* __restrict__ hb,
                                                    const float* __restrict__ aux,
                                                    float* __restrict__ out) {
    __shared__ float part[8][128];
    __shared__ float red[128];
    __shared__ float pl[128];
    int b = blockIdx.x, tid = threadIdx.x;
    int c = tid & 127, w = tid >> 7;            // w = 0..7
    float s = 0.f;
    for (int t = w; t < 512; t += 8) s += h[((size_t)b * 512 + t) * 128 + c];
    part[w][c] = s;
    __syncthreads();
    float pooled = 0.f;
    if (tid < 128) {
#pragma unroll
        for (int k = 0; k < 8; ++k) pooled += part[k][tid];
        pooled *= (1.f / 512.f);
        red[tid] = pooled;
    }
    __syncthreads();
    for (int st = 64; st > 0; st >>= 1) { if (tid < st) red[tid] += red[tid + st]; __syncthreads(); }
    float mean = red[0] * (1.f / 128.f);
    __syncthreads();
    float d = pooled - mean;
    if (tid < 128) red[tid] = d * d;
    __syncthreads();
    for (int st = 64; st > 0; st >>= 1) { if (tid < st) red[tid] += red[tid + st]; __syncthreads(); }
    float var = red[0] * (1.f / 128.f);
    if (tid < 128) pl[tid] = d / sqrtf(var + 1e-5f) * g[tid] + bb[tid];
    __syncthreads();
    if (tid < 2) {
        float acc = hb[tid];
        for (int k = 0; k < 128; ++k) acc += pl[k] * hW[k * 2 + tid];
        out[b * 2 + tid] = acc;
    }
    if (b == 0 && tid == 0) out[64] = aux[0];
}

// ---------------------------------------------------------------------------
extern "C" void kernel_launch(void* const* d_in, const int* in_sizes, int n_in,
                              void* d_out, int out_size, void* d_ws, size_t ws_size,
                              hipStream_t stream) {
    (void)in_sizes; (void)n_in; (void)out_size; (void)ws_size;
    const float* x      = (const float*)d_in[0];
    const float* proj_W = (const float*)d_in[1];
    const float* proj_b = (const float*)d_in[2];
    const float* pos    = (const float*)d_in[3];
    const float* ln1_g  = (const float*)d_in[4];
    const float* ln1_b  = (const float*)d_in[5];
    const float* qkv_W  = (const float*)d_in[6];
    const float* qkv_b  = (const float*)d_in[7];
    const float* out_W  = (const float*)d_in[8];
    const float* out_b  = (const float*)d_in[9];
    const float* ln2_g  = (const float*)d_in[10];
    const float* ln2_b  = (const float*)d_in[11];
    const float* gate_W = (const float*)d_in[12];
    const float* w1     = (const float*)d_in[13];
    const float* b1     = (const float*)d_in[14];
    const float* w2     = (const float*)d_in[15];
    const float* b2     = (const float*)d_in[16];
    const float* hl_g   = (const float*)d_in[17];
    const float* hl_b   = (const float*)d_in[18];
    const float* head_W = (const float*)d_in[19];
    const float* head_b = (const float*)d_in[20];
    float* outp = (float*)d_out;

    // workspace layout (float granularity)
    float* ws = (float*)d_ws;
    size_t off = 0;
    auto alloc = [&](size_t n) { float* p = ws + off; off += (n + 63) & ~(size_t)63; return p; };
    float* hidbf_f = alloc((size_t)MAXASSIGN * 256);  // bf16 hid; aliases xtb
    float* h       = alloc((size_t)BT * 128);
    float* zbf_f   = alloc((size_t)(BT + 1) * 64);    // bf16 [16385][128], row BT = zeros
    float* qkvbf_f = alloc((size_t)BT * 192);         // bf16 head-major [3][8][BT][16]
    float* obbf_f  = alloc((size_t)BT * 64);          // bf16 [16384][128]
    float* yw      = alloc((size_t)MAXASSIGN * 64);   // bf16 [MAXASSIGN][128] (R22)
    float* projWt_f= alloc(128 * 448 / 2);
    float* qkvWt_f = alloc(4 * 384 * 128 / 2);
    float* outWt_f = alloc(4 * 128 * 128 / 2);
    float* w1t_f   = alloc((size_t)32 * 512 * 128 / 2);
    float* w2t_f   = alloc((size_t)32 * 128 * 512 / 2);
    float* topw    = alloc(32768);
    float* awt     = alloc(MAXASSIGN);
    float* impc    = alloc(4096);                     // 4 layers x (impS[64][8] + cntS[64][8])
    float* auxp    = alloc(1);
    int* topi      = (int*)alloc(32768);
    int* atok      = (int*)alloc(MAXASSIGN);
    int* tokpos    = (int*)alloc(32768);
    int* moff      = (int*)alloc(32);

    __hip_bfloat16* hidbf  = (__hip_bfloat16*)hidbf_f;
    __hip_bfloat16* xtb    = (__hip_bfloat16*)hidbf_f;   // alias: dead after proj
    __hip_bfloat16* zbf    = (__hip_bfloat16*)zbf_f;
    __hip_bfloat16* qkvbf  = (__hip_bfloat16*)qkvbf_f;
    __hip_bfloat16* obbf   = (__hip_bfloat16*)obbf_f;
    __hip_bfloat16* ywb    = (__hip_bfloat16*)yw;
    __hip_bfloat16* projWt = (__hip_bfloat16*)projWt_f;
    __hip_bfloat16* qkvWt  = (__hip_bfloat16*)qkvWt_f;
    __hip_bfloat16* outWt  = (__hip_bfloat16*)outWt_f;
    __hip_bfloat16* w1t    = (__hip_bfloat16*)w1t_f;
    __hip_bfloat16* w2t    = (__hip_bfloat16*)w2t_f;

    // init: aux, all layers' slots, zbf zero gather row (1 launch)
    init_kernel<<<1, 256, 0, stream>>>(auxp, impc,
                                       (unsigned*)((char*)zbf + (size_t)BT * 256));

    // input transpose + projconv (1 launch) + all weight conversions (1 launch)
    transpose_kernel<<<480, 256, 0, stream>>>(x, xtb, proj_W, projWt);
    wconvt4_kernel<<<1088, 256, 0, stream>>>(qkv_W, qkvWt, out_W, outWt,
                                             w1, w1t, w2, w2t);

    // proj: h = xtb @ projWt^T + proj_b + pos  (K=448)
    mm_kernel<0, 64><<<dim3(256, 1), 256, 0, stream>>>(
        xtb, projWt, proj_b, pos, h, 448, 128, 0, nullptr, nullptr, nullptr);
    // layer-0 ln1 (subsequent ln1's are fused into combine_ln)
    ln_kernel<<<4096, 256, 0, stream>>>(h, ln1_g, ln1_b, zbf);

    for (int i = 0; i < 4; ++i) {
        float* impS = impc + (size_t)i * 1024;          // per-layer slots
        int*   cntS = (int*)(impc + (size_t)i * 1024 + 512);
        // qkv -> bf16 head-major, Q pre-scaled
        mm_kernel<5, 64><<<dim3(256, 3), 256, 0, stream>>>(
            zbf, qkvWt + (size_t)i * 384 * 128, qkv_b + i * 384, nullptr, qkvbf,
            128, 384, 0, nullptr, nullptr, nullptr);
        attn_kernel<<<dim3(2, 8, 32), 512, 0, stream>>>(qkvbf, obbf);
        mm_kernel<2, 64><<<dim3(256, 1), 256, 0, stream>>>(
            obbf, outWt + (size_t)i * 128 * 128, out_b + i * 128, h, h,
            128, 128, 0, nullptr, nullptr, nullptr);
        ln2gate_kernel<<<4096, 256, 0, stream>>>(h, ln2_g + i * 128, ln2_b + i * 128,
                                                 gate_W + (size_t)i * 128 * 8, zbf,
                                                 topi, topw, impS, cntS);
        // scatter + fused offsets (no fill atomics, no offsets kernel)
        scatter_kernel<<<64, 256, 0, stream>>>(topi, topw, cntS, impS,
                                               atok, awt, tokpos, moff, auxp);
        // moe1: hid = gelu(gather(zbf) @ w1t^T + b1)  -> bf16  (R22: BM=64)
        mm_kernel<3, 64><<<dim3(528, 4), 256, 0, stream>>>(
            zbf, w1t + (size_t)i * 8 * 512 * 128, b1 + (size_t)i * 8 * 512, nullptr,
            hidbf, 128, 512, 512 * 128, moff, atok, awt);
        // moe2: yw = bf16((hid @ w2t^T + b2) * awt)  (R22: bf16 out)
        mm_kernel<4, 64><<<dim3(528, 1), 256, 0, stream>>>(
            hidbf, w2t + (size_t)i * 8 * 128 * 512, b2 + (size_t)i * 8 * 128, nullptr,
            ywb, 512, 128, 128 * 512, moff, atok, awt);
        // combine + next-layer ln1 (fused); last layer: no LN
        combine_ln_kernel<<<4096, 256, 0, stream>>>(ywb, tokpos, h,
                                                    ln1_g + (i + 1 < 4 ? (i + 1) * 128 : 0),
                                                    ln1_b + (i + 1 < 4 ? (i + 1) * 128 : 0),
                                                    (i < 3) ? zbf : (__hip_bfloat16*)nullptr);
    }
    head_kernel<<<32, 1024, 0, stream>>>(h, hl_g, hl_b, head_W, head_b, auxp, outp);
}

// Round 12
// 599.572 us; speedup vs baseline: 1.6488x; 1.0005x over previous
//
#include <hip/hip_runtime.h>
#include <hip/hip_bf16.h>
#include <cstdint>
#include <cstddef>

// ---------------------------------------------------------------------------
// Model constants
// ---------------------------------------------------------------------------
#define BT        16384          // B*T tokens
#define MAXASSIGN 33792          // 32768 + 8*127 rounded to 128-aligned segments
#define QSCALE    0.36067376022224085f   // 0.25 * log2(e): fold 1/sqrt(dh) + exp->exp2

typedef __attribute__((ext_vector_type(8)))  short short8;   // 8 bf16 = 1 MFMA frag
typedef __attribute__((ext_vector_type(4)))  short short4v;
typedef __attribute__((ext_vector_type(4)))  float f32x4;
typedef __attribute__((ext_vector_type(16))) float f32x16;

typedef const uint32_t __attribute__((address_space(1))) gas_u32;
typedef uint32_t __attribute__((address_space(3))) las_u32;

// async global->LDS direct copy, 16B per lane; LDS dest = wave base + lane*16
__device__ __forceinline__ void gload16(const void* g, void* l) {
    __builtin_amdgcn_global_load_lds((gas_u32*)g, (las_u32*)l, 16, 0, 0);
}

// gelu(x) = 0.5x(1+tanh(u)) = x*sigmoid(2u), u = sqrt(2/pi)(x+0.044715x^3).
__device__ __forceinline__ float gelu_f(float x) {
    float u2l = (x + 0.044715f * x * x * x) * 2.3022081927f;   // 2u*log2(e)
    float e = exp2f(u2l);
    float r = __builtin_amdgcn_rcpf(e + 1.0f);
    return x * e * r;
}

// pack 2 floats -> 1 u32 of 2 bf16 (RNE), a = low half
__device__ __forceinline__ unsigned pkbf(float a, float b) {
    __hip_bfloat16 ha = __float2bfloat16(a);
    __hip_bfloat16 hb = __float2bfloat16(b);
    unsigned short ua = *reinterpret_cast<unsigned short*>(&ha);
    unsigned short ub = *reinterpret_cast<unsigned short*>(&hb);
    return (unsigned)ua | ((unsigned)ub << 16);
}

__device__ __forceinline__ float bf2f(unsigned short u) {
    unsigned v = (unsigned)u << 16;
    return __uint_as_float(v);
}

// ---------------------------------------------------------------------------
// 0. One-shot init: aux, all 4 layers' router slots, zbf zero gather row.
// ---------------------------------------------------------------------------
__global__ void init_kernel(float* __restrict__ auxp, float* __restrict__ impc,
                            unsigned* __restrict__ zrow) {
    int tid = threadIdx.x;               // 256
    if (tid == 0) auxp[0] = 0.f;
    for (int u = tid; u < 4096; u += 256) impc[u] = 0.f;
    if (tid < 64) zrow[tid] = 0u;        // 128 bf16 = 64 u32
}

// ---------------------------------------------------------------------------
// 1. x [32,55,512,8] -> xtb [16384][448] bf16 (cols 440..447 zero-padded)
//    blocks >= 256 run the (tiny) projconv.
// ---------------------------------------------------------------------------
__global__ __launch_bounds__(256) void transpose_kernel(const float* __restrict__ x,
                                                        __hip_bfloat16* __restrict__ xtb,
                                                        const float* __restrict__ projW,
                                                        __hip_bfloat16* __restrict__ projWt) {
    __shared__ unsigned tile[64][228];   // [t][packed bf16-pair col]; pad 224->228
    if (blockIdx.x >= 256) {             // projconv part: 224 blocks
        int idx = (blockIdx.x - 256) * 256 + threadIdx.x;   // 128*448 exact
        int k = idx % 448, n = idx / 448;
        projWt[idx] = __float2bfloat16(k < 440 ? projW[k * 128 + n] : 0.f);
        return;
    }
    const int b  = blockIdx.x >> 3;      // 32 batches
    const int t0 = (blockIdx.x & 7) * 64;
    const int tid = threadIdx.x;
    tile[tid >> 2][220 + (tid & 3)] = 0u;
    const int tt  = tid >> 2;            // 0..63  (t within tile)
    const int ncp = tid & 3;             // bf16-pair within nb block
    for (int nb = 0; nb < 55; ++nb) {
        const float2* src = (const float2*)(x + (((size_t)(b * 55 + nb)) * 512 + t0) * 8);
        float2 v = src[tid];             // 256 float2 = 64t x 8nc, contiguous
        tile[tt][nb * 4 + ncp] = pkbf(v.x, v.y);
    }
    __syncthreads();
#pragma unroll
    for (int u = 0; u < 14; ++u) {
        int idx = u * 256 + tid;
        int t = idx / 56, c = idx % 56;
        *(uint4*)(xtb + ((size_t)b * 512 + t0 + t) * 448 + c * 8) =
            *(const uint4*)&tile[t][c * 4];
    }
}

// ---------------------------------------------------------------------------
// 2. Weight convert+transpose via LDS tile, all 4 tensors in one launch:
//    [0,48) qkv_W | [48,64) out_W | [64,576) w1 | [576,1088) w2
// ---------------------------------------------------------------------------
__global__ __launch_bounds__(256) void wconvt4_kernel(
    const float* __restrict__ qkvW, __hip_bfloat16* __restrict__ qkvWt_,
    const float* __restrict__ outW, __hip_bfloat16* __restrict__ outWt_,
    const float* __restrict__ w1i, __hip_bfloat16* __restrict__ w1o,
    const float* __restrict__ w2i, __hip_bfloat16* __restrict__ w2o)
{
    __shared__ float tile[64][65];
    const int bid = blockIdx.x;
    const float* in; __hip_bfloat16* out; int K, N, blk;
    if (bid < 48)       { in = qkvW; out = qkvWt_; K = 128; N = 384; blk = bid; }
    else if (bid < 64)  { in = outW; out = outWt_; K = 128; N = 128; blk = bid - 48; }
    else if (bid < 576) { in = w1i;  out = w1o;    K = 128; N = 512; blk = bid - 64; }
    else                { in = w2i;  out = w2o;    K = 512; N = 128; blk = bid - 576; }
    const int kt = K >> 6, nt = N >> 6;
    const int per = kt * nt;
    const int bb  = blk / per;
    const int rem = blk % per;
    const int k0  = (rem / nt) << 6;
    const int n0  = (rem % nt) << 6;
    const int tid = threadIdx.x;

    const float* src = in + ((size_t)bb * K + k0) * N + n0;
    int tk = tid >> 4;               // 0..15
    int tn = (tid & 15) * 4;         // 0..60
#pragma unroll
    for (int r = 0; r < 4; ++r) {
        float4 v = *(const float4*)(src + (size_t)(tk + r * 16) * N + tn);
        tile[tk + r * 16][tn]     = v.x;
        tile[tk + r * 16][tn + 1] = v.y;
        tile[tk + r * 16][tn + 2] = v.z;
        tile[tk + r * 16][tn + 3] = v.w;
    }
    __syncthreads();
    int on = tid >> 2;               // 0..63
    int ok = (tid & 3) * 16;         // 0,16,32,48
    unsigned pk[8];
#pragma unroll
    for (int u = 0; u < 8; ++u)
        pk[u] = pkbf(tile[ok + 2 * u][on], tile[ok + 2 * u + 1][on]);
    uint4* dst = (uint4*)(out + ((size_t)bb * N + n0 + on) * K + k0 + ok);
    dst[0] = (uint4){pk[0], pk[1], pk[2], pk[3]};
    dst[1] = (uint4){pk[4], pk[5], pk[6], pk[7]};
}

// ---------------------------------------------------------------------------
// 3. bf16 MFMA GEMM, templated <MODE, BM> (per-mode DCE; BM = row-tile).
//    BM=64: 2x4 frags, 2x grid for the latency-bound K=64..512 GEMMs.
//    mfma_f32_16x16x32_bf16, operand-swapped (acc = C^T frags). LDS
//    chunk-XOR swizzle; global_load_lds width-16 linear-dest staging with
//    inverse-swizzled global source. LDS-repack epilogue, coalesced stores.
//    MODE 0: proj, f32 out + pos.   MODE 2: out-proj, f32 residual add.
//    MODE 3: moe1, gathered A (atok), gelu, bf16 out.
//    MODE 4: moe2, bf16 out * awt.
//    MODE 5: qkv, bf16 HEAD-MAJOR [part][h][token][16], Q pre-scaled.
// ---------------------------------------------------------------------------
template<int MODE, int BM>
__global__ __launch_bounds__(256) void mm_kernel(
    const __hip_bfloat16* __restrict__ A, const __hip_bfloat16* __restrict__ Wt,
    const float* __restrict__ bias, const float* __restrict__ extra,
    void* __restrict__ Cout, int K, int N, int wstride,
    const int* __restrict__ moff, const int* __restrict__ atok,
    const float* __restrict__ awt)
{
    constexpr int FI = BM / 32;          // A p-groups / frag rows per wave
    __shared__ short smem[16384];        // 32 KB: As|Bs in K-loop, C-tile after
    short* As = smem;                    // BM*64 shorts
    short* Bs = smem + BM * 64;          // 8192 shorts (128x64)
    const int tid  = threadIdx.x;
    const int row0 = blockIdx.x * BM;
    const int col0 = blockIdx.y * 128;

    const float* bias2 = bias;
    int lim = 0;
    if constexpr (MODE == 3 || MODE == 4) {
        if (row0 >= moff[8]) return;             // segments are 128-aligned
        int e = 0;                               // (64-tile never straddles)
        while (moff[e + 1] <= row0) ++e;
        Wt    += (size_t)e * wstride;
        bias2  = bias + e * N;
        lim    = moff[e] + moff[9 + e];          // valid-assignment end
    }

    const int wave = tid >> 6, lane = tid & 63;
    const int crow = tid >> 3;   // 0..31  (staging row within p-group)
    const int cc   = tid & 7;    // 0..7   (16B chunk within row)

    int srow[FI];
#pragma unroll
    for (int p = 0; p < FI; ++p) {
        int grow = row0 + p * 32 + crow;
        srow[p] = grow;
        if constexpr (MODE == 3)
            srow[p] = (grow < lim) ? atok[grow] : BT;   // pad -> zeroed row
    }

    f32x4 acc[FI][4];
#pragma unroll
    for (int i = 0; i < FI; ++i)
#pragma unroll
        for (int j = 0; j < 4; ++j) acc[i][j] = (f32x4){0.f, 0.f, 0.f, 0.f};

    const int wm = (wave >> 1) * (BM / 2), wn = (wave & 1) * 64;
    const int lr = lane & 15, q = lane >> 4;

    for (int k0 = 0; k0 < K; k0 += 64) {
#pragma unroll
        for (int p = 0; p < FI; ++p) {
            int row = p * 32 + crow;
            int sc  = (cc ^ (row & 7)) << 3;             // swizzled src chunk
            short* la = &As[(p * 32 + wave * 8) * 64];
            gload16(A + (size_t)srow[p] * K + k0 + sc, la);
        }
#pragma unroll
        for (int p = 0; p < 4; ++p) {
            int row = p * 32 + crow;
            int sc  = (cc ^ (row & 7)) << 3;
            short* lb = &Bs[(p * 32 + wave * 8) * 64];
            gload16(Wt + (size_t)(col0 + row) * K + k0 + sc, lb);
        }
        __syncthreads();
#pragma unroll
        for (int s = 0; s < 2; ++s) {
            short8 af[FI], bf[4];
#pragma unroll
            for (int f = 0; f < FI; ++f) {
                int m = wm + f * 16 + lr;
                af[f] = *(const short8*)&As[(m * 8 + ((s * 4 + q) ^ (m & 7))) * 8];
            }
#pragma unroll
            for (int f = 0; f < 4; ++f) {
                int n = wn + f * 16 + lr;
                bf[f] = *(const short8*)&Bs[(n * 8 + ((s * 4 + q) ^ (n & 7))) * 8];
            }
            // swapped operands: acc[i][j] = C^T frag; lane element r is
            // C[token = row0+wm+i*16+lr][col = col0+wn+j*16+q*4+r]
#pragma unroll
            for (int i = 0; i < FI; ++i)
#pragma unroll
                for (int j = 0; j < 4; ++j)
                    acc[i][j] = __builtin_amdgcn_mfma_f32_16x16x32_bf16(
                        bf[j], af[i], acc[i][j], 0, 0, 0);
        }
        __syncthreads();
    }

    // ---- epilogue: bias in-register, LDS repack, coalesced vector stores ----
    float4 b4[4];
#pragma unroll
    for (int j = 0; j < 4; ++j)
        b4[j] = *(const float4*)&bias2[col0 + wn + j * 16 + q * 4];

    if constexpr (MODE == 3 || MODE == 4 || MODE == 5) {
        // bf16 output: BM x 128 bf16 tile, 16B-chunk XOR swizzle
        const bool qsc = (MODE == 5) && (col0 == 0);
#pragma unroll
        for (int i = 0; i < FI; ++i) {
            int trow = wm + i * 16 + lr;
            float aw = 1.f;
            if constexpr (MODE == 4) aw = awt[row0 + trow];
#pragma unroll
            for (int j = 0; j < 4; ++j) {
                int cb = wn + j * 16 + q * 4;
                float v0 = acc[i][j][0] + b4[j].x;
                float v1 = acc[i][j][1] + b4[j].y;
                float v2 = acc[i][j][2] + b4[j].z;
                float v3 = acc[i][j][3] + b4[j].w;
                if constexpr (MODE == 3) {
                    v0 = gelu_f(v0); v1 = gelu_f(v1);
                    v2 = gelu_f(v2); v3 = gelu_f(v3);
                }
                if constexpr (MODE == 4) {
                    v0 *= aw; v1 *= aw; v2 *= aw; v3 *= aw;
                }
                if (qsc) { v0 *= QSCALE; v1 *= QSCALE; v2 *= QSCALE; v3 *= QSCALE; }
                uint2 pk = {pkbf(v0, v1), pkbf(v2, v3)};
                int ch = cb >> 3;
                *(uint2*)((char*)smem + trow * 256 + ((ch ^ (trow & 7)) << 4)
                          + ((cb & 7) << 1)) = pk;
            }
        }
        __syncthreads();
        __hip_bfloat16* outb = (__hip_bfloat16*)Cout;
        constexpr int TPR = 256 / BM;                // threads per row (2 or 4)
        constexpr int CPT = 16 / TPR;                // chunks per thread (8 or 4)
        int rrow = tid / TPR;
        if constexpr (MODE == 3 || MODE == 4) {
            size_t rb = (size_t)(row0 + rrow) * N + col0;
#pragma unroll
            for (int u = 0; u < CPT; ++u) {
                int c = (tid % TPR) * CPT + u;
                uint4 d = *(const uint4*)((char*)smem + rrow * 256
                                          + ((c ^ (rrow & 7)) << 4));
                *(uint4*)(outb + rb + c * 8) = d;
            }
        } else {
            size_t pbase = (size_t)(col0 >> 7) * 8 * BT * 16;
#pragma unroll
            for (int u = 0; u < CPT; ++u) {
                int c = (tid % TPR) * CPT + u;           // h = c>>1, dblk = c&1
                uint4 d = *(const uint4*)((char*)smem + rrow * 256
                                          + ((c ^ (rrow & 7)) << 4));
                size_t dst = pbase + ((size_t)(c >> 1) * BT + row0 + rrow) * 16
                           + (c & 1) * 8;
                *(uint4*)(outb + dst) = d;
            }
        }
    } else {
        // f32 output: 64-row half-tiles ([64][128] f32 = 32 KB), BM/64 passes
        float* outf = (float*)Cout;
        constexpr int HP = BM / 64;
        for (int h = 0; h < HP; ++h) {
            if (HP == 1 || (wm >> 6) == h) {
#pragma unroll
                for (int i = 0; i < FI; ++i) {
                    int trow = (wm & 63) + i * 16 + lr;
#pragma unroll
                    for (int j = 0; j < 4; ++j) {
                        int cb = wn + j * 16 + q * 4;
                        f32x4 v = acc[i][j];
                        v[0] += b4[j].x; v[1] += b4[j].y;
                        v[2] += b4[j].z; v[3] += b4[j].w;
                        int ch = cb >> 2;
                        *(f32x4*)((char*)smem + trow * 512
                                  + ((ch ^ (trow & 7)) << 4)) = v;
                    }
                }
            }
            __syncthreads();
            {
                int rrow = tid >> 2;                     // 0..63
                int grow = row0 + h * 64 + rrow;
                size_t rb = (size_t)grow * N + col0;
#pragma unroll
                for (int u = 0; u < 8; ++u) {
                    int c = (tid & 3) * 8 + u;
                    f32x4 d = *(const f32x4*)((char*)smem + rrow * 512
                                              + ((c ^ (rrow & 7)) << 4));
                    int gcol = col0 + c * 4;
                    if constexpr (MODE == 0) {
                        float4 p = *(const float4*)&extra[(grow & 511) * 128 + gcol];
                        d[0] += p.x; d[1] += p.y; d[2] += p.z; d[3] += p.w;
                    } else if constexpr (MODE == 2) {
                        float4 p = *(const float4*)&extra[rb + c * 4];
                        d[0] += p.x; d[1] += p.y; d[2] += p.z; d[3] += p.w;
                    }
                    *(f32x4*)&outf[rb + c * 4] = d;
                }
            }
            __syncthreads();
        }
    }
}

// ---------------------------------------------------------------------------
// 4. LayerNorm over D=128 -> bf16 zbf (layer-0 ln1 only)
// ---------------------------------------------------------------------------
__global__ __launch_bounds__(256) void ln_kernel(const float* __restrict__ x,
                                                 const float* __restrict__ g,
                                                 const float* __restrict__ b,
                                                 __hip_bfloat16* __restrict__ zbf) {
    int wave = threadIdx.x >> 6, lane = threadIdx.x & 63;
    size_t row = (size_t)blockIdx.x * 4 + wave;
    const float* xr = x + row * 128;
    float a0 = xr[lane], a1 = xr[lane + 64];
    float s = a0 + a1;
#pragma unroll
    for (int off = 32; off > 0; off >>= 1) s += __shfl_xor(s, off);
    float mean = s * (1.f / 128.f);
    float d0 = a0 - mean, d1 = a1 - mean;
    float v = d0 * d0 + d1 * d1;
#pragma unroll
    for (int off = 32; off > 0; off >>= 1) v += __shfl_xor(v, off);
    float inv = rsqrtf(v * (1.f / 128.f) + 1e-5f);
    zbf[row * 128 + lane]      = __float2bfloat16(d0 * inv * g[lane] + b[lane]);
    zbf[row * 128 + lane + 64] = __float2bfloat16(d1 * inv * g[lane + 64] + b[lane + 64]);
}

// ---------------------------------------------------------------------------
// 5. MFMA flash attention v4 (R23): one block per (b,h), 1024 threads,
//    16 waves x 32 q-rows = all 512 rows. K/V staged ONCE (was twice: once
//    per q-half) and staging split across thread halves (tid<512 K, else V)
//    -> staging serial length ~4x shorter. Math identical to v3.
// ---------------------------------------------------------------------------
__global__ __launch_bounds__(1024) void attn_kernel(const __hip_bfloat16* __restrict__ qkv,
                                                    __hip_bfloat16* __restrict__ o) {
    __shared__ short Ks[512 * 24];    // K [key][16 used, 24 pitch] : 24 KB
    __shared__ short Vt[17 * 520];    // V^T [col 0..15, 16=ones][key, 520 pitch]
    const int hh = blockIdx.x, b = blockIdx.y;
    const int tid = threadIdx.x;
    const __hip_bfloat16* Qh = qkv + ((size_t)(0 * 8 + hh) * BT + b * 512) * 16;
    const __hip_bfloat16* Kh = qkv + ((size_t)(1 * 8 + hh) * BT + b * 512) * 16;
    const __hip_bfloat16* Vh = qkv + ((size_t)(2 * 8 + hh) * BT + b * 512) * 16;

    // ---- stage: tid<512 stages K row tid; tid>=512 stages V row tid-512 ----
    if (tid < 512) {
        int r = tid;
        const uint4* ksrc = (const uint4*)(Kh + (size_t)r * 16);
        uint4 k0 = ksrc[0], k1 = ksrc[1];
        *(uint4*)&Ks[r * 24 + 0] = k0;
        *(uint4*)&Ks[r * 24 + 8] = k1;
    } else {
        int r = tid - 512;
        const uint4* vsrc = (const uint4*)(Vh + (size_t)r * 16);
        uint4 v0 = vsrc[0], v1 = vsrc[1];
        unsigned vv[8] = {v0.x, v0.y, v0.z, v0.w, v1.x, v1.y, v1.z, v1.w};
#pragma unroll
        for (int c = 0; c < 8; ++c) {
            Vt[(2 * c)     * 520 + r] = (short)(vv[c] & 0xffff);
            Vt[(2 * c + 1) * 520 + r] = (short)(vv[c] >> 16);
        }
        Vt[16 * 520 + r] = (short)0x3F80;   // 1.0 bf16
    }
    __syncthreads();

    const int wave = tid >> 6, lane = tid & 63;
    const int lm = lane & 31, lh = lane >> 5;
    const int qrow0 = wave * 32;           // 16 waves x 32 rows = 512

    short8 qf = *(const short8*)(Qh + (size_t)(qrow0 + lm) * 16 + lh * 8);

    f32x16 accO;
#pragma unroll
    for (int r = 0; r < 16; ++r) accO[r] = 0.f;

    for (int kc = 0; kc < 16; ++kc) {
        short8 kf = *(const short8*)&Ks[(kc * 32 + lm) * 24 + lh * 8];
        int vr = (lm < 16) ? lm : 16;    // cols >16 duplicate rowsum (unread)
        const short* vb2 = &Vt[vr * 520 + kc * 32];
        short4v va  = *(const short4v*)(vb2 + 4 * lh);
        short4v vbq = *(const short4v*)(vb2 + 8 + 4 * lh);
        short4v vc  = *(const short4v*)(vb2 + 16 + 4 * lh);
        short4v vd  = *(const short4v*)(vb2 + 24 + 4 * lh);
        short8 vf0, vf1;
#pragma unroll
        for (int j = 0; j < 4; ++j) {
            vf0[j] = va[j];  vf0[4 + j] = vbq[j];
            vf1[j] = vc[j];  vf1[4 + j] = vd[j];
        }
        f32x16 st;
#pragma unroll
        for (int r = 0; r < 16; ++r) st[r] = 0.f;
        st = __builtin_amdgcn_mfma_f32_32x32x16_bf16(kf, qf, st, 0, 0, 0);
        short8 pf0, pf1;
#pragma unroll
        for (int r = 0; r < 8; ++r) {
            pf0[r] = (short)(__float_as_uint(exp2f(st[r]))     >> 16);
            pf1[r] = (short)(__float_as_uint(exp2f(st[8 + r])) >> 16);
        }
        accO = __builtin_amdgcn_mfma_f32_32x32x16_bf16(pf0, vf0, accO, 0, 0, 0);
        accO = __builtin_amdgcn_mfma_f32_32x32x16_bf16(pf1, vf1, accO, 0, 0, 0);
    }

    // ---- epilogue: col n<16 = O_unnorm, col 16 = rowsum ----
#pragma unroll
    for (int r = 0; r < 16; ++r) {
        float val = accO[r];
        float s = __shfl(val, (lane & 32) + 16);   // n=16 lane, same half
        if (lm < 16) {
            int qr = qrow0 + (r & 3) + 8 * (r >> 2) + 4 * lh;
            o[((size_t)b * 512 + qr) * 128 + hh * 16 + lm] = __float2bfloat16(val / s);
        }
    }
}

// ---------------------------------------------------------------------------
// 6. Fused LN2 + router. Slot index = blockIdx>>6: slot s aggregates exactly
//    scatter-block s's 256 tokens. Per-layer slots zeroed once in preamble.
// ---------------------------------------------------------------------------
__global__ __launch_bounds__(256) void ln2gate_kernel(
    const float* __restrict__ x, const float* __restrict__ g, const float* __restrict__ b,
    const float* __restrict__ gW, __hip_bfloat16* __restrict__ zbf,
    int* __restrict__ topi, float* __restrict__ topw,
    float* __restrict__ impS, int* __restrict__ cntS)
{
    __shared__ float simp[8];
    __shared__ int scnt[8];
    const int tid = threadIdx.x;
    if (tid < 8) { simp[tid] = 0.f; scnt[tid] = 0; }
    __syncthreads();
    const int wave = tid >> 6, lane = tid & 63;
    const size_t row = (size_t)blockIdx.x * 4 + wave;
    const float* xr = x + row * 128;
    float a0 = xr[lane], a1 = xr[lane + 64];
    float s = a0 + a1;
#pragma unroll
    for (int off = 32; off > 0; off >>= 1) s += __shfl_xor(s, off);
    float mean = s * (1.f / 128.f);
    float d0 = a0 - mean, d1 = a1 - mean;
    float v = d0 * d0 + d1 * d1;
#pragma unroll
    for (int off = 32; off > 0; off >>= 1) v += __shfl_xor(v, off);
    float inv = rsqrtf(v * (1.f / 128.f) + 1e-5f);
    float o0 = d0 * inv * g[lane] + b[lane];
    float o1 = d1 * inv * g[lane + 64] + b[lane + 64];
    zbf[row * 128 + lane]      = __float2bfloat16(o0);
    zbf[row * 128 + lane + 64] = __float2bfloat16(o1);
    // router logits: lg[e] = sum_d z[d]*gW[d][e]
    float4 gA = *(const float4*)&gW[lane * 8];
    float4 gB = *(const float4*)&gW[lane * 8 + 4];
    float4 gC = *(const float4*)&gW[(lane + 64) * 8];
    float4 gD = *(const float4*)&gW[(lane + 64) * 8 + 4];
    float lg[8];
    lg[0] = o0 * gA.x + o1 * gC.x;  lg[1] = o0 * gA.y + o1 * gC.y;
    lg[2] = o0 * gA.z + o1 * gC.z;  lg[3] = o0 * gA.w + o1 * gC.w;
    lg[4] = o0 * gB.x + o1 * gD.x;  lg[5] = o0 * gB.y + o1 * gD.y;
    lg[6] = o0 * gB.z + o1 * gD.z;  lg[7] = o0 * gB.w + o1 * gD.w;
#pragma unroll
    for (int e = 0; e < 8; ++e)
#pragma unroll
        for (int off = 32; off > 0; off >>= 1) lg[e] += __shfl_xor(lg[e], off);
    if (lane == 0) {
        float p[8];
        float mx = lg[0];
#pragma unroll
        for (int k = 1; k < 8; ++k) mx = fmaxf(mx, lg[k]);
        float ssum = 0.f;
#pragma unroll
        for (int k = 0; k < 8; ++k) { p[k] = expf(lg[k] - mx); ssum += p[k]; }
        float pinv = 1.f / ssum;
#pragma unroll
        for (int k = 0; k < 8; ++k) p[k] *= pinv;
        int i0 = 0; float v0 = p[0];
#pragma unroll
        for (int k = 1; k < 8; ++k) if (p[k] > v0) { v0 = p[k]; i0 = k; }
        int i1 = -1; float v1 = -1.f;
#pragma unroll
        for (int k = 0; k < 8; ++k) if (k != i0 && p[k] > v1) { v1 = p[k]; i1 = k; }
        float wsum = v0 + v1;
        topi[row * 2] = i0;  topi[row * 2 + 1] = i1;
        topw[row * 2] = v0 / wsum;  topw[row * 2 + 1] = v1 / wsum;
#pragma unroll
        for (int k = 0; k < 8; ++k) atomicAdd(&simp[k], p[k]);
        atomicAdd(&scnt[i0], 1); atomicAdd(&scnt[i1], 1);
    }
    __syncthreads();
    if (tid < 8) {
        int slot = (blockIdx.x >> 6) * 8 + tid;     // slot s = scatter block s
        atomicAdd(&impS[slot], simp[tid]);
        atomicAdd(&cntS[slot], scnt[tid]);
    }
}

// ---------------------------------------------------------------------------
// 8. Scatter + fused offsets. Each of the 64 blocks redundantly reduces the
//    64x8 slot table (L2-hot); prefix over slots < blk gives deterministic
//    per-expert base. Block 0 writes moff[] + aux. No global fill atomics.
// ---------------------------------------------------------------------------
__global__ __launch_bounds__(256) void scatter_kernel(
    const int* __restrict__ topi, const float* __restrict__ topw,
    const int* __restrict__ cntS, const float* __restrict__ impS,
    int* __restrict__ atok, float* __restrict__ awt, int* __restrict__ tokpos,
    int* __restrict__ moffw, float* __restrict__ aux)
{
    __shared__ int lcnt[8];
    __shared__ int lbase[8];
    __shared__ int csum[8];
    __shared__ float isum[8];
    const int tid = threadIdx.x;
    const int blk = blockIdx.x;                  // 0..63
    if (tid < 64) {                              // wave 0, all lanes active
        int e = tid & 7, grp = tid >> 3;
        int ct = 0, cp = 0; float im = 0.f;
        for (int g = 0; g < 8; ++g) {
            int sl = grp * 8 + g;
            int vv = cntS[sl * 8 + e];
            ct += vv;
            cp += (sl < blk) ? vv : 0;
            im += impS[sl * 8 + e];
        }
#pragma unroll
        for (int off = 32; off >= 8; off >>= 1) {
            ct += __shfl_down(ct, off);
            cp += __shfl_down(cp, off);
            im += __shfl_down(im, off);
        }
        if (tid < 8) { csum[tid] = ct; isum[tid] = im; lbase[tid] = cp; lcnt[tid] = 0; }
    }
    __syncthreads();
    if (tid < 8) {
        int t = 0;
        for (int k = 0; k < tid; ++k) t += (csum[k] + 127) & ~127;   // moff[tid]
        lbase[tid] += t;                         // moff[e] + prefix-before-block
    }
    if (blk == 0 && tid == 64) {                 // separate lane: write moff + aux
        int t = 0; float s = 0.f;
        for (int k = 0; k < 8; ++k) {
            int ck = csum[k];
            moffw[k] = t;
            moffw[9 + k] = ck;
            t += (ck + 127) & ~127;
            s += (isum[k] * (1.f / 16384.f)) * ((float)ck * (1.f / 16384.f));
        }
        moffw[8] = t;
        aux[0] += 8.f * s;
    }
    __syncthreads();
    const int token = blk * 256 + tid;
    const int e0 = topi[token * 2], e1 = topi[token * 2 + 1];
    const float w0 = topw[token * 2], w1 = topw[token * 2 + 1];
    const int l0 = atomicAdd(&lcnt[e0], 1);
    const int l1 = atomicAdd(&lcnt[e1], 1);      // e1 != e0 (top-2 distinct)
    const int p0 = lbase[e0] + l0;
    const int p1 = lbase[e1] + l1;
    atok[p0] = token;  awt[p0] = w0;  tokpos[token * 2]     = p0;
    atok[p1] = token;  awt[p1] = w1;  tokpos[token * 2 + 1] = p1;
}

// ---------------------------------------------------------------------------
// 9. Fused combine + next-layer LN1: h += expert outputs (bf16 yw);
//    optional LN -> zbf
// ---------------------------------------------------------------------------
__global__ __launch_bounds__(256) void combine_ln_kernel(
    const __hip_bfloat16* __restrict__ yw, const int* __restrict__ tokpos,
    float* __restrict__ h, const float* __restrict__ g, const float* __restrict__ b,
    __hip_bfloat16* __restrict__ zbf)
{
    const int tid = threadIdx.x;
    const int wave = tid >> 6, lane = tid & 63;
    const size_t row = (size_t)blockIdx.x * 4 + wave;
    const int p0 = tokpos[row * 2], p1 = tokpos[row * 2 + 1];
    const unsigned short* y0 = (const unsigned short*)(yw + (size_t)p0 * 128);
    const unsigned short* y1 = (const unsigned short*)(yw + (size_t)p1 * 128);
    float a0 = h[row * 128 + lane]      + bf2f(y0[lane])      + bf2f(y1[lane]);
    float a1 = h[row * 128 + lane + 64] + bf2f(y0[lane + 64]) + bf2f(y1[lane + 64]);
    h[row * 128 + lane]      = a0;
    h[row * 128 + lane + 64] = a1;
    if (zbf) {
        float s = a0 + a1;
#pragma unroll
        for (int off = 32; off > 0; off >>= 1) s += __shfl_xor(s, off);
        float mean = s * (1.f / 128.f);
        float d0 = a0 - mean, d1 = a1 - mean;
        float v = d0 * d0 + d1 * d1;
#pragma unroll
        for (int off = 32; off > 0; off >>= 1) v += __shfl_xor(v, off);
        float inv = rsqrtf(v * (1.f / 128.f) + 1e-5f);
        zbf[row * 128 + lane]      = __float2bfloat16(d0 * inv * g[lane] + b[lane]);
        zbf[row * 128 + lane + 64] = __float2bfloat16(d1 * inv * g[lane + 64] + b[lane + 64]);
    }
}

// ---------------------------------------------------------------------------
// 10. mean over T -> LN -> head matmul [128,2]; writes aux scalar
// ---------------------------------------------------------------------------
__global__ __launch_bounds__(1024) void head_kernel(const float* __restrict__ h,
                                                    const float* __restrict__ g,
                                                    const float* __restrict__ bb,
                                                    const float* __restrict__ hW,
                                                    const float* __restrict__ hb,
                                                    const float* __restrict__ aux,
                                                    float* __restrict__ out) {
    __shared__ float part[8][128];
    __shared__ float red[128];
    __shared__ float pl[128];
    int b = blockIdx.x, tid = threadIdx.x;
    int c = tid & 127, w = tid >> 7;            // w = 0..7
    float s = 0.f;
    for (int t = w; t < 512; t += 8) s += h[((size_t)b * 512 + t) * 128 + c];
    part[w][c] = s;
    __syncthreads();
    float pooled = 0.f;
    if (tid < 128) {
#pragma unroll
        for (int k = 0; k < 8; ++k) pooled += part[k][tid];
        pooled *= (1.f / 512.f);
        red[tid] = pooled;
    }
    __syncthreads();
    for (int st = 64; st > 0; st >>= 1) { if (tid < st) red[tid] += red[tid + st]; __syncthreads(); }
    float mean = red[0] * (1.f / 128.f);
    __syncthreads();
    float d = pooled - mean;
    if (tid < 128) red[tid] = d * d;
    __syncthreads();
    for (int st = 64; st > 0; st >>= 1) { if (tid < st) red[tid] += red[tid + st]; __syncthreads(); }
    float var = red[0] * (1.f / 128.f);
    if (tid < 128) pl[tid] = d / sqrtf(var + 1e-5f) * g[tid] + bb[tid];
    __syncthreads();
    if (tid < 2) {
        float acc = hb[tid];
        for (int k = 0; k < 128; ++k) acc += pl[k] * hW[k * 2 + tid];
        out[b * 2 + tid] = acc;
    }
    if (b == 0 && tid == 0) out[64] = aux[0];
}

// ---------------------------------------------------------------------------
extern "C" void kernel_launch(void* const* d_in, const int* in_sizes, int n_in,
                              void* d_out, int out_size, void* d_ws, size_t ws_size,
                              hipStream_t stream) {
    (void)in_sizes; (void)n_in; (void)out_size; (void)ws_size;
    const float* x      = (const float*)d_in[0];
    const float* proj_W = (const float*)d_in[1];
    const float* proj_b = (const float*)d_in[2];
    const float* pos    = (const float*)d_in[3];
    const float* ln1_g  = (const float*)d_in[4];
    const float* ln1_b  = (const float*)d_in[5];
    const float* qkv_W  = (const float*)d_in[6];
    const float* qkv_b  = (const float*)d_in[7];
    const float* out_W  = (const float*)d_in[8];
    const float* out_b  = (const float*)d_in[9];
    const float* ln2_g  = (const float*)d_in[10];
    const float* ln2_b  = (const float*)d_in[11];
    const float* gate_W = (const float*)d_in[12];
    const float* w1     = (const float*)d_in[13];
    const float* b1     = (const float*)d_in[14];
    const float* w2     = (const float*)d_in[15];
    const float* b2     = (const float*)d_in[16];
    const float* hl_g   = (const float*)d_in[17];
    const float* hl_b   = (const float*)d_in[18];
    const float* head_W = (const float*)d_in[19];
    const float* head_b = (const float*)d_in[20];
    float* outp = (float*)d_out;

    // workspace layout (float granularity)
    float* ws = (float*)d_ws;
    size_t off = 0;
    auto alloc = [&](size_t n) { float* p = ws + off; off += (n + 63) & ~(size_t)63; return p; };
    float* hidbf_f = alloc((size_t)MAXASSIGN * 256);  // bf16 hid; aliases xtb
    float* h       = alloc((size_t)BT * 128);
    float* zbf_f   = alloc((size_t)(BT + 1) * 64);    // bf16 [16385][128], row BT = zeros
    float* qkvbf_f = alloc((size_t)BT * 192);         // bf16 head-major [3][8][BT][16]
    float* obbf_f  = alloc((size_t)BT * 64);          // bf16 [16384][128]
    float* yw      = alloc((size_t)MAXASSIGN * 64);   // bf16 [MAXASSIGN][128]
    float* projWt_f= alloc(128 * 448 / 2);
    float* qkvWt_f = alloc(4 * 384 * 128 / 2);
    float* outWt_f = alloc(4 * 128 * 128 / 2);
    float* w1t_f   = alloc((size_t)32 * 512 * 128 / 2);
    float* w2t_f   = alloc((size_t)32 * 128 * 512 / 2);
    float* topw    = alloc(32768);
    float* awt     = alloc(MAXASSIGN);
    float* impc    = alloc(4096);                     // 4 layers x (impS[64][8] + cntS[64][8])
    float* auxp    = alloc(1);
    int* topi      = (int*)alloc(32768);
    int* atok      = (int*)alloc(MAXASSIGN);
    int* tokpos    = (int*)alloc(32768);
    int* moff      = (int*)alloc(32);

    __hip_bfloat16* hidbf  = (__hip_bfloat16*)hidbf_f;
    __hip_bfloat16* xtb    = (__hip_bfloat16*)hidbf_f;   // alias: dead after proj
    __hip_bfloat16* zbf    = (__hip_bfloat16*)zbf_f;
    __hip_bfloat16* qkvbf  = (__hip_bfloat16*)qkvbf_f;
    __hip_bfloat16* obbf   = (__hip_bfloat16*)obbf_f;
    __hip_bfloat16* ywb    = (__hip_bfloat16*)yw;
    __hip_bfloat16* projWt = (__hip_bfloat16*)projWt_f;
    __hip_bfloat16* qkvWt  = (__hip_bfloat16*)qkvWt_f;
    __hip_bfloat16* outWt  = (__hip_bfloat16*)outWt_f;
    __hip_bfloat16* w1t    = (__hip_bfloat16*)w1t_f;
    __hip_bfloat16* w2t    = (__hip_bfloat16*)w2t_f;

    // init: aux, all layers' slots, zbf zero gather row (1 launch)
    init_kernel<<<1, 256, 0, stream>>>(auxp, impc,
                                       (unsigned*)((char*)zbf + (size_t)BT * 256));

    // input transpose + projconv (1 launch) + all weight conversions (1 launch)
    transpose_kernel<<<480, 256, 0, stream>>>(x, xtb, proj_W, projWt);
    wconvt4_kernel<<<1088, 256, 0, stream>>>(qkv_W, qkvWt, out_W, outWt,
                                             w1, w1t, w2, w2t);

    // proj: h = xtb @ projWt^T + proj_b + pos  (K=448)
    mm_kernel<0, 64><<<dim3(256, 1), 256, 0, stream>>>(
        xtb, projWt, proj_b, pos, h, 448, 128, 0, nullptr, nullptr, nullptr);
    // layer-0 ln1 (subsequent ln1's are fused into combine_ln)
    ln_kernel<<<4096, 256, 0, stream>>>(h, ln1_g, ln1_b, zbf);

    for (int i = 0; i < 4; ++i) {
        float* impS = impc + (size_t)i * 1024;          // per-layer slots
        int*   cntS = (int*)(impc + (size_t)i * 1024 + 512);
        // qkv -> bf16 head-major, Q pre-scaled
        mm_kernel<5, 64><<<dim3(256, 3), 256, 0, stream>>>(
            zbf, qkvWt + (size_t)i * 384 * 128, qkv_b + i * 384, nullptr, qkvbf,
            128, 384, 0, nullptr, nullptr, nullptr);
        attn_kernel<<<dim3(8, 32), 1024, 0, stream>>>(qkvbf, obbf);
        mm_kernel<2, 64><<<dim3(256, 1), 256, 0, stream>>>(
            obbf, outWt + (size_t)i * 128 * 128, out_b + i * 128, h, h,
            128, 128, 0, nullptr, nullptr, nullptr);
        ln2gate_kernel<<<4096, 256, 0, stream>>>(h, ln2_g + i * 128, ln2_b + i * 128,
                                                 gate_W + (size_t)i * 128 * 8, zbf,
                                                 topi, topw, impS, cntS);
        // scatter + fused offsets (no fill atomics, no offsets kernel)
        scatter_kernel<<<64, 256, 0, stream>>>(topi, topw, cntS, impS,
                                               atok, awt, tokpos, moff, auxp);
        // moe1: hid = gelu(gather(zbf) @ w1t^T + b1)  -> bf16
        mm_kernel<3, 64><<<dim3(528, 4), 256, 0, stream>>>(
            zbf, w1t + (size_t)i * 8 * 512 * 128, b1 + (size_t)i * 8 * 512, nullptr,
            hidbf, 128, 512, 512 * 128, moff, atok, awt);
        // moe2: yw = bf16((hid @ w2t^T + b2) * awt)
        mm_kernel<4, 64><<<dim3(528, 1), 256, 0, stream>>>(
            hidbf, w2t + (size_t)i * 8 * 128 * 512, b2 + (size_t)i * 8 * 128, nullptr,
            ywb, 512, 128, 128 * 512, moff, atok, awt);
        // combine + next-layer ln1 (fused); last layer: no LN
        combine_ln_kernel<<<4096, 256, 0, stream>>>(ywb, tokpos, h,
                                                    ln1_g + (i + 1 < 4 ? (i + 1) * 128 : 0),
                                                    ln1_b + (i + 1 < 4 ? (i + 1) * 128 : 0),
                                                    (i < 3) ? zbf : (__hip_bfloat16*)nullptr);
    }
    head_kernel<<<32, 1024, 0, stream>>>(h, hl_g, hl_b, head_W, head_b, auxp, outp);
}

// Round 13
// 557.880 us; speedup vs baseline: 1.7720x; 1.0747x over previous
//
#include <hip/hip_runtime.h>
#include <hip/hip_bf16.h>
#include <cstdint>
#include <cstddef>

// ---------------------------------------------------------------------------
// Model constants
// ---------------------------------------------------------------------------
#define BT        16384          // B*T tokens
#define MAXASSIGN 33792          // 32768 + 8*127 rounded to 128-aligned segments
#define QSCALE    0.36067376022224085f   // 0.25 * log2(e): fold 1/sqrt(dh) + exp->exp2

typedef __attribute__((ext_vector_type(8)))  short short8;   // 8 bf16 = 1 MFMA frag
typedef __attribute__((ext_vector_type(4)))  short short4v;
typedef __attribute__((ext_vector_type(4)))  float f32x4;
typedef __attribute__((ext_vector_type(16))) float f32x16;

typedef const uint32_t __attribute__((address_space(1))) gas_u32;
typedef uint32_t __attribute__((address_space(3))) las_u32;

// async global->LDS direct copy, 16B per lane; LDS dest = wave base + lane*16
__device__ __forceinline__ void gload16(const void* g, void* l) {
    __builtin_amdgcn_global_load_lds((gas_u32*)g, (las_u32*)l, 16, 0, 0);
}

// gelu(x) = 0.5x(1+tanh(u)) = x*sigmoid(2u), u = sqrt(2/pi)(x+0.044715x^3).
__device__ __forceinline__ float gelu_f(float x) {
    float u2l = (x + 0.044715f * x * x * x) * 2.3022081927f;   // 2u*log2(e)
    float e = exp2f(u2l);
    float r = __builtin_amdgcn_rcpf(e + 1.0f);
    return x * e * r;
}

// pack 2 floats -> 1 u32 of 2 bf16 (RNE), a = low half
__device__ __forceinline__ unsigned pkbf(float a, float b) {
    __hip_bfloat16 ha = __float2bfloat16(a);
    __hip_bfloat16 hb = __float2bfloat16(b);
    unsigned short ua = *reinterpret_cast<unsigned short*>(&ha);
    unsigned short ub = *reinterpret_cast<unsigned short*>(&hb);
    return (unsigned)ua | ((unsigned)ub << 16);
}

__device__ __forceinline__ float bf2f(unsigned short u) {
    unsigned v = (unsigned)u << 16;
    return __uint_as_float(v);
}

// ---------------------------------------------------------------------------
// 0. One-shot init: aux, all 4 layers' router slots, zbf zero gather row.
// ---------------------------------------------------------------------------
__global__ void init_kernel(float* __restrict__ auxp, float* __restrict__ impc,
                            unsigned* __restrict__ zrow) {
    int tid = threadIdx.x;               // 256
    if (tid == 0) auxp[0] = 0.f;
    for (int u = tid; u < 4096; u += 256) impc[u] = 0.f;
    if (tid < 64) zrow[tid] = 0u;        // 128 bf16 = 64 u32
}

// ---------------------------------------------------------------------------
// 1. x [32,55,512,8] -> xtb [16384][448] bf16 (cols 440..447 zero-padded)
//    blocks >= 256 run the (tiny) projconv.
// ---------------------------------------------------------------------------
__global__ __launch_bounds__(256) void transpose_kernel(const float* __restrict__ x,
                                                        __hip_bfloat16* __restrict__ xtb,
                                                        const float* __restrict__ projW,
                                                        __hip_bfloat16* __restrict__ projWt) {
    __shared__ unsigned tile[64][228];   // [t][packed bf16-pair col]; pad 224->228
    if (blockIdx.x >= 256) {             // projconv part: 224 blocks
        int idx = (blockIdx.x - 256) * 256 + threadIdx.x;   // 128*448 exact
        int k = idx % 448, n = idx / 448;
        projWt[idx] = __float2bfloat16(k < 440 ? projW[k * 128 + n] : 0.f);
        return;
    }
    const int b  = blockIdx.x >> 3;      // 32 batches
    const int t0 = (blockIdx.x & 7) * 64;
    const int tid = threadIdx.x;
    tile[tid >> 2][220 + (tid & 3)] = 0u;
    const int tt  = tid >> 2;            // 0..63  (t within tile)
    const int ncp = tid & 3;             // bf16-pair within nb block
    for (int nb = 0; nb < 55; ++nb) {
        const float2* src = (const float2*)(x + (((size_t)(b * 55 + nb)) * 512 + t0) * 8);
        float2 v = src[tid];             // 256 float2 = 64t x 8nc, contiguous
        tile[tt][nb * 4 + ncp] = pkbf(v.x, v.y);
    }
    __syncthreads();
#pragma unroll
    for (int u = 0; u < 14; ++u) {
        int idx = u * 256 + tid;
        int t = idx / 56, c = idx % 56;
        *(uint4*)(xtb + ((size_t)b * 512 + t0 + t) * 448 + c * 8) =
            *(const uint4*)&tile[t][c * 4];
    }
}

// ---------------------------------------------------------------------------
// 2. Weight convert+transpose via LDS tile, all 4 tensors in one launch:
//    [0,48) qkv_W | [48,64) out_W | [64,576) w1 | [576,1088) w2
// ---------------------------------------------------------------------------
__global__ __launch_bounds__(256) void wconvt4_kernel(
    const float* __restrict__ qkvW, __hip_bfloat16* __restrict__ qkvWt_,
    const float* __restrict__ outW, __hip_bfloat16* __restrict__ outWt_,
    const float* __restrict__ w1i, __hip_bfloat16* __restrict__ w1o,
    const float* __restrict__ w2i, __hip_bfloat16* __restrict__ w2o)
{
    __shared__ float tile[64][65];
    const int bid = blockIdx.x;
    const float* in; __hip_bfloat16* out; int K, N, blk;
    if (bid < 48)       { in = qkvW; out = qkvWt_; K = 128; N = 384; blk = bid; }
    else if (bid < 64)  { in = outW; out = outWt_; K = 128; N = 128; blk = bid - 48; }
    else if (bid < 576) { in = w1i;  out = w1o;    K = 128; N = 512; blk = bid - 64; }
    else                { in = w2i;  out = w2o;    K = 512; N = 128; blk = bid - 576; }
    const int kt = K >> 6, nt = N >> 6;
    const int per = kt * nt;
    const int bb  = blk / per;
    const int rem = blk % per;
    const int k0  = (rem / nt) << 6;
    const int n0  = (rem % nt) << 6;
    const int tid = threadIdx.x;

    const float* src = in + ((size_t)bb * K + k0) * N + n0;
    int tk = tid >> 4;               // 0..15
    int tn = (tid & 15) * 4;         // 0..60
#pragma unroll
    for (int r = 0; r < 4; ++r) {
        float4 v = *(const float4*)(src + (size_t)(tk + r * 16) * N + tn);
        tile[tk + r * 16][tn]     = v.x;
        tile[tk + r * 16][tn + 1] = v.y;
        tile[tk + r * 16][tn + 2] = v.z;
        tile[tk + r * 16][tn + 3] = v.w;
    }
    __syncthreads();
    int on = tid >> 2;               // 0..63
    int ok = (tid & 3) * 16;         // 0,16,32,48
    unsigned pk[8];
#pragma unroll
    for (int u = 0; u < 8; ++u)
        pk[u] = pkbf(tile[ok + 2 * u][on], tile[ok + 2 * u + 1][on]);
    uint4* dst = (uint4*)(out + ((size_t)bb * N + n0 + on) * K + k0 + ok);
    dst[0] = (uint4){pk[0], pk[1], pk[2], pk[3]};
    dst[1] = (uint4){pk[4], pk[5], pk[6], pk[7]};
}

// ---------------------------------------------------------------------------
// 3. bf16 MFMA GEMM, templated <MODE, BM>.
//    MODE 0: proj, f32 out + pos.   MODE 2: out-proj, f32 residual add.
//    MODE 5: qkv, bf16 HEAD-MAJOR [part][h][token][16], Q pre-scaled.
//    (moe modes replaced by fused moe_kernel in R24)
// ---------------------------------------------------------------------------
template<int MODE, int BM>
__global__ __launch_bounds__(256) void mm_kernel(
    const __hip_bfloat16* __restrict__ A, const __hip_bfloat16* __restrict__ Wt,
    const float* __restrict__ bias, const float* __restrict__ extra,
    void* __restrict__ Cout, int K, int N)
{
    constexpr int FI = BM / 32;          // A p-groups / frag rows per wave
    __shared__ short smem[16384];        // 32 KB: As|Bs in K-loop, C-tile after
    short* As = smem;                    // BM*64 shorts
    short* Bs = smem + BM * 64;          // 8192 shorts (128x64)
    const int tid  = threadIdx.x;
    const int row0 = blockIdx.x * BM;
    const int col0 = blockIdx.y * 128;

    const int wave = tid >> 6, lane = tid & 63;
    const int crow = tid >> 3;   // 0..31  (staging row within p-group)
    const int cc   = tid & 7;    // 0..7   (16B chunk within row)

    f32x4 acc[FI][4];
#pragma unroll
    for (int i = 0; i < FI; ++i)
#pragma unroll
        for (int j = 0; j < 4; ++j) acc[i][j] = (f32x4){0.f, 0.f, 0.f, 0.f};

    const int wm = (wave >> 1) * (BM / 2), wn = (wave & 1) * 64;
    const int lr = lane & 15, q = lane >> 4;

    for (int k0 = 0; k0 < K; k0 += 64) {
#pragma unroll
        for (int p = 0; p < FI; ++p) {
            int row = p * 32 + crow;
            int sc  = (cc ^ (row & 7)) << 3;             // swizzled src chunk
            short* la = &As[(p * 32 + wave * 8) * 64];
            gload16(A + (size_t)(row0 + row) * K + k0 + sc, la);
        }
#pragma unroll
        for (int p = 0; p < 4; ++p) {
            int row = p * 32 + crow;
            int sc  = (cc ^ (row & 7)) << 3;
            short* lb = &Bs[(p * 32 + wave * 8) * 64];
            gload16(Wt + (size_t)(col0 + row) * K + k0 + sc, lb);
        }
        __syncthreads();
#pragma unroll
        for (int s = 0; s < 2; ++s) {
            short8 af[FI], bf[4];
#pragma unroll
            for (int f = 0; f < FI; ++f) {
                int m = wm + f * 16 + lr;
                af[f] = *(const short8*)&As[(m * 8 + ((s * 4 + q) ^ (m & 7))) * 8];
            }
#pragma unroll
            for (int f = 0; f < 4; ++f) {
                int n = wn + f * 16 + lr;
                bf[f] = *(const short8*)&Bs[(n * 8 + ((s * 4 + q) ^ (n & 7))) * 8];
            }
#pragma unroll
            for (int i = 0; i < FI; ++i)
#pragma unroll
                for (int j = 0; j < 4; ++j)
                    acc[i][j] = __builtin_amdgcn_mfma_f32_16x16x32_bf16(
                        bf[j], af[i], acc[i][j], 0, 0, 0);
        }
        __syncthreads();
    }

    float4 b4[4];
#pragma unroll
    for (int j = 0; j < 4; ++j)
        b4[j] = *(const float4*)&bias[col0 + wn + j * 16 + q * 4];

    if constexpr (MODE == 5) {
        const bool qsc = (col0 == 0);
#pragma unroll
        for (int i = 0; i < FI; ++i) {
            int trow = wm + i * 16 + lr;
#pragma unroll
            for (int j = 0; j < 4; ++j) {
                int cb = wn + j * 16 + q * 4;
                float v0 = acc[i][j][0] + b4[j].x;
                float v1 = acc[i][j][1] + b4[j].y;
                float v2 = acc[i][j][2] + b4[j].z;
                float v3 = acc[i][j][3] + b4[j].w;
                if (qsc) { v0 *= QSCALE; v1 *= QSCALE; v2 *= QSCALE; v3 *= QSCALE; }
                uint2 pk = {pkbf(v0, v1), pkbf(v2, v3)};
                int ch = cb >> 3;
                *(uint2*)((char*)smem + trow * 256 + ((ch ^ (trow & 7)) << 4)
                          + ((cb & 7) << 1)) = pk;
            }
        }
        __syncthreads();
        __hip_bfloat16* outb = (__hip_bfloat16*)Cout;
        constexpr int TPR = 256 / BM;
        constexpr int CPT = 16 / TPR;
        int rrow = tid / TPR;
        size_t pbase = (size_t)(col0 >> 7) * 8 * BT * 16;
#pragma unroll
        for (int u = 0; u < CPT; ++u) {
            int c = (tid % TPR) * CPT + u;               // h = c>>1, dblk = c&1
            uint4 d = *(const uint4*)((char*)smem + rrow * 256
                                      + ((c ^ (rrow & 7)) << 4));
            size_t dst = pbase + ((size_t)(c >> 1) * BT + row0 + rrow) * 16
                       + (c & 1) * 8;
            *(uint4*)(outb + dst) = d;
        }
    } else {
        // f32 output: one 64-row tile ([64][128] f32 = 32 KB)
        float* outf = (float*)Cout;
#pragma unroll
        for (int i = 0; i < FI; ++i) {
            int trow = wm + i * 16 + lr;                 // 0..63 (BM=64)
#pragma unroll
            for (int j = 0; j < 4; ++j) {
                int cb = wn + j * 16 + q * 4;
                f32x4 v = acc[i][j];
                v[0] += b4[j].x; v[1] += b4[j].y;
                v[2] += b4[j].z; v[3] += b4[j].w;
                int ch = cb >> 2;
                *(f32x4*)((char*)smem + trow * 512
                          + ((ch ^ (trow & 7)) << 4)) = v;
            }
        }
        __syncthreads();
        {
            int rrow = tid >> 2;                         // 0..63
            int grow = row0 + rrow;
            size_t rb = (size_t)grow * N + col0;
#pragma unroll
            for (int u = 0; u < 8; ++u) {
                int c = (tid & 3) * 8 + u;
                f32x4 d = *(const f32x4*)((char*)smem + rrow * 512
                                          + ((c ^ (rrow & 7)) << 4));
                int gcol = col0 + c * 4;
                if constexpr (MODE == 0) {
                    float4 p = *(const float4*)&extra[(grow & 511) * 128 + gcol];
                    d[0] += p.x; d[1] += p.y; d[2] += p.z; d[3] += p.w;
                } else if constexpr (MODE == 2) {
                    float4 p = *(const float4*)&extra[rb + c * 4];
                    d[0] += p.x; d[1] += p.y; d[2] += p.z; d[3] += p.w;
                }
                *(f32x4*)&outf[rb + c * 4] = d;
            }
        }
        __syncthreads();
    }
}

// ---------------------------------------------------------------------------
// 3b. R24 fused MoE FFN: yw = bf16(((gelu(gather(zbf)@w1^T+b1)) @ w2^T + b2)*awt)
//     One block = 64 gathered tokens, FULL FFN. zbf A-tile staged ONCE (was
//     read 4x by moe1's col-blocks); hid lives in LDS (kills the 34.6 MB/layer
//     hidbf round trip). hid passes through bf16 exactly as hidbf did, and
//     w2 K-order is the same ascending 0,64..448 -> bit-identical results.
//     LDS 48 KB: zA 64x128 | Bs 128x64 | hA 64x128 (C-tile reuses Bs).
// ---------------------------------------------------------------------------
__global__ __launch_bounds__(256) void moe_kernel(
    const __hip_bfloat16* __restrict__ zbf, const __hip_bfloat16* __restrict__ w1t,
    const float* __restrict__ b1, const __hip_bfloat16* __restrict__ w2t,
    const float* __restrict__ b2, __hip_bfloat16* __restrict__ yout,
    const int* __restrict__ moff, const int* __restrict__ atok,
    const float* __restrict__ awt)
{
    __shared__ short smem[24576];        // 48 KB
    short* zA = smem;                    // [2 ksteps][64x64]
    short* Bs = smem + 8192;             // [128x64]
    short* hA = smem + 16384;            // [2 ksteps][64x64]
    const int tid  = threadIdx.x;
    const int row0 = blockIdx.x * 64;
    if (row0 >= moff[8]) return;         // segments are 128-aligned
    int e = 0;
    while (moff[e + 1] <= row0) ++e;
    const __hip_bfloat16* W1 = w1t + (size_t)e * 512 * 128;
    const __hip_bfloat16* W2 = w2t + (size_t)e * 128 * 512;
    const float* bb1 = b1 + e * 512;
    const float* bb2 = b2 + e * 128;
    const int lim = moff[e] + moff[9 + e];

    const int wave = tid >> 6, lane = tid & 63;
    const int crow = tid >> 3;           // 0..31
    const int cc   = tid & 7;            // 0..7

    int srow[2];
#pragma unroll
    for (int p = 0; p < 2; ++p) {
        int grow = row0 + p * 32 + crow;
        srow[p] = (grow < lim) ? atok[grow] : BT;       // pad -> zeroed row
    }

    // ---- stage gathered A (zbf rows, K=128) once ----
#pragma unroll
    for (int ks = 0; ks < 2; ++ks)
#pragma unroll
        for (int p = 0; p < 2; ++p) {
            int row = p * 32 + crow;
            int sc  = (cc ^ (row & 7)) << 3;
            gload16(zbf + (size_t)srow[p] * 128 + ks * 64 + sc,
                    &zA[ks * 4096 + (p * 32 + wave * 8) * 64]);
        }

    const int wm = (wave >> 1) * 32, wn = (wave & 1) * 64;
    const int lr = lane & 15, q = lane >> 4;

    f32x4 acc2[2][4];
#pragma unroll
    for (int i = 0; i < 2; ++i)
#pragma unroll
        for (int j = 0; j < 4; ++j) acc2[i][j] = (f32x4){0.f, 0.f, 0.f, 0.f};

    __syncthreads();                     // zA ready

    for (int f0 = 0; f0 < 4; ++f0) {     // FF chunks of 128
        f32x4 acc1[2][4];
#pragma unroll
        for (int i = 0; i < 2; ++i)
#pragma unroll
            for (int j = 0; j < 4; ++j) acc1[i][j] = (f32x4){0.f, 0.f, 0.f, 0.f};

        // ---- moe1 partial: hid[64][128] = gather(zbf) @ w1 chunk ----
#pragma unroll
        for (int ks = 0; ks < 2; ++ks) {
#pragma unroll
            for (int p = 0; p < 4; ++p) {
                int row = p * 32 + crow;                 // 0..127 (FF rows)
                int sc  = (cc ^ (row & 7)) << 3;
                gload16(W1 + (size_t)(f0 * 128 + row) * 128 + ks * 64 + sc,
                        &Bs[(p * 32 + wave * 8) * 64]);
            }
            __syncthreads();
#pragma unroll
            for (int s = 0; s < 2; ++s) {
                short8 af[2], bf[4];
#pragma unroll
                for (int f = 0; f < 2; ++f) {
                    int m = wm + f * 16 + lr;
                    af[f] = *(const short8*)&zA[ks * 4096
                            + (m * 8 + ((s * 4 + q) ^ (m & 7))) * 8];
                }
#pragma unroll
                for (int f = 0; f < 4; ++f) {
                    int n = wn + f * 16 + lr;
                    bf[f] = *(const short8*)&Bs[(n * 8 + ((s * 4 + q) ^ (n & 7))) * 8];
                }
#pragma unroll
                for (int i = 0; i < 2; ++i)
#pragma unroll
                    for (int j = 0; j < 4; ++j)
                        acc1[i][j] = __builtin_amdgcn_mfma_f32_16x16x32_bf16(
                            bf[j], af[i], acc1[i][j], 0, 0, 0);
            }
            __syncthreads();
        }

        // ---- gelu+bias, pack hid chunk into hA in As-swizzle format ----
#pragma unroll
        for (int i = 0; i < 2; ++i) {
            int trow = wm + i * 16 + lr;
#pragma unroll
            for (int j = 0; j < 4; ++j) {
                int cb = wn + j * 16 + q * 4;            // hid col 0..127
                float4 g4 = *(const float4*)&bb1[f0 * 128 + cb];
                float v0 = gelu_f(acc1[i][j][0] + g4.x);
                float v1 = gelu_f(acc1[i][j][1] + g4.y);
                float v2 = gelu_f(acc1[i][j][2] + g4.z);
                float v3 = gelu_f(acc1[i][j][3] + g4.w);
                uint2 pk = {pkbf(v0, v1), pkbf(v2, v3)};
                int s2 = cb >> 6, kl = cb & 63, ch = kl >> 3;
                *(uint2*)((char*)hA + s2 * 8192 + trow * 128
                          + ((ch ^ (trow & 7)) << 4) + ((kl & 7) << 1)) = pk;
            }
        }
        __syncthreads();                 // hA complete

        // ---- moe2 partial: acc2 += hid_chunk @ w2[:, f0*128..] ----
#pragma unroll
        for (int ks2 = 0; ks2 < 2; ++ks2) {
#pragma unroll
            for (int p = 0; p < 4; ++p) {
                int row = p * 32 + crow;                 // 0..127 (out cols)
                int sc  = (cc ^ (row & 7)) << 3;
                gload16(W2 + (size_t)row * 512 + f0 * 128 + ks2 * 64 + sc,
                        &Bs[(p * 32 + wave * 8) * 64]);
            }
            __syncthreads();
#pragma unroll
            for (int s = 0; s < 2; ++s) {
                short8 af[2], bf[4];
#pragma unroll
                for (int f = 0; f < 2; ++f) {
                    int m = wm + f * 16 + lr;
                    af[f] = *(const short8*)&hA[ks2 * 4096
                            + (m * 8 + ((s * 4 + q) ^ (m & 7))) * 8];
                }
#pragma unroll
                for (int f = 0; f < 4; ++f) {
                    int n = wn + f * 16 + lr;
                    bf[f] = *(const short8*)&Bs[(n * 8 + ((s * 4 + q) ^ (n & 7))) * 8];
                }
#pragma unroll
                for (int i = 0; i < 2; ++i)
#pragma unroll
                    for (int j = 0; j < 4; ++j)
                        acc2[i][j] = __builtin_amdgcn_mfma_f32_16x16x32_bf16(
                            bf[j], af[i], acc2[i][j], 0, 0, 0);
            }
            __syncthreads();
        }
    }

    // ---- epilogue: b2 + awt scale, bf16 pack into Bs region, coalesced ----
    float4 b4[4];
#pragma unroll
    for (int j = 0; j < 4; ++j)
        b4[j] = *(const float4*)&bb2[wn + j * 16 + q * 4];
#pragma unroll
    for (int i = 0; i < 2; ++i) {
        int trow = wm + i * 16 + lr;
        float aw = awt[row0 + trow];
#pragma unroll
        for (int j = 0; j < 4; ++j) {
            int cb = wn + j * 16 + q * 4;
            float v0 = (acc2[i][j][0] + b4[j].x) * aw;
            float v1 = (acc2[i][j][1] + b4[j].y) * aw;
            float v2 = (acc2[i][j][2] + b4[j].z) * aw;
            float v3 = (acc2[i][j][3] + b4[j].w) * aw;
            uint2 pk = {pkbf(v0, v1), pkbf(v2, v3)};
            int ch = cb >> 3;                            // 0..15
            *(uint2*)((char*)Bs + trow * 256 + ((ch ^ (trow & 7)) << 4)
                      + ((cb & 7) << 1)) = pk;
        }
    }
    __syncthreads();
    {
        int rrow = tid >> 2;                             // 0..63
        size_t rb = (size_t)(row0 + rrow) * 128;
#pragma unroll
        for (int u = 0; u < 4; ++u) {
            int c = (tid & 3) * 4 + u;                   // chunk 0..15
            uint4 d = *(const uint4*)((char*)Bs + rrow * 256
                                      + ((c ^ (rrow & 7)) << 4));
            *(uint4*)(yout + rb + c * 8) = d;
        }
    }
}

// ---------------------------------------------------------------------------
// 4. LayerNorm over D=128 -> bf16 zbf (layer-0 ln1 only)
// ---------------------------------------------------------------------------
__global__ __launch_bounds__(256) void ln_kernel(const float* __restrict__ x,
                                                 const float* __restrict__ g,
                                                 const float* __restrict__ b,
                                                 __hip_bfloat16* __restrict__ zbf) {
    int wave = threadIdx.x >> 6, lane = threadIdx.x & 63;
    size_t row = (size_t)blockIdx.x * 4 + wave;
    const float* xr = x + row * 128;
    float a0 = xr[lane], a1 = xr[lane + 64];
    float s = a0 + a1;
#pragma unroll
    for (int off = 32; off > 0; off >>= 1) s += __shfl_xor(s, off);
    float mean = s * (1.f / 128.f);
    float d0 = a0 - mean, d1 = a1 - mean;
    float v = d0 * d0 + d1 * d1;
#pragma unroll
    for (int off = 32; off > 0; off >>= 1) v += __shfl_xor(v, off);
    float inv = rsqrtf(v * (1.f / 128.f) + 1e-5f);
    zbf[row * 128 + lane]      = __float2bfloat16(d0 * inv * g[lane] + b[lane]);
    zbf[row * 128 + lane + 64] = __float2bfloat16(d1 * inv * g[lane + 64] + b[lane + 64]);
}

// ---------------------------------------------------------------------------
// 5. MFMA flash attention v4: one block per (b,h), 1024 threads, 16 waves.
//    K/V staged once; staging split across thread halves.
// ---------------------------------------------------------------------------
__global__ __launch_bounds__(1024) void attn_kernel(const __hip_bfloat16* __restrict__ qkv,
                                                    __hip_bfloat16* __restrict__ o) {
    __shared__ short Ks[512 * 24];    // K [key][16 used, 24 pitch] : 24 KB
    __shared__ short Vt[17 * 520];    // V^T [col 0..15, 16=ones][key, 520 pitch]
    const int hh = blockIdx.x, b = blockIdx.y;
    const int tid = threadIdx.x;
    const __hip_bfloat16* Qh = qkv + ((size_t)(0 * 8 + hh) * BT + b * 512) * 16;
    const __hip_bfloat16* Kh = qkv + ((size_t)(1 * 8 + hh) * BT + b * 512) * 16;
    const __hip_bfloat16* Vh = qkv + ((size_t)(2 * 8 + hh) * BT + b * 512) * 16;

    if (tid < 512) {
        int r = tid;
        const uint4* ksrc = (const uint4*)(Kh + (size_t)r * 16);
        uint4 k0 = ksrc[0], k1 = ksrc[1];
        *(uint4*)&Ks[r * 24 + 0] = k0;
        *(uint4*)&Ks[r * 24 + 8] = k1;
    } else {
        int r = tid - 512;
        const uint4* vsrc = (const uint4*)(Vh + (size_t)r * 16);
        uint4 v0 = vsrc[0], v1 = vsrc[1];
        unsigned vv[8] = {v0.x, v0.y, v0.z, v0.w, v1.x, v1.y, v1.z, v1.w};
#pragma unroll
        for (int c = 0; c < 8; ++c) {
            Vt[(2 * c)     * 520 + r] = (short)(vv[c] & 0xffff);
            Vt[(2 * c + 1) * 520 + r] = (short)(vv[c] >> 16);
        }
        Vt[16 * 520 + r] = (short)0x3F80;   // 1.0 bf16
    }
    __syncthreads();

    const int wave = tid >> 6, lane = tid & 63;
    const int lm = lane & 31, lh = lane >> 5;
    const int qrow0 = wave * 32;           // 16 waves x 32 rows = 512

    short8 qf = *(const short8*)(Qh + (size_t)(qrow0 + lm) * 16 + lh * 8);

    f32x16 accO;
#pragma unroll
    for (int r = 0; r < 16; ++r) accO[r] = 0.f;

    for (int kc = 0; kc < 16; ++kc) {
        short8 kf = *(const short8*)&Ks[(kc * 32 + lm) * 24 + lh * 8];
        int vr = (lm < 16) ? lm : 16;
        const short* vb2 = &Vt[vr * 520 + kc * 32];
        short4v va  = *(const short4v*)(vb2 + 4 * lh);
        short4v vbq = *(const short4v*)(vb2 + 8 + 4 * lh);
        short4v vc  = *(const short4v*)(vb2 + 16 + 4 * lh);
        short4v vd  = *(const short4v*)(vb2 + 24 + 4 * lh);
        short8 vf0, vf1;
#pragma unroll
        for (int j = 0; j < 4; ++j) {
            vf0[j] = va[j];  vf0[4 + j] = vbq[j];
            vf1[j] = vc[j];  vf1[4 + j] = vd[j];
        }
        f32x16 st;
#pragma unroll
        for (int r = 0; r < 16; ++r) st[r] = 0.f;
        st = __builtin_amdgcn_mfma_f32_32x32x16_bf16(kf, qf, st, 0, 0, 0);
        short8 pf0, pf1;
#pragma unroll
        for (int r = 0; r < 8; ++r) {
            pf0[r] = (short)(__float_as_uint(exp2f(st[r]))     >> 16);
            pf1[r] = (short)(__float_as_uint(exp2f(st[8 + r])) >> 16);
        }
        accO = __builtin_amdgcn_mfma_f32_32x32x16_bf16(pf0, vf0, accO, 0, 0, 0);
        accO = __builtin_amdgcn_mfma_f32_32x32x16_bf16(pf1, vf1, accO, 0, 0, 0);
    }

#pragma unroll
    for (int r = 0; r < 16; ++r) {
        float val = accO[r];
        float s = __shfl(val, (lane & 32) + 16);
        if (lm < 16) {
            int qr = qrow0 + (r & 3) + 8 * (r >> 2) + 4 * lh;
            o[((size_t)b * 512 + qr) * 128 + hh * 16 + lm] = __float2bfloat16(val / s);
        }
    }
}

// ---------------------------------------------------------------------------
// 6. Fused LN2 + router. Slot index = blockIdx>>6: slot s aggregates exactly
//    scatter-block s's 256 tokens. Per-layer slots zeroed once in preamble.
// ---------------------------------------------------------------------------
__global__ __launch_bounds__(256) void ln2gate_kernel(
    const float* __restrict__ x, const float* __restrict__ g, const float* __restrict__ b,
    const float* __restrict__ gW, __hip_bfloat16* __restrict__ zbf,
    int* __restrict__ topi, float* __restrict__ topw,
    float* __restrict__ impS, int* __restrict__ cntS)
{
    __shared__ float simp[8];
    __shared__ int scnt[8];
    const int tid = threadIdx.x;
    if (tid < 8) { simp[tid] = 0.f; scnt[tid] = 0; }
    __syncthreads();
    const int wave = tid >> 6, lane = tid & 63;
    const size_t row = (size_t)blockIdx.x * 4 + wave;
    const float* xr = x + row * 128;
    float a0 = xr[lane], a1 = xr[lane + 64];
    float s = a0 + a1;
#pragma unroll
    for (int off = 32; off > 0; off >>= 1) s += __shfl_xor(s, off);
    float mean = s * (1.f / 128.f);
    float d0 = a0 - mean, d1 = a1 - mean;
    float v = d0 * d0 + d1 * d1;
#pragma unroll
    for (int off = 32; off > 0; off >>= 1) v += __shfl_xor(v, off);
    float inv = rsqrtf(v * (1.f / 128.f) + 1e-5f);
    float o0 = d0 * inv * g[lane] + b[lane];
    float o1 = d1 * inv * g[lane + 64] + b[lane + 64];
    zbf[row * 128 + lane]      = __float2bfloat16(o0);
    zbf[row * 128 + lane + 64] = __float2bfloat16(o1);
    // router logits: lg[e] = sum_d z[d]*gW[d][e]
    float4 gA = *(const float4*)&gW[lane * 8];
    float4 gB = *(const float4*)&gW[lane * 8 + 4];
    float4 gC = *(const float4*)&gW[(lane + 64) * 8];
    float4 gD = *(const float4*)&gW[(lane + 64) * 8 + 4];
    float lg[8];
    lg[0] = o0 * gA.x + o1 * gC.x;  lg[1] = o0 * gA.y + o1 * gC.y;
    lg[2] = o0 * gA.z + o1 * gC.z;  lg[3] = o0 * gA.w + o1 * gC.w;
    lg[4] = o0 * gB.x + o1 * gD.x;  lg[5] = o0 * gB.y + o1 * gD.y;
    lg[6] = o0 * gB.z + o1 * gD.z;  lg[7] = o0 * gB.w + o1 * gD.w;
#pragma unroll
    for (int e = 0; e < 8; ++e)
#pragma unroll
        for (int off = 32; off > 0; off >>= 1) lg[e] += __shfl_xor(lg[e], off);
    if (lane == 0) {
        float p[8];
        float mx = lg[0];
#pragma unroll
        for (int k = 1; k < 8; ++k) mx = fmaxf(mx, lg[k]);
        float ssum = 0.f;
#pragma unroll
        for (int k = 0; k < 8; ++k) { p[k] = expf(lg[k] - mx); ssum += p[k]; }
        float pinv = 1.f / ssum;
#pragma unroll
        for (int k = 0; k < 8; ++k) p[k] *= pinv;
        int i0 = 0; float v0 = p[0];
#pragma unroll
        for (int k = 1; k < 8; ++k) if (p[k] > v0) { v0 = p[k]; i0 = k; }
        int i1 = -1; float v1 = -1.f;
#pragma unroll
        for (int k = 0; k < 8; ++k) if (k != i0 && p[k] > v1) { v1 = p[k]; i1 = k; }
        float wsum = v0 + v1;
        topi[row * 2] = i0;  topi[row * 2 + 1] = i1;
        topw[row * 2] = v0 / wsum;  topw[row * 2 + 1] = v1 / wsum;
#pragma unroll
        for (int k = 0; k < 8; ++k) atomicAdd(&simp[k], p[k]);
        atomicAdd(&scnt[i0], 1); atomicAdd(&scnt[i1], 1);
    }
    __syncthreads();
    if (tid < 8) {
        int slot = (blockIdx.x >> 6) * 8 + tid;     // slot s = scatter block s
        atomicAdd(&impS[slot], simp[tid]);
        atomicAdd(&cntS[slot], scnt[tid]);
    }
}

// ---------------------------------------------------------------------------
// 8. Scatter + fused offsets. Each of the 64 blocks redundantly reduces the
//    64x8 slot table (L2-hot); prefix over slots < blk gives deterministic
//    per-expert base. Block 0 writes moff[] + aux. No global fill atomics.
// ---------------------------------------------------------------------------
__global__ __launch_bounds__(256) void scatter_kernel(
    const int* __restrict__ topi, const float* __restrict__ topw,
    const int* __restrict__ cntS, const float* __restrict__ impS,
    int* __restrict__ atok, float* __restrict__ awt, int* __restrict__ tokpos,
    int* __restrict__ moffw, float* __restrict__ aux)
{
    __shared__ int lcnt[8];
    __shared__ int lbase[8];
    __shared__ int csum[8];
    __shared__ float isum[8];
    const int tid = threadIdx.x;
    const int blk = blockIdx.x;                  // 0..63
    if (tid < 64) {                              // wave 0, all lanes active
        int e = tid & 7, grp = tid >> 3;
        int ct = 0, cp = 0; float im = 0.f;
        for (int g = 0; g < 8; ++g) {
            int sl = grp * 8 + g;
            int vv = cntS[sl * 8 + e];
            ct += vv;
            cp += (sl < blk) ? vv : 0;
            im += impS[sl * 8 + e];
        }
#pragma unroll
        for (int off = 32; off >= 8; off >>= 1) {
            ct += __shfl_down(ct, off);
            cp += __shfl_down(cp, off);
            im += __shfl_down(im, off);
        }
        if (tid < 8) { csum[tid] = ct; isum[tid] = im; lbase[tid] = cp; lcnt[tid] = 0; }
    }
    __syncthreads();
    if (tid < 8) {
        int t = 0;
        for (int k = 0; k < tid; ++k) t += (csum[k] + 127) & ~127;   // moff[tid]
        lbase[tid] += t;                         // moff[e] + prefix-before-block
    }
    if (blk == 0 && tid == 64) {                 // separate lane: write moff + aux
        int t = 0; float s = 0.f;
        for (int k = 0; k < 8; ++k) {
            int ck = csum[k];
            moffw[k] = t;
            moffw[9 + k] = ck;
            t += (ck + 127) & ~127;
            s += (isum[k] * (1.f / 16384.f)) * ((float)ck * (1.f / 16384.f));
        }
        moffw[8] = t;
        aux[0] += 8.f * s;
    }
    __syncthreads();
    const int token = blk * 256 + tid;
    const int e0 = topi[token * 2], e1 = topi[token * 2 + 1];
    const float w0 = topw[token * 2], w1 = topw[token * 2 + 1];
    const int l0 = atomicAdd(&lcnt[e0], 1);
    const int l1 = atomicAdd(&lcnt[e1], 1);      // e1 != e0 (top-2 distinct)
    const int p0 = lbase[e0] + l0;
    const int p1 = lbase[e1] + l1;
    atok[p0] = token;  awt[p0] = w0;  tokpos[token * 2]     = p0;
    atok[p1] = token;  awt[p1] = w1;  tokpos[token * 2 + 1] = p1;
}

// ---------------------------------------------------------------------------
// 9. Fused combine + next-layer LN1: h += expert outputs (bf16 yw);
//    optional LN -> zbf
// ---------------------------------------------------------------------------
__global__ __launch_bounds__(256) void combine_ln_kernel(
    const __hip_bfloat16* __restrict__ yw, const int* __restrict__ tokpos,
    float* __restrict__ h, const float* __restrict__ g, const float* __restrict__ b,
    __hip_bfloat16* __restrict__ zbf)
{
    const int tid = threadIdx.x;
    const int wave = tid >> 6, lane = tid & 63;
    const size_t row = (size_t)blockIdx.x * 4 + wave;
    const int p0 = tokpos[row * 2], p1 = tokpos[row * 2 + 1];
    const unsigned short* y0 = (const unsigned short*)(yw + (size_t)p0 * 128);
    const unsigned short* y1 = (const unsigned short*)(yw + (size_t)p1 * 128);
    float a0 = h[row * 128 + lane]      + bf2f(y0[lane])      + bf2f(y1[lane]);
    float a1 = h[row * 128 + lane + 64] + bf2f(y0[lane + 64]) + bf2f(y1[lane + 64]);
    h[row * 128 + lane]      = a0;
    h[row * 128 + lane + 64] = a1;
    if (zbf) {
        float s = a0 + a1;
#pragma unroll
        for (int off = 32; off > 0; off >>= 1) s += __shfl_xor(s, off);
        float mean = s * (1.f / 128.f);
        float d0 = a0 - mean, d1 = a1 - mean;
        float v = d0 * d0 + d1 * d1;
#pragma unroll
        for (int off = 32; off > 0; off >>= 1) v += __shfl_xor(v, off);
        float inv = rsqrtf(v * (1.f / 128.f) + 1e-5f);
        zbf[row * 128 + lane]      = __float2bfloat16(d0 * inv * g[lane] + b[lane]);
        zbf[row * 128 + lane + 64] = __float2bfloat16(d1 * inv * g[lane + 64] + b[lane + 64]);
    }
}

// ---------------------------------------------------------------------------
// 10. mean over T -> LN -> head matmul [128,2]; writes aux scalar
// ---------------------------------------------------------------------------
__global__ __launch_bounds__(1024) void head_kernel(const float* __restrict__ h,
                                                    const float* __restrict__ g,
                                                    const float* __restrict__ bb,
                                                    const float* __restrict__ hW,
                                                    const float* __restrict__ hb,
                                                    const float* __restrict__ aux,
                                                    float* __restrict__ out) {
    __shared__ float part[8][128];
    __shared__ float red[128];
    __shared__ float pl[128];
    int b = blockIdx.x, tid = threadIdx.x;
    int c = tid & 127, w = tid >> 7;            // w = 0..7
    float s = 0.f;
    for (int t = w; t < 512; t += 8) s += h[((size_t)b * 512 + t) * 128 + c];
    part[w][c] = s;
    __syncthreads();
    float pooled = 0.f;
    if (tid < 128) {
#pragma unroll
        for (int k = 0; k < 8; ++k) pooled += part[k][tid];
        pooled *= (1.f / 512.f);
        red[tid] = pooled;
    }
    __syncthreads();
    for (int st = 64; st > 0; st >>= 1) { if (tid < st) red[tid] += red[tid + st]; __syncthreads(); }
    float mean = red[0] * (1.f / 128.f);
    __syncthreads();
    float d = pooled - mean;
    if (tid < 128) red[tid] = d * d;
    __syncthreads();
    for (int st = 64; st > 0; st >>= 1) { if (tid < st) red[tid] += red[tid + st]; __syncthreads(); }
    float var = red[0] * (1.f / 128.f);
    if (tid < 128) pl[tid] = d / sqrtf(var + 1e-5f) * g[tid] + bb[tid];
    __syncthreads();
    if (tid < 2) {
        float acc = hb[tid];
        for (int k = 0; k < 128; ++k) acc += pl[k] * hW[k * 2 + tid];
        out[b * 2 + tid] = acc;
    }
    if (b == 0 && tid == 0) out[64] = aux[0];
}

// ---------------------------------------------------------------------------
extern "C" void kernel_launch(void* const* d_in, const int* in_sizes, int n_in,
                              void* d_out, int out_size, void* d_ws, size_t ws_size,
                              hipStream_t stream) {
    (void)in_sizes; (void)n_in; (void)out_size; (void)ws_size;
    const float* x      = (const float*)d_in[0];
    const float* proj_W = (const float*)d_in[1];
    const float* proj_b = (const float*)d_in[2];
    const float* pos    = (const float*)d_in[3];
    const float* ln1_g  = (const float*)d_in[4];
    const float* ln1_b  = (const float*)d_in[5];
    const float* qkv_W  = (const float*)d_in[6];
    const float* qkv_b  = (const float*)d_in[7];
    const float* out_W  = (const float*)d_in[8];
    const float* out_b  = (const float*)d_in[9];
    const float* ln2_g  = (const float*)d_in[10];
    const float* ln2_b  = (const float*)d_in[11];
    const float* gate_W = (const float*)d_in[12];
    const float* w1     = (const float*)d_in[13];
    const float* b1     = (const float*)d_in[14];
    const float* w2     = (const float*)d_in[15];
    const float* b2     = (const float*)d_in[16];
    const float* hl_g   = (const float*)d_in[17];
    const float* hl_b   = (const float*)d_in[18];
    const float* head_W = (const float*)d_in[19];
    const float* head_b = (const float*)d_in[20];
    float* outp = (float*)d_out;

    // workspace layout (float granularity)
    float* ws = (float*)d_ws;
    size_t off = 0;
    auto alloc = [&](size_t n) { float* p = ws + off; off += (n + 63) & ~(size_t)63; return p; };
    float* xtb_f   = alloc((size_t)BT * 224);         // bf16 [16384][448]
    float* h       = alloc((size_t)BT * 128);
    float* zbf_f   = alloc((size_t)(BT + 1) * 64);    // bf16 [16385][128], row BT = zeros
    float* qkvbf_f = alloc((size_t)BT * 192);         // bf16 head-major [3][8][BT][16]
    float* obbf_f  = alloc((size_t)BT * 64);          // bf16 [16384][128]
    float* yw      = alloc((size_t)MAXASSIGN * 64);   // bf16 [MAXASSIGN][128]
    float* projWt_f= alloc(128 * 448 / 2);
    float* qkvWt_f = alloc(4 * 384 * 128 / 2);
    float* outWt_f = alloc(4 * 128 * 128 / 2);
    float* w1t_f   = alloc((size_t)32 * 512 * 128 / 2);
    float* w2t_f   = alloc((size_t)32 * 128 * 512 / 2);
    float* topw    = alloc(32768);
    float* awt     = alloc(MAXASSIGN);
    float* impc    = alloc(4096);                     // 4 layers x (impS[64][8] + cntS[64][8])
    float* auxp    = alloc(1);
    int* topi      = (int*)alloc(32768);
    int* atok      = (int*)alloc(MAXASSIGN);
    int* tokpos    = (int*)alloc(32768);
    int* moff      = (int*)alloc(32);

    __hip_bfloat16* xtb    = (__hip_bfloat16*)xtb_f;
    __hip_bfloat16* zbf    = (__hip_bfloat16*)zbf_f;
    __hip_bfloat16* qkvbf  = (__hip_bfloat16*)qkvbf_f;
    __hip_bfloat16* obbf   = (__hip_bfloat16*)obbf_f;
    __hip_bfloat16* ywb    = (__hip_bfloat16*)yw;
    __hip_bfloat16* projWt = (__hip_bfloat16*)projWt_f;
    __hip_bfloat16* qkvWt  = (__hip_bfloat16*)qkvWt_f;
    __hip_bfloat16* outWt  = (__hip_bfloat16*)outWt_f;
    __hip_bfloat16* w1t    = (__hip_bfloat16*)w1t_f;
    __hip_bfloat16* w2t    = (__hip_bfloat16*)w2t_f;

    // init: aux, all layers' slots, zbf zero gather row (1 launch)
    init_kernel<<<1, 256, 0, stream>>>(auxp, impc,
                                       (unsigned*)((char*)zbf + (size_t)BT * 256));

    // input transpose + projconv (1 launch) + all weight conversions (1 launch)
    transpose_kernel<<<480, 256, 0, stream>>>(x, xtb, proj_W, projWt);
    wconvt4_kernel<<<1088, 256, 0, stream>>>(qkv_W, qkvWt, out_W, outWt,
                                             w1, w1t, w2, w2t);

    // proj: h = xtb @ projWt^T + proj_b + pos  (K=448)
    mm_kernel<0, 64><<<dim3(256, 1), 256, 0, stream>>>(
        xtb, projWt, proj_b, pos, h, 448, 128);
    // layer-0 ln1 (subsequent ln1's are fused into combine_ln)
    ln_kernel<<<4096, 256, 0, stream>>>(h, ln1_g, ln1_b, zbf);

    for (int i = 0; i < 4; ++i) {
        float* impS = impc + (size_t)i * 1024;          // per-layer slots
        int*   cntS = (int*)(impc + (size_t)i * 1024 + 512);
        // qkv -> bf16 head-major, Q pre-scaled
        mm_kernel<5, 64><<<dim3(256, 3), 256, 0, stream>>>(
            zbf, qkvWt + (size_t)i * 384 * 128, qkv_b + i * 384, nullptr, qkvbf,
            128, 384);
        attn_kernel<<<dim3(8, 32), 1024, 0, stream>>>(qkvbf, obbf);
        mm_kernel<2, 64><<<dim3(256, 1), 256, 0, stream>>>(
            obbf, outWt + (size_t)i * 128 * 128, out_b + i * 128, h, h,
            128, 128);
        ln2gate_kernel<<<4096, 256, 0, stream>>>(h, ln2_g + i * 128, ln2_b + i * 128,
                                                 gate_W + (size_t)i * 128 * 8, zbf,
                                                 topi, topw, impS, cntS);
        // scatter + fused offsets (no fill atomics, no offsets kernel)
        scatter_kernel<<<64, 256, 0, stream>>>(topi, topw, cntS, impS,
                                               atok, awt, tokpos, moff, auxp);
        // fused MoE FFN: gather -> w1+gelu -> (LDS) -> w2 -> *awt -> bf16 yw
        moe_kernel<<<528, 256, 0, stream>>>(
            zbf, w1t + (size_t)i * 8 * 512 * 128, b1 + (size_t)i * 8 * 512,
            w2t + (size_t)i * 8 * 128 * 512, b2 + (size_t)i * 8 * 128,
            ywb, moff, atok, awt);
        // combine + next-layer ln1 (fused); last layer: no LN
        combine_ln_kernel<<<4096, 256, 0, stream>>>(ywb, tokpos, h,
                                                    ln1_g + (i + 1 < 4 ? (i + 1) * 128 : 0),
                                                    ln1_b + (i + 1 < 4 ? (i + 1) * 128 : 0),
                                                    (i < 3) ? zbf : (__hip_bfloat16*)nullptr);
    }
    head_kernel<<<32, 1024, 0, stream>>>(h, hl_g, hl_b, head_W, head_b, auxp, outp);
}